// Round 3
// baseline (7858.632 us; speedup 1.0000x reference)
//
#include <hip/hip_runtime.h>
#include <hip/hip_bf16.h>
#include <math.h>

#define NRAD 96
#define HIDDIM 128

__device__ __forceinline__ float silu_f(float x){ return x / (1.f + __expf(-x)); }

// ---------------- dtype detection ----------------
// flags[0] = 1 if floats are bf16, 0 if fp32
// flags[1] = 1 if ints are int64, 0 if int32
__global__ void k_detect(const unsigned short* posw, int npos,
                         const int* batchw, int nb, int* flags){
  __shared__ int bad, orv;
  if (threadIdx.x == 0){ bad = 0; orv = 0; }
  __syncthreads();
  int nscan = npos < 4096 ? npos : 4096;
  for (int t = threadIdx.x; t < nscan; t += 256){
    float x = __uint_as_float(((unsigned int)posw[t]) << 16);
    if (!(fabsf(x) <= 1000.f)) atomicOr(&bad, 1);   // catches NaN/inf too
  }
  for (int t = threadIdx.x; t < nb; t += 256){
    if (t & 1) atomicOr(&orv, batchw[t]);
  }
  __syncthreads();
  if (threadIdx.x == 0){ flags[0] = bad ? 0 : 1; flags[1] = orv ? 0 : 1; }
}

// normalize int inputs to int32
__global__ void k_iconv(const int* zsrc, const int* bsrc, const int* esrc,
                        int* zi, int* bi, int* eii, int Nn, int E2, const int* flags){
  int f = flags[1];
  int total = 2*Nn + E2;
  for (int t = blockIdx.x*blockDim.x + threadIdx.x; t < total; t += gridDim.x*blockDim.x){
    if (t < Nn) zi[t] = zsrc[(size_t)t << f];
    else if (t < 2*Nn) bi[t-Nn] = bsrc[(size_t)(t-Nn) << f];
    else eii[t-2*Nn] = esrc[(size_t)(t-2*Nn) << f];
  }
}

// ---------------- conversion: (bf16|f32) -> f32 ----------------
struct ConvDesc { const unsigned short* src; float* dst; int n; };
struct ConvArgs { ConvDesc d[32]; };

__global__ void k_conv(ConvArgs a, int cnt, const int* flags){
  int y = blockIdx.y;
  if (y >= cnt) return;
  int f = flags[0];
  const unsigned short* s = a.d[y].src;
  float* dst = a.d[y].dst;
  int n = a.d[y].n;
  if (f){
    for (int t = blockIdx.x*blockDim.x + threadIdx.x; t < n; t += gridDim.x*blockDim.x)
      dst[t] = __uint_as_float(((unsigned int)s[t]) << 16);
  } else {
    const float* sf = (const float*)s;
    for (int t = blockIdx.x*blockDim.x + threadIdx.x; t < n; t += gridDim.x*blockDim.x)
      dst[t] = sf[t];
  }
}

__global__ void k_zero(float* __restrict__ p, int n){
  int t = blockIdx.x*blockDim.x + threadIdx.x;
  int stride = gridDim.x*blockDim.x;
  for (; t < n; t += stride) p[t] = 0.f;
}

__global__ void k_sentinel(__hip_bfloat16* out, int n, float val){
  int t = threadIdx.x;
  if (t < n) out[t] = __float2bfloat16(val);
}

// ---------------- per-chunk geometry + RBF (local-indexed outputs) ----------------
__global__ void k_geom(const float* __restrict__ pos, const int* __restrict__ ei,
                       int E, int off, int Cc,
                       float* __restrict__ edb, float* __restrict__ ecv,
                       float* __restrict__ rb, float* __restrict__ remb)
{
  int el = blockIdx.x*blockDim.x + threadIdx.x;
  if (el >= Cc) return;
  int g = off + el;
  int j = ei[g], i = ei[E+g];
  float pjx = pos[3*j], pjy = pos[3*j+1], pjz = pos[3*j+2];
  float pix = pos[3*i], piy = pos[3*i+1], piz = pos[3*i+2];
  float vx = pjx-pix, vy = pjy-piy, vz = pjz-piz;
  float d = sqrtf(vx*vx + vy*vy + vz*vz);
  float inv = 1.f/(d + 1e-10f);
  float edx = vx*inv, edy = vy*inv, edz = vz*inv;
  float cx = piy*pjz - piz*pjy;
  float cy = piz*pjx - pix*pjz;
  float cz = pix*pjy - piy*pjx;
  float cn = sqrtf(cx*cx + cy*cy + cz*cz);
  float inv2 = 1.f/(cn + 1e-10f);
  cx *= inv2; cy *= inv2; cz *= inv2;
  float evx = edy*cz - edz*cy;
  float evy = edz*cx - edx*cz;
  float evz = edx*cy - edy*cx;
  edb[3*el]=edx; edb[3*el+1]=edy; edb[3*el+2]=edz;
  ecv[6*el]=cx; ecv[6*el+1]=cy; ecv[6*el+2]=cz;
  ecv[6*el+3]=evx; ecv[6*el+4]=evy; ecv[6*el+5]=evz;
  float rbv = 0.5f*(cosf(d*0.52359877559829887f) + 1.f);  // cos(d*pi/6)
  rb[el] = rbv;
  float env = (d < 6.f) ? rbv : 0.f;
  const double st = 0.0024787521766663585;      // exp(-6)
  const double pr = (2.0/96.0)*(1.0 - st);
  float beta = (float)(1.0/(pr*pr));
  float emd = expf(-d);
  for (int k = 0; k < NRAD; ++k){
    float mu = (float)(st + (1.0 - st)*((double)k/95.0));
    float t = emd - mu;
    remb[(size_t)el*NRAD + k] = env * expf(-beta*t*t);
  }
}

// ---------------- node embedding + layernorm ----------------
__global__ __launch_bounds__(128) void k_embed(const int* __restrict__ z,
    const float* __restrict__ ne_w, const float* __restrict__ ne_b,
    float* __restrict__ s, float* __restrict__ h0, int Nn)
{
  int n = blockIdx.x; int h = threadIdx.x;
  float x = ne_w[(size_t)z[n]*HIDDIM + h] + ne_b[h];
  __shared__ float red[128];
  red[h] = x; __syncthreads();
  for (int o = 64; o > 0; o >>= 1){ if (h < o) red[h] += red[h+o]; __syncthreads(); }
  float mean = red[0] * (1.f/128.f);
  __syncthreads();
  float dx = x - mean;
  red[h] = dx*dx; __syncthreads();
  for (int o = 64; o > 0; o >>= 1){ if (h < o) red[h] += red[h+o]; __syncthreads(); }
  float var = red[0] * (1.f/128.f);
  float y = dx * rsqrtf(var + 1e-5f);
  s[(size_t)n*HIDDIM + h] = y;
  h0[(size_t)n*HIDDIM + h] = y;
}

__global__ __launch_bounds__(128) void k_ln(const float* __restrict__ src, float* __restrict__ dst,
    const float* __restrict__ g, const float* __restrict__ b, int Nn)
{
  int n = blockIdx.x; int h = threadIdx.x;
  float x = src[(size_t)n*HIDDIM + h];
  __shared__ float red[128];
  red[h] = x; __syncthreads();
  for (int o = 64; o > 0; o >>= 1){ if (h < o) red[h] += red[h+o]; __syncthreads(); }
  float mean = red[0] * (1.f/128.f);
  __syncthreads();
  float dx = x - mean;
  red[h] = dx*dx; __syncthreads();
  for (int o = 64; o > 0; o >>= 1){ if (h < o) red[h] += red[h+o]; __syncthreads(); }
  float var = red[0] * (1.f/128.f);
  float y = dx * rsqrtf(var + 1e-5f);
  dst[(size_t)n*HIDDIM + h] = y * g[h] + b[h];
}

// ---------------- segment sums (atomics), chunk-local per-edge data ----------------
__global__ void k_seg1(const int* __restrict__ ei, int E, int off, int Cc,
                       const float* __restrict__ h0,
                       const float* __restrict__ rhid, float* __restrict__ s)
{
  int t = blockIdx.x*blockDim.x + threadIdx.x;
  if (t >= Cc*HIDDIM) return;
  int el = t >> 7, h = t & 127;
  int g = off + el;
  int j = ei[g], i = ei[E+g];
  atomicAdd(&s[(size_t)i*HIDDIM + h], h0[(size_t)j*HIDDIM + h] * rhid[t]);
}

__global__ void k_seg2(const int* __restrict__ ei, int E, int off, int Cc,
                       const float* __restrict__ slin,
                       const float* __restrict__ rhid, const float* __restrict__ edb,
                       float* __restrict__ S)
{
  int t = blockIdx.x*blockDim.x + threadIdx.x;
  if (t >= Cc*HIDDIM) return;
  int el = t >> 7, h = t & 127;
  int g = off + el;
  int j = ei[g], i = ei[E+g];
  float val = slin[(size_t)j*HIDDIM + h] * rhid[t];
  float e0 = edb[3*el], e1 = edb[3*el+1], e2 = edb[3*el+2];
  float* base = &S[(size_t)i*384 + h];
  atomicAdd(base,        val*e0);
  atomicAdd(base + 128,  val*e1);
  atomicAdd(base + 256,  val*e2);
}

__global__ void k_seg3(const int* __restrict__ ei, int E, int off, int Cc,
                       const float* __restrict__ m, const float* __restrict__ edb,
                       float* __restrict__ s, float* __restrict__ vecacc)
{
  int t = blockIdx.x*blockDim.x + threadIdx.x;
  if (t >= Cc*HIDDIM) return;
  int el = t >> 7, h = t & 127;
  int g = off + el;
  int i = ei[E+g];
  float m1 = m[(size_t)el*384 + h];
  float m3 = m[(size_t)el*384 + 256 + h];
  atomicAdd(&s[(size_t)i*HIDDIM + h], m1);
  const float is128 = 0.08838834764831845f; // 1/sqrt(128)
  float mm = m3 * is128;
  float* base = &vecacc[(size_t)i*384 + h];
  atomicAdd(base,       mm*edb[3*el]);
  atomicAdd(base + 128, mm*edb[3*el+1]);
  atomicAdd(base + 256, mm*edb[3*el+2]);
}

// ---------------- scalarize + ew assembly (chunk-local) ----------------
__global__ __launch_bounds__(128) void k_scalarize(
  const int* __restrict__ ei, int E, int off,
  const float* __restrict__ S, const float* __restrict__ edb, const float* __restrict__ ecv,
  const float* __restrict__ rb, const float* __restrict__ rhid, const float* __restrict__ remb,
  const float* __restrict__ w1, const float* __restrict__ b1,
  const float* __restrict__ w2, const float* __restrict__ b2,
  float* __restrict__ ew)
{
  int el = blockIdx.x;
  int which = blockIdx.y;     // 0 -> S[i] (scalar3), 1 -> S[j] (scalar4)
  int h = threadIdx.x;
  int g = off + el;
  int n = (which == 0) ? ei[E+g] : ei[g];
  float f00 = edb[3*el], f01 = edb[3*el+1], f02 = edb[3*el+2];
  float f10 = ecv[6*el], f11 = ecv[6*el+1], f12 = ecv[6*el+2];
  float f20 = ecv[6*el+3], f21 = ecv[6*el+4], f22 = ecv[6*el+5];
  const float* Sn = &S[(size_t)n*384];
  float S0 = Sn[h], S1 = Sn[128+h], S2 = Sn[256+h];
  float v0 = S0*f00 + S1*f01 + S2*f02;
  float v1 = fabsf(S0*f10 + S1*f11 + S2*f12);
  float v2 = S0*f20 + S1*f21 + S2*f22;
  float out = b2[0];
  #pragma unroll
  for (int u = 0; u < 32; ++u){
    float t = v0*w1[u] + v1*w1[32+u] + v2*w1[64+u] + b1[u];
    t = silu_f(t);
    out += t * w2[u];
  }
  float scal = out + v0;
  float* ewr = &ew[(size_t)el*480];
  ewr[which*128 + h] = scal * rb[el];
  if (which == 0){
    ewr[256 + h] = rhid[(size_t)el*HIDDIM + h];
    if (h < NRAD) ewr[384 + h] = remb[(size_t)el*NRAD + h];
  }
}

// ---------------- generic tiled fp32 GEMM: C = epi(A@B + bias) ----------------
// A: MxK row-major, B: KxN row-major, N%64==0, K%16==0
// epi: 0 none, 1 silu, 2 *rowscale[row], 3 *mul1[row,col]*xhp[jidx[row],col]
// NOTE: C must not alias mul1/xhp/A/B.
__global__ __launch_bounds__(256) void gemm_k(
  const float* __restrict__ A, const float* __restrict__ B,
  const float* __restrict__ bias, float* __restrict__ C,
  int M, int N, int K, int epi,
  const float* __restrict__ rowscale,
  const float* __restrict__ mul1,
  const float* __restrict__ xhp,
  const int* __restrict__ jidx)
{
  __shared__ float As[16][68];
  __shared__ float Bs[16][68];
  const int tid = threadIdx.x;
  const int tx = tid & 15, ty = tid >> 4;
  const int rowBase = blockIdx.y * 64;
  const int colBase = blockIdx.x * 64;
  const int ar = tid >> 2;
  const int ak = (tid & 3) << 2;
  const int br = tid >> 4;
  const int bc = (tid & 15) << 2;
  float acc[4][4] = {};
  for (int k0 = 0; k0 < K; k0 += 16){
    float4 av = make_float4(0.f, 0.f, 0.f, 0.f);
    if (rowBase + ar < M)
      av = *(const float4*)(A + (size_t)(rowBase + ar)*K + k0 + ak);
    As[ak][ar] = av.x; As[ak+1][ar] = av.y; As[ak+2][ar] = av.z; As[ak+3][ar] = av.w;
    float4 bv = *(const float4*)(B + (size_t)(k0 + br)*N + colBase + bc);
    *(float4*)&Bs[br][bc] = bv;
    __syncthreads();
    #pragma unroll
    for (int k = 0; k < 16; ++k){
      float a0 = As[k][ty], a1 = As[k][ty+16], a2 = As[k][ty+32], a3 = As[k][ty+48];
      float b0 = Bs[k][tx], b1 = Bs[k][tx+16], b2 = Bs[k][tx+32], b3 = Bs[k][tx+48];
      acc[0][0] += a0*b0; acc[0][1] += a0*b1; acc[0][2] += a0*b2; acc[0][3] += a0*b3;
      acc[1][0] += a1*b0; acc[1][1] += a1*b1; acc[1][2] += a1*b2; acc[1][3] += a1*b3;
      acc[2][0] += a2*b0; acc[2][1] += a2*b1; acc[2][2] += a2*b2; acc[2][3] += a2*b3;
      acc[3][0] += a3*b0; acc[3][1] += a3*b1; acc[3][2] += a3*b2; acc[3][3] += a3*b3;
    }
    __syncthreads();
  }
  #pragma unroll
  for (int ii = 0; ii < 4; ++ii){
    int row = rowBase + ty + 16*ii;
    if (row >= M) continue;
    #pragma unroll
    for (int jj = 0; jj < 4; ++jj){
      int col = colBase + tx + 16*jj;
      float x = acc[ii][jj] + (bias ? bias[col] : 0.f);
      if (epi == 1) x = silu_f(x);
      else if (epi == 2) x *= rowscale[row];
      else if (epi == 3) x = x * mul1[(size_t)row*N + col] * xhp[(size_t)jidx[row]*N + col];
      C[(size_t)row*N + col] = x;
    }
  }
}

// ---------------- fte prep (node-chunked): scalar, vec_dot, cat ----------------
__global__ __launch_bounds__(128) void k_fte_pre(const float* __restrict__ vpc,
    const float* __restrict__ s, float* __restrict__ cat, float* __restrict__ vdot,
    int no)
{
  int nl = blockIdx.x, h = threadIdx.x;
  int n = no + nl;
  const float* base = &vpc[(size_t)nl*768];
  float a0 = base[h],       a1 = base[256+h],     a2 = base[512+h];
  float c0 = base[128+h],   c1 = base[384+h],     c2 = base[640+h];
  float scal = sqrtf(a0*a0 + a1*a1 + a2*a2 + 1e-10f);
  float vd = (a0*c0 + a1*c1 + a2*c2) * 0.08838834764831845f;  // /sqrt(128)
  cat[(size_t)n*256 + h] = s[(size_t)n*HIDDIM + h];
  cat[(size_t)n*256 + 128 + h] = scal;
  vdot[(size_t)n*HIDDIM + h] = vd;
}

// ---------------- final node update + per-node output ----------------
__global__ __launch_bounds__(128) void k_out(const float* __restrict__ xh2,
    const float* __restrict__ vdot, const float* __restrict__ s,
    const float* __restrict__ ow, const float* __restrict__ ob,
    float* __restrict__ nodeout, int Nn)
{
  int n = blockIdx.x, h = threadIdx.x;
  float a1 = xh2[(size_t)n*384 + h];
  float a2 = xh2[(size_t)n*384 + 128 + h];
  float sv = s[(size_t)n*HIDDIM + h] + (a1 + a2*vdot[(size_t)n*HIDDIM + h]) * 0.7071067811865476f;
  __shared__ float red[128];
  red[h] = sv * ow[h];
  __syncthreads();
  for (int o = 64; o > 0; o >>= 1){ if (h < o) red[h] += red[h+o]; __syncthreads(); }
  if (h == 0) nodeout[n] = red[0] + ob[0];
}

__global__ __launch_bounds__(256) void k_final(const float* __restrict__ nodeout,
    const int* __restrict__ batch, void* __restrict__ out, int Nn, const int* flags)
{
  int g = blockIdx.x;
  __shared__ float rs[256], rc[256];
  float sm = 0.f, c = 0.f;
  for (int n = threadIdx.x; n < Nn; n += 256){
    if (batch[n] == g){ sm += nodeout[n]; c += 1.f; }
  }
  rs[threadIdx.x] = sm; rc[threadIdx.x] = c;
  __syncthreads();
  for (int o = 128; o > 0; o >>= 1){
    if (threadIdx.x < o){ rs[threadIdx.x] += rs[threadIdx.x+o]; rc[threadIdx.x] += rc[threadIdx.x+o]; }
    __syncthreads();
  }
  if (threadIdx.x == 0){
    float v = (rc[0] > 0.f) ? rs[0]/rc[0] : 0.f;
    if (flags[0]) ((__hip_bfloat16*)out)[g] = __float2bfloat16(v);
    else ((float*)out)[g] = v;
  }
}

// =====================================================================
extern "C" void kernel_launch(void* const* d_in, const int* in_sizes, int n_in,
                              void* d_out, int out_size, void* d_ws, size_t ws_size,
                              hipStream_t stream)
{
  const int N = in_sizes[0] / 3;
  const int E = in_sizes[3] / 2;

  size_t off = 0;
  auto alloc = [&](size_t n)->float*{
    float* p = (float*)d_ws + off;
    off += (n + 3) & ~(size_t)3;
    return p;
  };

  int* flags = (int*)alloc(4);
  int* zi    = (int*)alloc((size_t)N);
  int* bi    = (int*)alloc((size_t)N);
  int* eii   = (int*)alloc((size_t)2*E);

  float* pos = alloc((size_t)N*3);
  float* w[31];
  for (int t = 0; t < 31; ++t) w[t] = alloc((size_t)in_sizes[4+t]);
  float* rl_w1=w[0];  float* rl_b1=w[1];  float* rl_w2=w[2];  float* rl_b2=w[3];
  float* ne_w =w[4];  float* ne_b =w[5];  float* sv_w =w[6];  float* sv_b =w[7];
  float* l3_w1=w[8];  float* l3_b1=w[9];  float* l3_w2=w[10]; float* l3_b2=w[11];
  float* mp_w =w[12]; float* mp_b =w[13]; float* xp_w1=w[14]; float* xp_b1=w[15];
  float* xp_w2=w[16]; float* xp_b2=w[17]; float* rp_w =w[18]; float* rp_b =w[19];
  float* ip_w1=w[20]; float* ip_b1=w[21]; float* ip_w2=w[22]; float* ip_b2=w[23];
  float* fte_eq=w[24];float* fte_w1=w[25];float* fte_b1=w[26];float* fte_w2=w[27];
  float* fte_b2=w[28];float* out_w=w[29]; float* out_b=w[30];

  // persistent node arrays (with overlays)
  float* s    = alloc((size_t)N*HIDDIM);
  float* h0   = alloc((size_t)N*HIDDIM);   // dead after seg1 -> reused as cat (with slin)
  float* slin = alloc((size_t)N*HIDDIM);   // adjacent to h0; dead after seg2
  float* xln  = alloc((size_t)N*HIDDIM);
  float* hbuf = alloc((size_t)N*HIDDIM);
  float* S    = alloc((size_t)N*384);      // dead after scalarize -> reused as xh2
  float* vecacc = alloc((size_t)N*384);    // contiguous with S for zeroing
  float* xh   = alloc((size_t)N*384);
  float* vdot = alloc((size_t)N*HIDDIM);
  float* nodeout = alloc((size_t)N);
  float* cat  = h0;       // N*256 overlay on h0+slin
  float* xh2  = S;        // N*384 overlay on S

  // ---- chunk scratch: 1482 floats per edge ----
  size_t avail = (ws_size / sizeof(float) > off) ? (ws_size / sizeof(float) - off) : 0;
  int C = 8192;
  while (C >= 64 && (size_t)C*1482 > avail) C >>= 1;
  if (C < 64){
    k_sentinel<<<1, 64, 0, stream>>>((__hip_bfloat16*)d_out, out_size,
                                     (float)(double)(ws_size >> 20));
    return;
  }
  float* scratch = alloc((size_t)C*1482);
  float* edb  = scratch;                    // 3C
  float* ecv  = edb  + (size_t)3*C;         // 6C
  float* rb   = ecv  + (size_t)6*C;         // C
  float* remb = rb   + (size_t)C;           // 96C
  float* rhid = remb + (size_t)96*C;        // 128C
  float* ew   = rhid + (size_t)128*C;       // 480C  (also reused as epi3 output)
  float* R1   = ew   + (size_t)480*C;       // 384C
  float* R2   = R1   + (size_t)384*C;       // 384C
  float* vpc  = scratch;                    // 768C overlay (phase F)

  auto gemm = [&](const float* A, const float* B, const float* bias, float* Cp,
                  int M, int Nc, int K, int epi,
                  const float* rowscale = nullptr, const float* mul1 = nullptr,
                  const float* xhp = nullptr, const int* jidx = nullptr){
    dim3 grid(Nc/64, (M + 63)/64);
    gemm_k<<<grid, 256, 0, stream>>>(A, B, bias, Cp, M, Nc, K, epi, rowscale, mul1, xhp, jidx);
  };
  auto geom_rl = [&](int o, int Cc){
    k_geom<<<(Cc + 255)/256, 256, 0, stream>>>(pos, eii, E, o, Cc, edb, ecv, rb, remb);
    gemm(remb, rl_w1, rl_b1, R2, Cc, 128, 96, 1);
    gemm(R2, rl_w2, rl_b2, rhid, Cc, 128, 128, 2, rb);
  };

  // 0) detect dtypes, normalize ints
  k_detect<<<1, 256, 0, stream>>>((const unsigned short*)d_in[0], in_sizes[0],
                                  (const int*)d_in[2], in_sizes[2], flags);
  k_iconv<<<1024, 256, 0, stream>>>((const int*)d_in[1], (const int*)d_in[2],
                                    (const int*)d_in[3], zi, bi, eii, N, 2*E, flags);

  // 1) convert all float inputs to f32
  ConvArgs ca;
  ca.d[0] = { (const unsigned short*)d_in[0], pos, in_sizes[0] };
  for (int t = 0; t < 31; ++t)
    ca.d[1+t] = { (const unsigned short*)d_in[4+t], w[t], in_sizes[4+t] };
  k_conv<<<dim3(64, 32), 256, 0, stream>>>(ca, 32, flags);

  // 2) zero accumulators (S and vecacc are contiguous)
  k_zero<<<2048, 256, 0, stream>>>(S, N*384*2);

  // 3) node embedding + LN -> s (=h0 copy)
  k_embed<<<N, 128, 0, stream>>>(zi, ne_w, ne_b, s, h0, N);

  // Phase B: s += segsum(h0[j]*r_hid -> i), chunked
  for (int o = 0; o < E; o += C){
    int Cc = (E - o < C) ? (E - o) : C;
    geom_rl(o, Cc);
    k_seg1<<<((size_t)Cc*128 + 255)/256, 256, 0, stream>>>(eii, E, o, Cc, h0, rhid, s);
  }

  // Phase C: slin, xln, xh (all from post-seg1 s)
  gemm(s, sv_w, sv_b, slin, N, 128, 128, 1);
  k_ln<<<N, 128, 0, stream>>>(s, xln, mp_w, mp_b, N);
  gemm(xln, xp_w1, xp_b1, hbuf, N, 128, 128, 1);
  gemm(hbuf, xp_w2, xp_b2, xh, N, 384, 128, 0);

  // Phase D: S[i,d,h] += s_lin[j,h]*r_hid[e,h]*ed[e,d], chunked
  for (int o = 0; o < E; o += C){
    int Cc = (E - o < C) ? (E - o) : C;
    geom_rl(o, Cc);
    k_seg2<<<((size_t)Cc*128 + 255)/256, 256, 0, stream>>>(eii, E, o, Cc, slin, rhid, edb, S);
  }

  // Phase E: per-edge big MLPs + seg3, chunked
  for (int o = 0; o < E; o += C){
    int Cc = (E - o < C) ? (E - o) : C;
    geom_rl(o, Cc);
    k_scalarize<<<dim3(Cc, 2), 128, 0, stream>>>(eii, E, o, S, edb, ecv, rb, rhid, remb,
                                                 l3_w1, l3_b1, l3_w2, l3_b2, ew);
    gemm(remb, rp_w, rp_b, R1, Cc, 384, 96, 0);
    gemm(ew, ip_w1, ip_b1, R2, Cc, 384, 480, 1);          // ew dead after this
    gemm(R2, ip_w2, ip_b2, ew, Cc, 384, 384, 3, nullptr, R1, xh, eii + o);  // m -> ew
    k_seg3<<<((size_t)Cc*128 + 255)/256, 256, 0, stream>>>(eii, E, o, Cc, ew, edb, s, vecacc);
  }

  // Phase F: fte, node-chunked vp then full-N MLP
  int Cn = (int)((size_t)C*1482 / 768);
  if (Cn > N) Cn = N;
  for (int no = 0; no < N; no += Cn){
    int Cc = (N - no < Cn) ? (N - no) : Cn;
    gemm(vecacc + (size_t)no*384, fte_eq, nullptr, vpc, 3*Cc, 256, 128, 0);
    k_fte_pre<<<Cc, 128, 0, stream>>>(vpc, s, cat, vdot, no);
  }
  gemm(cat, fte_w1, fte_b1, hbuf, N, 128, 256, 1);
  gemm(hbuf, fte_w2, fte_b2, xh2, N, 384, 128, 0);

  // Phase G: final update + per-graph mean
  k_out<<<N, 128, 0, stream>>>(xh2, vdot, s, out_w, out_b, nodeout, N);
  k_final<<<out_size, 256, 0, stream>>>(nodeout, bi, d_out, N, flags);
}

// Round 4
// 5079.240 us; speedup vs baseline: 1.5472x; 1.5472x over previous
//
#include <hip/hip_runtime.h>
#include <hip/hip_bf16.h>
#include <math.h>

#define NRAD 96
#define HIDDIM 128
typedef unsigned short ushortT;

typedef __attribute__((ext_vector_type(8))) short bf8_t;   // 8 bf16 (4 VGPRs)
typedef __attribute__((ext_vector_type(4))) float f4_t;    // 4 fp32 acc

__device__ __forceinline__ float silu_f(float x){ return x / (1.f + __expf(-x)); }
__device__ __forceinline__ float b2f(ushortT u){ return __uint_as_float(((unsigned int)u) << 16); }
__device__ __forceinline__ ushortT f2b(float x){
  unsigned int u = __float_as_uint(x);
  unsigned int r = (u + 0x7fffu + ((u >> 16) & 1u)) >> 16;
  return (ushortT)r;
}

// ---------------- dtype detection ----------------
__global__ void k_detect(const ushortT* posw, int npos,
                         const int* batchw, int nb, int* flags){
  __shared__ int bad, orv;
  if (threadIdx.x == 0){ bad = 0; orv = 0; }
  __syncthreads();
  int nscan = npos < 4096 ? npos : 4096;
  for (int t = threadIdx.x; t < nscan; t += 256){
    float x = b2f(posw[t]);
    if (!(fabsf(x) <= 1000.f)) atomicOr(&bad, 1);
  }
  for (int t = threadIdx.x; t < nb; t += 256){
    if (t & 1) atomicOr(&orv, batchw[t]);
  }
  __syncthreads();
  if (threadIdx.x == 0){ flags[0] = bad ? 0 : 1; flags[1] = orv ? 0 : 1; }
}

__global__ void k_iconv(const int* zsrc, const int* bsrc, const int* esrc,
                        int* zi, int* bi, int* eii, int Nn, int E2, const int* flags){
  int f = flags[1];
  int total = 2*Nn + E2;
  for (int t = blockIdx.x*blockDim.x + threadIdx.x; t < total; t += gridDim.x*blockDim.x){
    if (t < Nn) zi[t] = zsrc[(size_t)t << f];
    else if (t < 2*Nn) bi[t-Nn] = bsrc[(size_t)(t-Nn) << f];
    else eii[t-2*Nn] = esrc[(size_t)(t-2*Nn) << f];
  }
}

// ---------------- conversion: (bf16|f32) -> f32 ----------------
struct ConvDesc { const ushortT* src; float* dst; int n; };
struct ConvArgs { ConvDesc d[32]; };

__global__ void k_conv(ConvArgs a, int cnt, const int* flags){
  int y = blockIdx.y;
  if (y >= cnt) return;
  int f = flags[0];
  const ushortT* s = a.d[y].src;
  float* dst = a.d[y].dst;
  int n = a.d[y].n;
  if (f){
    for (int t = blockIdx.x*blockDim.x + threadIdx.x; t < n; t += gridDim.x*blockDim.x)
      dst[t] = b2f(s[t]);
  } else {
    const float* sf = (const float*)s;
    for (int t = blockIdx.x*blockDim.x + threadIdx.x; t < n; t += gridDim.x*blockDim.x)
      dst[t] = sf[t];
  }
}

// ---------------- weight transpose -> bf16 [N][K] ----------------
struct TDesc { const ushortT* src; ushortT* dst; int K, N; };
struct TArgs { TDesc d[12]; };

__global__ void k_wt(TArgs a, int cnt, const int* flags){
  int y = blockIdx.y;
  if (y >= cnt) return;
  int f = flags[0];
  const ushortT* s = a.d[y].src;
  ushortT* dst = a.d[y].dst;
  int K = a.d[y].K, N = a.d[y].N, tot = K*N;
  for (int t = blockIdx.x*blockDim.x + threadIdx.x; t < tot; t += gridDim.x*blockDim.x){
    int k = t / N, n = t - k*N;
    ushortT v = f ? s[t] : f2b(((const float*)s)[t]);
    dst[(size_t)n*K + k] = v;
  }
}

__global__ void k_f2b(const float* __restrict__ src, ushortT* __restrict__ dst, int n){
  for (int t = blockIdx.x*blockDim.x + threadIdx.x; t < n; t += gridDim.x*blockDim.x)
    dst[t] = f2b(src[t]);
}

__global__ void k_zero(float* __restrict__ p, int n){
  int t = blockIdx.x*blockDim.x + threadIdx.x;
  int stride = gridDim.x*blockDim.x;
  for (; t < n; t += stride) p[t] = 0.f;
}

__global__ void k_sentinel(__hip_bfloat16* out, int n, float val){
  int t = threadIdx.x;
  if (t < n) out[t] = __float2bfloat16(val);
}

// ---------------- geometry + RBF ----------------
__global__ void k_geom(const float* __restrict__ pos, const int* __restrict__ ei,
                       int E, int off, int Cc,
                       float* __restrict__ edb, float* __restrict__ ecv,
                       float* __restrict__ rb, ushortT* __restrict__ remb)
{
  int el = blockIdx.x*blockDim.x + threadIdx.x;
  if (el >= Cc) return;
  int g = off + el;
  int j = ei[g], i = ei[E+g];
  float pjx = pos[3*j], pjy = pos[3*j+1], pjz = pos[3*j+2];
  float pix = pos[3*i], piy = pos[3*i+1], piz = pos[3*i+2];
  float vx = pjx-pix, vy = pjy-piy, vz = pjz-piz;
  float d = sqrtf(vx*vx + vy*vy + vz*vz);
  float inv = 1.f/(d + 1e-10f);
  float edx = vx*inv, edy = vy*inv, edz = vz*inv;
  float cx = piy*pjz - piz*pjy;
  float cy = piz*pjx - pix*pjz;
  float cz = pix*pjy - piy*pjx;
  float cn = sqrtf(cx*cx + cy*cy + cz*cz);
  float inv2 = 1.f/(cn + 1e-10f);
  cx *= inv2; cy *= inv2; cz *= inv2;
  float evx = edy*cz - edz*cy;
  float evy = edz*cx - edx*cz;
  float evz = edx*cy - edy*cx;
  edb[3*el]=edx; edb[3*el+1]=edy; edb[3*el+2]=edz;
  ecv[6*el]=cx; ecv[6*el+1]=cy; ecv[6*el+2]=cz;
  ecv[6*el+3]=evx; ecv[6*el+4]=evy; ecv[6*el+5]=evz;
  float rbv = 0.5f*(cosf(d*0.52359877559829887f) + 1.f);
  rb[el] = rbv;
  float env = (d < 6.f) ? rbv : 0.f;
  const double st = 0.0024787521766663585;      // exp(-6)
  const double pr = (2.0/96.0)*(1.0 - st);
  float beta = (float)(1.0/(pr*pr));
  float emd = expf(-d);
  for (int k = 0; k < NRAD; ++k){
    float mu = (float)(st + (1.0 - st)*((double)k/95.0));
    float t = emd - mu;
    remb[(size_t)el*NRAD + k] = f2b(env * expf(-beta*t*t));
  }
}

// ---------------- node embedding + layernorm ----------------
__global__ __launch_bounds__(128) void k_embed(const int* __restrict__ z,
    const float* __restrict__ ne_w, const float* __restrict__ ne_b,
    float* __restrict__ s, float* __restrict__ h0, int Nn)
{
  int n = blockIdx.x; int h = threadIdx.x;
  float x = ne_w[(size_t)z[n]*HIDDIM + h] + ne_b[h];
  __shared__ float red[128];
  red[h] = x; __syncthreads();
  for (int o = 64; o > 0; o >>= 1){ if (h < o) red[h] += red[h+o]; __syncthreads(); }
  float mean = red[0] * (1.f/128.f);
  __syncthreads();
  float dx = x - mean;
  red[h] = dx*dx; __syncthreads();
  for (int o = 64; o > 0; o >>= 1){ if (h < o) red[h] += red[h+o]; __syncthreads(); }
  float var = red[0] * (1.f/128.f);
  float y = dx * rsqrtf(var + 1e-5f);
  s[(size_t)n*HIDDIM + h] = y;
  h0[(size_t)n*HIDDIM + h] = y;
}

__global__ __launch_bounds__(128) void k_ln(const float* __restrict__ src, ushortT* __restrict__ dst,
    const float* __restrict__ g, const float* __restrict__ b)
{
  int n = blockIdx.x; int h = threadIdx.x;
  float x = src[(size_t)n*HIDDIM + h];
  __shared__ float red[128];
  red[h] = x; __syncthreads();
  for (int o = 64; o > 0; o >>= 1){ if (h < o) red[h] += red[h+o]; __syncthreads(); }
  float mean = red[0] * (1.f/128.f);
  __syncthreads();
  float dx = x - mean;
  red[h] = dx*dx; __syncthreads();
  for (int o = 64; o > 0; o >>= 1){ if (h < o) red[h] += red[h+o]; __syncthreads(); }
  float var = red[0] * (1.f/128.f);
  float y = dx * rsqrtf(var + 1e-5f);
  dst[(size_t)n*HIDDIM + h] = f2b(y * g[h] + b[h]);
}

// ---------------- segment sums (atomics) ----------------
__global__ void k_seg1(const int* __restrict__ ei, int E, int off, int Cc,
                       const float* __restrict__ h0,
                       const ushortT* __restrict__ rhid, float* __restrict__ s)
{
  int t = blockIdx.x*blockDim.x + threadIdx.x;
  if (t >= Cc*HIDDIM) return;
  int el = t >> 7, h = t & 127;
  int g = off + el;
  int j = ei[g], i = ei[E+g];
  atomicAdd(&s[(size_t)i*HIDDIM + h], h0[(size_t)j*HIDDIM + h] * b2f(rhid[t]));
}

__global__ void k_seg2(const int* __restrict__ ei, int E, int off, int Cc,
                       const ushortT* __restrict__ slin,
                       const ushortT* __restrict__ rhid, const float* __restrict__ edb,
                       float* __restrict__ S)
{
  int t = blockIdx.x*blockDim.x + threadIdx.x;
  if (t >= Cc*HIDDIM) return;
  int el = t >> 7, h = t & 127;
  int g = off + el;
  int j = ei[g], i = ei[E+g];
  float val = b2f(slin[(size_t)j*HIDDIM + h]) * b2f(rhid[t]);
  float e0 = edb[3*el], e1 = edb[3*el+1], e2 = edb[3*el+2];
  float* base = &S[(size_t)i*384 + h];
  atomicAdd(base,        val*e0);
  atomicAdd(base + 128,  val*e1);
  atomicAdd(base + 256,  val*e2);
}

__global__ void k_seg3(const int* __restrict__ ei, int E, int off, int Cc,
                       const float* __restrict__ m, const float* __restrict__ edb,
                       float* __restrict__ s, float* __restrict__ vecacc)
{
  int t = blockIdx.x*blockDim.x + threadIdx.x;
  if (t >= Cc*HIDDIM) return;
  int el = t >> 7, h = t & 127;
  int g = off + el;
  int i = ei[E+g];
  float m1 = m[(size_t)el*384 + h];
  float m3 = m[(size_t)el*384 + 256 + h];
  atomicAdd(&s[(size_t)i*HIDDIM + h], m1);
  const float is128 = 0.08838834764831845f;
  float mm = m3 * is128;
  float* base = &vecacc[(size_t)i*384 + h];
  atomicAdd(base,       mm*edb[3*el]);
  atomicAdd(base + 128, mm*edb[3*el+1]);
  atomicAdd(base + 256, mm*edb[3*el+2]);
}

// ---------------- scalarize + ew assembly ----------------
__global__ __launch_bounds__(128) void k_scalarize(
  const int* __restrict__ ei, int E, int off,
  const float* __restrict__ S, const float* __restrict__ edb, const float* __restrict__ ecv,
  const float* __restrict__ rb, const ushortT* __restrict__ rhid, const ushortT* __restrict__ remb,
  const float* __restrict__ w1, const float* __restrict__ b1,
  const float* __restrict__ w2, const float* __restrict__ b2,
  ushortT* __restrict__ ew)
{
  int el = blockIdx.x;
  int which = blockIdx.y;
  int h = threadIdx.x;
  int g = off + el;
  int n = (which == 0) ? ei[E+g] : ei[g];
  float f00 = edb[3*el], f01 = edb[3*el+1], f02 = edb[3*el+2];
  float f10 = ecv[6*el], f11 = ecv[6*el+1], f12 = ecv[6*el+2];
  float f20 = ecv[6*el+3], f21 = ecv[6*el+4], f22 = ecv[6*el+5];
  const float* Sn = &S[(size_t)n*384];
  float S0 = Sn[h], S1 = Sn[128+h], S2 = Sn[256+h];
  float v0 = S0*f00 + S1*f01 + S2*f02;
  float v1 = fabsf(S0*f10 + S1*f11 + S2*f12);
  float v2 = S0*f20 + S1*f21 + S2*f22;
  float out = b2[0];
  #pragma unroll
  for (int u = 0; u < 32; ++u){
    float t = v0*w1[u] + v1*w1[32+u] + v2*w1[64+u] + b1[u];
    t = silu_f(t);
    out += t * w2[u];
  }
  float scal = out + v0;
  ushortT* ewr = &ew[(size_t)el*480];
  ewr[which*128 + h] = f2b(scal * rb[el]);
  if (which == 0){
    ewr[256 + h] = rhid[(size_t)el*HIDDIM + h];
    if (h < NRAD) ewr[384 + h] = remb[(size_t)el*NRAD + h];
  }
}

// ---------------- bf16 MFMA GEMM ----------------
// A: MxK bf16 row-major; BT: NxK bf16 row-major. N%128==0, K%32==0.
// epi: 0 none, 1 silu, 2 *rowscale[row], 3 *mul1[row,col]*xhp[jidx[row],col]
__global__ __launch_bounds__(256) void mgemm(
  const ushortT* __restrict__ A, const ushortT* __restrict__ BT,
  const float* __restrict__ bias,
  float* __restrict__ Cf, ushortT* __restrict__ Cb,
  int M, int N, int K, int epi,
  const float* __restrict__ rowscale,
  const float* __restrict__ mul1,
  const float* __restrict__ xhp,
  const int* __restrict__ jidx)
{
  __shared__ short As[128*48];
  __shared__ short Bs[128*48];
  const int tid = threadIdx.x;
  const int w = tid >> 6;
  const int lane = tid & 63;
  const int l15 = lane & 15;
  const int q = lane >> 4;
  const int wm = w & 1, wn = w >> 1;
  const int rowBase = blockIdx.y * 128;
  const int colBase = blockIdx.x * 128;

  const int r0 = tid >> 2,         s0 = (tid & 3) << 3;
  const int r1 = (tid + 256) >> 2, s1 = ((tid + 256) & 3) << 3;

  f4_t acc[4][4] = {};

  for (int k0 = 0; k0 < K; k0 += 32){
    int4 a0v = make_int4(0,0,0,0), a1v = make_int4(0,0,0,0);
    if (rowBase + r0 < M) a0v = *(const int4*)&A[(size_t)(rowBase + r0)*K + k0 + s0];
    if (rowBase + r1 < M) a1v = *(const int4*)&A[(size_t)(rowBase + r1)*K + k0 + s1];
    int4 b0v = *(const int4*)&BT[(size_t)(colBase + r0)*K + k0 + s0];
    int4 b1v = *(const int4*)&BT[(size_t)(colBase + r1)*K + k0 + s1];
    __syncthreads();
    *(int4*)&As[r0*48 + s0] = a0v;
    *(int4*)&As[r1*48 + s1] = a1v;
    *(int4*)&Bs[r0*48 + s0] = b0v;
    *(int4*)&Bs[r1*48 + s1] = b1v;
    __syncthreads();
    bf8_t a[4], b[4];
    #pragma unroll
    for (int mt = 0; mt < 4; ++mt)
      a[mt] = *(const bf8_t*)&As[(wm*64 + mt*16 + l15)*48 + q*8];
    #pragma unroll
    for (int nt = 0; nt < 4; ++nt)
      b[nt] = *(const bf8_t*)&Bs[(wn*64 + nt*16 + l15)*48 + q*8];
    #pragma unroll
    for (int mt = 0; mt < 4; ++mt){
      #pragma unroll
      for (int nt = 0; nt < 4; ++nt)
        acc[mt][nt] = __builtin_amdgcn_mfma_f32_16x16x32_bf16(a[mt], b[nt], acc[mt][nt], 0, 0, 0);
    }
  }

  #pragma unroll
  for (int mt = 0; mt < 4; ++mt){
    int row = rowBase + wm*64 + mt*16 + q*4;
    #pragma unroll
    for (int nt = 0; nt < 4; ++nt){
      int col = colBase + wn*64 + nt*16 + l15;
      float bv = bias ? bias[col] : 0.f;
      #pragma unroll
      for (int r = 0; r < 4; ++r){
        int rr = row + r;
        if (rr >= M) continue;
        float x = acc[mt][nt][r] + bv;
        if (epi == 1) x = silu_f(x);
        else if (epi == 2) x *= rowscale[rr];
        else if (epi == 3) x = x * mul1[(size_t)rr*N + col] * xhp[(size_t)jidx[rr]*N + col];
        if (Cb) Cb[(size_t)rr*N + col] = f2b(x);
        else    Cf[(size_t)rr*N + col] = x;
      }
    }
  }
}

// ---------------- fte prep ----------------
__global__ __launch_bounds__(128) void k_fte_pre(const float* __restrict__ vpc,
    const float* __restrict__ s, ushortT* __restrict__ catb, float* __restrict__ vdot,
    int no)
{
  int nl = blockIdx.x, h = threadIdx.x;
  int n = no + nl;
  const float* base = &vpc[(size_t)nl*768];
  float a0 = base[h],       a1 = base[256+h],     a2 = base[512+h];
  float c0 = base[128+h],   c1 = base[384+h],     c2 = base[640+h];
  float scal = sqrtf(a0*a0 + a1*a1 + a2*a2 + 1e-10f);
  float vd = (a0*c0 + a1*c1 + a2*c2) * 0.08838834764831845f;
  catb[(size_t)n*256 + h] = f2b(s[(size_t)n*HIDDIM + h]);
  catb[(size_t)n*256 + 128 + h] = f2b(scal);
  vdot[(size_t)n*HIDDIM + h] = vd;
}

// ---------------- final ----------------
__global__ __launch_bounds__(128) void k_out(const float* __restrict__ xh2,
    const float* __restrict__ vdot, const float* __restrict__ s,
    const float* __restrict__ ow, const float* __restrict__ ob,
    float* __restrict__ nodeout)
{
  int n = blockIdx.x, h = threadIdx.x;
  float a1 = xh2[(size_t)n*384 + h];
  float a2 = xh2[(size_t)n*384 + 128 + h];
  float sv = s[(size_t)n*HIDDIM + h] + (a1 + a2*vdot[(size_t)n*HIDDIM + h]) * 0.7071067811865476f;
  __shared__ float red[128];
  red[h] = sv * ow[h];
  __syncthreads();
  for (int o = 64; o > 0; o >>= 1){ if (h < o) red[h] += red[h+o]; __syncthreads(); }
  if (h == 0) nodeout[n] = red[0] + ob[0];
}

__global__ __launch_bounds__(256) void k_final(const float* __restrict__ nodeout,
    const int* __restrict__ batch, void* __restrict__ out, int Nn, const int* flags)
{
  int g = blockIdx.x;
  __shared__ float rs[256], rc[256];
  float sm = 0.f, c = 0.f;
  for (int n = threadIdx.x; n < Nn; n += 256){
    if (batch[n] == g){ sm += nodeout[n]; c += 1.f; }
  }
  rs[threadIdx.x] = sm; rc[threadIdx.x] = c;
  __syncthreads();
  for (int o = 128; o > 0; o >>= 1){
    if (threadIdx.x < o){ rs[threadIdx.x] += rs[threadIdx.x+o]; rc[threadIdx.x] += rc[threadIdx.x+o]; }
    __syncthreads();
  }
  if (threadIdx.x == 0){
    float v = (rc[0] > 0.f) ? rs[0]/rc[0] : 0.f;
    if (flags[0]) ((__hip_bfloat16*)out)[g] = __float2bfloat16(v);
    else ((float*)out)[g] = v;
  }
}

// =====================================================================
extern "C" void kernel_launch(void* const* d_in, const int* in_sizes, int n_in,
                              void* d_out, int out_size, void* d_ws, size_t ws_size,
                              hipStream_t stream)
{
  const int N = in_sizes[0] / 3;
  const int E = in_sizes[3] / 2;

  size_t off = 0;
  auto alloc = [&](size_t n)->float*{
    float* p = (float*)d_ws + off;
    off += (n + 3) & ~(size_t)3;
    return p;
  };
  auto allocU = [&](size_t n)->ushortT*{ return (ushortT*)alloc((n + 1) / 2); };

  int* flags = (int*)alloc(4);
  int* zi    = (int*)alloc((size_t)N);
  int* bi    = (int*)alloc((size_t)N);
  int* eii   = (int*)alloc((size_t)2*E);

  float* pos = alloc((size_t)N*3);
  float* w[31];
  for (int t = 0; t < 31; ++t) w[t] = alloc((size_t)in_sizes[4+t]);
  float* rl_b1=w[1];  float* rl_b2=w[3];
  float* ne_w =w[4];  float* ne_b =w[5];  float* sv_b =w[7];
  float* l3_w1=w[8];  float* l3_b1=w[9];  float* l3_w2=w[10]; float* l3_b2=w[11];
  float* mp_w =w[12]; float* mp_b =w[13]; float* xp_b1=w[15];
  float* xp_b2=w[17]; float* rp_b =w[19];
  float* ip_b1=w[21]; float* ip_b2=w[23];
  float* fte_b1=w[26];float* fte_b2=w[28];float* out_w=w[29]; float* out_b=w[30];

  ushortT* wt_rl1 = allocU(96*128);
  ushortT* wt_rl2 = allocU(128*128);
  ushortT* wt_sv  = allocU(128*128);
  ushortT* wt_xp1 = allocU(128*128);
  ushortT* wt_xp2 = allocU((size_t)128*384);
  ushortT* wt_rp  = allocU((size_t)96*384);
  ushortT* wt_ip1 = allocU((size_t)480*384);
  ushortT* wt_ip2 = allocU((size_t)384*384);
  ushortT* wt_feq = allocU((size_t)128*256);
  ushortT* wt_ft1 = allocU((size_t)256*128);
  ushortT* wt_ft2 = allocU((size_t)128*384);

  float* s    = alloc((size_t)N*HIDDIM);
  float* h0   = alloc((size_t)N*HIDDIM);      // dead after seg1 -> vdot overlay
  ushortT* sb     = allocU((size_t)N*HIDDIM);
  ushortT* slin_b = allocU((size_t)N*HIDDIM);
  ushortT* xln_b  = allocU((size_t)N*HIDDIM);
  ushortT* hb     = allocU((size_t)N*HIDDIM);
  float* S    = alloc((size_t)N*384);         // dead after scalarize -> xh2 overlay
  float* vecacc = alloc((size_t)N*384);       // contiguous with S for zeroing
  float* xh   = alloc((size_t)N*384);
  ushortT* vab  = allocU((size_t)N*384);
  ushortT* catb = allocU((size_t)N*256);
  float* nodeout = alloc((size_t)N);
  float* vdot = h0;
  float* xh2  = S;

  size_t wsF = ws_size / sizeof(float);
  size_t availF = (wsF > off) ? (wsF - off) : 0;
  size_t edgeP = (size_t)E*(3+6+1+48+64);
  bool persist = false; int C = 0;
  for (int c = 32768; c >= 1024; c >>= 1)
    if (edgeP + (size_t)c*1200 + 64 <= availF){ persist = true; C = c; break; }
  if (!persist)
    for (int c = 32768; c >= 256; c >>= 1)
      if ((size_t)c*1322 + 64 <= availF){ C = c; break; }
  if (C == 0){
    k_sentinel<<<1, 64, 0, stream>>>((__hip_bfloat16*)d_out, out_size,
                                     (float)(double)(ws_size >> 20));
    return;
  }

  float *edb_a=nullptr, *ecv_a=nullptr, *rb_a=nullptr;
  ushortT *remb_a=nullptr, *rhid_a=nullptr;
  if (persist){
    edb_a  = alloc((size_t)3*E);
    ecv_a  = alloc((size_t)6*E);
    rb_a   = alloc((size_t)E);
    remb_a = allocU((size_t)E*96);
    rhid_a = allocU((size_t)E*128);
  }
  float* scratch0 = (float*)d_ws + off;
  float *edb_l=nullptr, *ecv_l=nullptr, *rb_l=nullptr;
  ushortT *remb_l=nullptr, *rhid_l=nullptr;
  if (!persist){
    edb_l  = alloc((size_t)3*C);
    ecv_l  = alloc((size_t)6*C);
    rb_l   = alloc((size_t)C);
    remb_l = allocU((size_t)C*96);
    rhid_l = allocU((size_t)C*128);
  }
  ushortT* ew_b = allocU((size_t)C*480);
  ushortT* R2b  = allocU((size_t)C*384);
  float* R1 = alloc((size_t)C*384);
  float* Rm = alloc((size_t)C*384);
  float* vpc = scratch0;
  size_t scratchF = (size_t)C*(persist ? 1200 : 1322);

  auto mg = [&](const ushortT* A, const ushortT* BT, const float* bias,
                float* Cf, ushortT* Cb, int M, int Nc, int K, int epi,
                const float* rowscale = nullptr, const float* mul1 = nullptr,
                const float* xhp = nullptr, const int* jidx = nullptr){
    dim3 grid(Nc/128, (M + 127)/128);
    mgemm<<<grid, 256, 0, stream>>>(A, BT, bias, Cf, Cb, M, Nc, K, epi,
                                    rowscale, mul1, xhp, jidx);
  };
  auto rlchunk = [&](const ushortT* remb_p, const float* rb_p, ushortT* rhid_p, int Cc){
    mg(remb_p, wt_rl1, rl_b1, nullptr, R2b, Cc, 128, 96, 1);
    mg(R2b, wt_rl2, rl_b2, nullptr, rhid_p, Cc, 128, 128, 2, rb_p);
  };

  k_detect<<<1, 256, 0, stream>>>((const ushortT*)d_in[0], in_sizes[0],
                                  (const int*)d_in[2], in_sizes[2], flags);
  k_iconv<<<1024, 256, 0, stream>>>((const int*)d_in[1], (const int*)d_in[2],
                                    (const int*)d_in[3], zi, bi, eii, N, 2*E, flags);

  ConvArgs ca;
  ca.d[0] = { (const ushortT*)d_in[0], pos, in_sizes[0] };
  for (int t = 0; t < 31; ++t)
    ca.d[1+t] = { (const ushortT*)d_in[4+t], w[t], in_sizes[4+t] };
  k_conv<<<dim3(32, 32), 256, 0, stream>>>(ca, 32, flags);

  TArgs ta;
  ta.d[0]  = { (const ushortT*)d_in[4],  wt_rl1, 96, 128 };
  ta.d[1]  = { (const ushortT*)d_in[6],  wt_rl2, 128, 128 };
  ta.d[2]  = { (const ushortT*)d_in[10], wt_sv,  128, 128 };
  ta.d[3]  = { (const ushortT*)d_in[18], wt_xp1, 128, 128 };
  ta.d[4]  = { (const ushortT*)d_in[20], wt_xp2, 128, 384 };
  ta.d[5]  = { (const ushortT*)d_in[22], wt_rp,  96, 384 };
  ta.d[6]  = { (const ushortT*)d_in[24], wt_ip1, 480, 384 };
  ta.d[7]  = { (const ushortT*)d_in[26], wt_ip2, 384, 384 };
  ta.d[8]  = { (const ushortT*)d_in[28], wt_feq, 128, 256 };
  ta.d[9]  = { (const ushortT*)d_in[29], wt_ft1, 256, 128 };
  ta.d[10] = { (const ushortT*)d_in[31], wt_ft2, 128, 384 };
  k_wt<<<dim3(48, 11), 256, 0, stream>>>(ta, 11, flags);

  k_zero<<<2048, 256, 0, stream>>>(S, N*384*2);
  k_embed<<<N, 128, 0, stream>>>(zi, ne_w, ne_b, s, h0, N);

  if (persist){
    k_geom<<<(E + 255)/256, 256, 0, stream>>>(pos, eii, E, 0, E, edb_a, ecv_a, rb_a, remb_a);
    for (int o = 0; o < E; o += C){
      int Cc = (E - o < C) ? (E - o) : C;
      rlchunk(remb_a + (size_t)o*96, rb_a + o, rhid_a + (size_t)o*128, Cc);
    }
    k_seg1<<<((size_t)E*128 + 255)/256, 256, 0, stream>>>(eii, E, 0, E, h0, rhid_a, s);
  } else {
    for (int o = 0; o < E; o += C){
      int Cc = (E - o < C) ? (E - o) : C;
      k_geom<<<(Cc + 255)/256, 256, 0, stream>>>(pos, eii, E, o, Cc, edb_l, ecv_l, rb_l, remb_l);
      rlchunk(remb_l, rb_l, rhid_l, Cc);
      k_seg1<<<((size_t)Cc*128 + 255)/256, 256, 0, stream>>>(eii, E, o, Cc, h0, rhid_l, s);
    }
  }

  k_f2b<<<1024, 256, 0, stream>>>(s, sb, N*HIDDIM);
  mg(sb, wt_sv, sv_b, nullptr, slin_b, N, 128, 128, 1);
  k_ln<<<N, 128, 0, stream>>>(s, xln_b, mp_w, mp_b);
  mg(xln_b, wt_xp1, xp_b1, nullptr, hb, N, 128, 128, 1);
  mg(hb, wt_xp2, xp_b2, xh, nullptr, N, 384, 128, 0);

  if (persist){
    k_seg2<<<((size_t)E*128 + 255)/256, 256, 0, stream>>>(eii, E, 0, E, slin_b, rhid_a, edb_a, S);
  } else {
    for (int o = 0; o < E; o += C){
      int Cc = (E - o < C) ? (E - o) : C;
      k_geom<<<(Cc + 255)/256, 256, 0, stream>>>(pos, eii, E, o, Cc, edb_l, ecv_l, rb_l, remb_l);
      rlchunk(remb_l, rb_l, rhid_l, Cc);
      k_seg2<<<((size_t)Cc*128 + 255)/256, 256, 0, stream>>>(eii, E, o, Cc, slin_b, rhid_l, edb_l, S);
    }
  }

  for (int o = 0; o < E; o += C){
    int Cc = (E - o < C) ? (E - o) : C;
    const float *edb_p, *ecv_p, *rb_p; const ushortT *remb_p, *rhid_p;
    if (persist){
      edb_p = edb_a + (size_t)3*o; ecv_p = ecv_a + (size_t)6*o; rb_p = rb_a + o;
      remb_p = remb_a + (size_t)o*96; rhid_p = rhid_a + (size_t)o*128;
    } else {
      k_geom<<<(Cc + 255)/256, 256, 0, stream>>>(pos, eii, E, o, Cc, edb_l, ecv_l, rb_l, remb_l);
      rlchunk(remb_l, rb_l, rhid_l, Cc);
      edb_p = edb_l; ecv_p = ecv_l; rb_p = rb_l; remb_p = remb_l; rhid_p = rhid_l;
    }
    k_scalarize<<<dim3(Cc, 2), 128, 0, stream>>>(eii, E, o, S, edb_p, ecv_p, rb_p,
                                                 rhid_p, remb_p,
                                                 l3_w1, l3_b1, l3_w2, l3_b2, ew_b);
    mg(remb_p, wt_rp, rp_b, R1, nullptr, Cc, 384, 96, 0);
    mg(ew_b, wt_ip1, ip_b1, nullptr, R2b, Cc, 384, 480, 1);
    mg(R2b, wt_ip2, ip_b2, Rm, nullptr, Cc, 384, 384, 3, nullptr, R1, xh, eii + o);
    k_seg3<<<((size_t)Cc*128 + 255)/256, 256, 0, stream>>>(eii, E, o, Cc, Rm, edb_p, s, vecacc);
  }

  k_f2b<<<1024, 256, 0, stream>>>(vecacc, vab, N*384);
  int Cn = (int)(scratchF / 768);
  if (Cn > N) Cn = N;
  for (int no = 0; no < N; no += Cn){
    int Cc = (N - no < Cn) ? (N - no) : Cn;
    mg(vab + (size_t)no*384, wt_feq, nullptr, vpc, nullptr, 3*Cc, 256, 128, 0);
    k_fte_pre<<<Cc, 128, 0, stream>>>(vpc, s, catb, vdot, no);
  }
  mg(catb, wt_ft1, fte_b1, nullptr, hb, N, 128, 256, 1);
  mg(hb, wt_ft2, fte_b2, xh2, nullptr, N, 384, 128, 0);

  k_out<<<N, 128, 0, stream>>>(xh2, vdot, s, out_w, out_b, nodeout);
  k_final<<<out_size, 256, 0, stream>>>(nodeout, bi, d_out, N, flags);
}

// Round 5
// 3424.088 us; speedup vs baseline: 2.2951x; 1.4834x over previous
//
#include <hip/hip_runtime.h>
#include <hip/hip_bf16.h>
#include <math.h>

#define NRAD 96
#define HIDDIM 128
typedef unsigned short ushortT;

typedef __attribute__((ext_vector_type(8))) short bf8_t;   // 8 bf16 (4 VGPRs)
typedef __attribute__((ext_vector_type(4))) float f4_t;    // 4 fp32 acc

__device__ __forceinline__ float silu_f(float x){ return x / (1.f + __expf(-x)); }
__device__ __forceinline__ float b2f(ushortT u){ return __uint_as_float(((unsigned int)u) << 16); }
__device__ __forceinline__ ushortT f2b(float x){
  unsigned int u = __float_as_uint(x);
  unsigned int r = (u + 0x7fffu + ((u >> 16) & 1u)) >> 16;
  return (ushortT)r;
}

// ---------------- dtype detection ----------------
__global__ void k_detect(const ushortT* posw, int npos,
                         const int* batchw, int nb, int* flags){
  __shared__ int bad, orv;
  if (threadIdx.x == 0){ bad = 0; orv = 0; }
  __syncthreads();
  int nscan = npos < 4096 ? npos : 4096;
  for (int t = threadIdx.x; t < nscan; t += 256){
    float x = b2f(posw[t]);
    if (!(fabsf(x) <= 1000.f)) atomicOr(&bad, 1);
  }
  for (int t = threadIdx.x; t < nb; t += 256){
    if (t & 1) atomicOr(&orv, batchw[t]);
  }
  __syncthreads();
  if (threadIdx.x == 0){ flags[0] = bad ? 0 : 1; flags[1] = orv ? 0 : 1; }
}

__global__ void k_iconv(const int* zsrc, const int* bsrc, const int* esrc,
                        int* zi, int* bi, int* eii, int Nn, int E2, const int* flags){
  int f = flags[1];
  int total = 2*Nn + E2;
  for (int t = blockIdx.x*blockDim.x + threadIdx.x; t < total; t += gridDim.x*blockDim.x){
    if (t < Nn) zi[t] = zsrc[(size_t)t << f];
    else if (t < 2*Nn) bi[t-Nn] = bsrc[(size_t)(t-Nn) << f];
    else eii[t-2*Nn] = esrc[(size_t)(t-2*Nn) << f];
  }
}

// ---------------- conversion: (bf16|f32) -> f32 ----------------
struct ConvDesc { const ushortT* src; float* dst; int n; };
struct ConvArgs { ConvDesc d[32]; };

__global__ void k_conv(ConvArgs a, int cnt, const int* flags){
  int y = blockIdx.y;
  if (y >= cnt) return;
  int f = flags[0];
  const ushortT* s = a.d[y].src;
  float* dst = a.d[y].dst;
  int n = a.d[y].n;
  if (f){
    for (int t = blockIdx.x*blockDim.x + threadIdx.x; t < n; t += gridDim.x*blockDim.x)
      dst[t] = b2f(s[t]);
  } else {
    const float* sf = (const float*)s;
    for (int t = blockIdx.x*blockDim.x + threadIdx.x; t < n; t += gridDim.x*blockDim.x)
      dst[t] = sf[t];
  }
}

// ---------------- weight transpose -> bf16 [N][K] ----------------
struct TDesc { const ushortT* src; ushortT* dst; int K, N; };
struct TArgs { TDesc d[12]; };

__global__ void k_wt(TArgs a, int cnt, const int* flags){
  int y = blockIdx.y;
  if (y >= cnt) return;
  int f = flags[0];
  const ushortT* s = a.d[y].src;
  ushortT* dst = a.d[y].dst;
  int K = a.d[y].K, N = a.d[y].N, tot = K*N;
  for (int t = blockIdx.x*blockDim.x + threadIdx.x; t < tot; t += gridDim.x*blockDim.x){
    int k = t / N, n = t - k*N;
    ushortT v = f ? s[t] : f2b(((const float*)s)[t]);
    dst[(size_t)n*K + k] = v;
  }
}

__global__ void k_f2b(const float* __restrict__ src, ushortT* __restrict__ dst, int n){
  for (int t = blockIdx.x*blockDim.x + threadIdx.x; t < n; t += gridDim.x*blockDim.x)
    dst[t] = f2b(src[t]);
}

__global__ void k_zero(float* __restrict__ p, int n){
  int t = blockIdx.x*blockDim.x + threadIdx.x;
  int stride = gridDim.x*blockDim.x;
  for (; t < n; t += stride) p[t] = 0.f;
}

__global__ void k_sentinel(__hip_bfloat16* out, int n, float val){
  int t = threadIdx.x;
  if (t < n) out[t] = __float2bfloat16(val);
}

// ---------------- CSR build (sort edges by destination i) ----------------
__global__ void k_csr_deg(const int* __restrict__ eii, int E, int* __restrict__ deg){
  int e = blockIdx.x*blockDim.x + threadIdx.x;
  if (e < E) atomicAdd(&deg[eii[E+e]], 1);
}

__global__ void k_csr_scan(const int* __restrict__ deg, int* __restrict__ rowptr, int Nn){
  __shared__ int sh[256];
  __shared__ int carry;
  if (threadIdx.x == 0){ carry = 0; rowptr[0] = 0; }
  __syncthreads();
  for (int t0 = 0; t0 < Nn; t0 += 256){
    int idx = t0 + threadIdx.x;
    int v = (idx < Nn) ? deg[idx] : 0;
    sh[threadIdx.x] = v; __syncthreads();
    for (int o = 1; o < 256; o <<= 1){
      int u = (threadIdx.x >= o) ? sh[threadIdx.x - o] : 0;
      __syncthreads();
      sh[threadIdx.x] += u; __syncthreads();
    }
    if (idx < Nn) rowptr[idx + 1] = carry + sh[threadIdx.x];
    __syncthreads();
    if (threadIdx.x == 0) carry += sh[255];
    __syncthreads();
  }
}

__global__ void k_csr_scatter(const int* __restrict__ eii, int E,
                              const int* __restrict__ rowptr, int* __restrict__ cursor,
                              int* __restrict__ jp, int* __restrict__ ip){
  int e = blockIdx.x*blockDim.x + threadIdx.x;
  if (e >= E) return;
  int i = eii[E+e];
  int p = atomicAdd(&cursor[i], 1);
  int k = rowptr[i] + p;
  jp[k] = eii[e];
  ip[k] = i;
}

// ---------------- geometry + RBF (permuted, local-indexed outputs) ----------------
__global__ void k_geom(const float* __restrict__ pos,
                       const int* __restrict__ jp, const int* __restrict__ ip,
                       int off, int Cc,
                       float* __restrict__ edb, float* __restrict__ ecv,
                       float* __restrict__ rb, ushortT* __restrict__ remb)
{
  int el = blockIdx.x*blockDim.x + threadIdx.x;
  if (el >= Cc) return;
  int g = off + el;
  int j = jp[g], i = ip[g];
  float pjx = pos[3*j], pjy = pos[3*j+1], pjz = pos[3*j+2];
  float pix = pos[3*i], piy = pos[3*i+1], piz = pos[3*i+2];
  float vx = pjx-pix, vy = pjy-piy, vz = pjz-piz;
  float d = sqrtf(vx*vx + vy*vy + vz*vz);
  float inv = 1.f/(d + 1e-10f);
  float edx = vx*inv, edy = vy*inv, edz = vz*inv;
  float cx = piy*pjz - piz*pjy;
  float cy = piz*pjx - pix*pjz;
  float cz = pix*pjy - piy*pjx;
  float cn = sqrtf(cx*cx + cy*cy + cz*cz);
  float inv2 = 1.f/(cn + 1e-10f);
  cx *= inv2; cy *= inv2; cz *= inv2;
  float evx = edy*cz - edz*cy;
  float evy = edz*cx - edx*cz;
  float evz = edx*cy - edy*cx;
  edb[3*el]=edx; edb[3*el+1]=edy; edb[3*el+2]=edz;
  ecv[6*el]=cx; ecv[6*el+1]=cy; ecv[6*el+2]=cz;
  ecv[6*el+3]=evx; ecv[6*el+4]=evy; ecv[6*el+5]=evz;
  float rbv = 0.5f*(cosf(d*0.52359877559829887f) + 1.f);
  rb[el] = rbv;
  float env = (d < 6.f) ? rbv : 0.f;
  const double st = 0.0024787521766663585;      // exp(-6)
  const double pr = (2.0/96.0)*(1.0 - st);
  float beta = (float)(1.0/(pr*pr));
  float emd = expf(-d);
  for (int k = 0; k < NRAD; ++k){
    float mu = (float)(st + (1.0 - st)*((double)k/95.0));
    float t = emd - mu;
    remb[(size_t)el*NRAD + k] = f2b(env * expf(-beta*t*t));
  }
}

// ---------------- node embedding + layernorm ----------------
__global__ __launch_bounds__(128) void k_embed(const int* __restrict__ z,
    const float* __restrict__ ne_w, const float* __restrict__ ne_b,
    float* __restrict__ s, float* __restrict__ h0, int Nn)
{
  int n = blockIdx.x; int h = threadIdx.x;
  float x = ne_w[(size_t)z[n]*HIDDIM + h] + ne_b[h];
  __shared__ float red[128];
  red[h] = x; __syncthreads();
  for (int o = 64; o > 0; o >>= 1){ if (h < o) red[h] += red[h+o]; __syncthreads(); }
  float mean = red[0] * (1.f/128.f);
  __syncthreads();
  float dx = x - mean;
  red[h] = dx*dx; __syncthreads();
  for (int o = 64; o > 0; o >>= 1){ if (h < o) red[h] += red[h+o]; __syncthreads(); }
  float var = red[0] * (1.f/128.f);
  float y = dx * rsqrtf(var + 1e-5f);
  s[(size_t)n*HIDDIM + h] = y;
  h0[(size_t)n*HIDDIM + h] = y;
}

__global__ __launch_bounds__(128) void k_ln(const float* __restrict__ src, ushortT* __restrict__ dst,
    const float* __restrict__ g, const float* __restrict__ b)
{
  int n = blockIdx.x; int h = threadIdx.x;
  float x = src[(size_t)n*HIDDIM + h];
  __shared__ float red[128];
  red[h] = x; __syncthreads();
  for (int o = 64; o > 0; o >>= 1){ if (h < o) red[h] += red[h+o]; __syncthreads(); }
  float mean = red[0] * (1.f/128.f);
  __syncthreads();
  float dx = x - mean;
  red[h] = dx*dx; __syncthreads();
  for (int o = 64; o > 0; o >>= 1){ if (h < o) red[h] += red[h+o]; __syncthreads(); }
  float var = red[0] * (1.f/128.f);
  float y = dx * rsqrtf(var + 1e-5f);
  dst[(size_t)n*HIDDIM + h] = f2b(y * g[h] + b[h]);
}

// ---------------- run-leader segment sums (no atomics) ----------------
// Edges sorted by ip. One leader per contiguous i-run per launch does plain RMW.
__global__ void k_seg1_run(const int* __restrict__ jp, const int* __restrict__ ip,
                           int off, int Cc,
                           const float* __restrict__ h0,
                           const ushortT* __restrict__ rhid,   // local idx
                           float* __restrict__ s)
{
  int t = blockIdx.x*blockDim.x + threadIdx.x;
  if (t >= Cc*HIDDIM) return;
  int el = t >> 7, h = t & 127;
  int i = ip[off+el];
  if (el > 0 && ip[off+el-1] == i) return;
  float acc = 0.f;
  for (int m = el; m < Cc && ip[off+m] == i; ++m)
    acc += h0[(size_t)jp[off+m]*HIDDIM + h] * b2f(rhid[(size_t)m*HIDDIM + h]);
  s[(size_t)i*HIDDIM + h] += acc;
}

__global__ void k_seg2_run(const int* __restrict__ jp, const int* __restrict__ ip,
                           int off, int Cc,
                           const ushortT* __restrict__ slin,
                           const ushortT* __restrict__ rhid,   // local idx
                           const float* __restrict__ edb,      // local idx
                           float* __restrict__ S)
{
  int t = blockIdx.x*blockDim.x + threadIdx.x;
  if (t >= Cc*HIDDIM) return;
  int el = t >> 7, h = t & 127;
  int i = ip[off+el];
  if (el > 0 && ip[off+el-1] == i) return;
  float a0 = 0.f, a1 = 0.f, a2 = 0.f;
  for (int m = el; m < Cc && ip[off+m] == i; ++m){
    float val = b2f(slin[(size_t)jp[off+m]*HIDDIM + h]) * b2f(rhid[(size_t)m*HIDDIM + h]);
    a0 += val*edb[3*m]; a1 += val*edb[3*m+1]; a2 += val*edb[3*m+2];
  }
  float* base = &S[(size_t)i*384 + h];
  base[0]   += a0;
  base[128] += a1;
  base[256] += a2;
}

__global__ void k_seg3_run(const int* __restrict__ ip,
                           int off, int Cc,
                           const ushortT* __restrict__ mb,     // local idx, 384/edge
                           const float* __restrict__ edb,      // local idx
                           float* __restrict__ s, float* __restrict__ vecacc)
{
  int t = blockIdx.x*blockDim.x + threadIdx.x;
  if (t >= Cc*HIDDIM) return;
  int el = t >> 7, h = t & 127;
  int i = ip[off+el];
  if (el > 0 && ip[off+el-1] == i) return;
  const float is128 = 0.08838834764831845f;
  float am = 0.f, v0 = 0.f, v1 = 0.f, v2 = 0.f;
  for (int m = el; m < Cc && ip[off+m] == i; ++m){
    float m1 = b2f(mb[(size_t)m*384 + h]);
    float mm = b2f(mb[(size_t)m*384 + 256 + h]) * is128;
    am += m1;
    v0 += mm*edb[3*m]; v1 += mm*edb[3*m+1]; v2 += mm*edb[3*m+2];
  }
  s[(size_t)i*HIDDIM + h] += am;
  float* base = &vecacc[(size_t)i*384 + h];
  base[0]   += v0;
  base[128] += v1;
  base[256] += v2;
}

// ---------------- scalarize + ew assembly ----------------
__global__ __launch_bounds__(128) void k_scalarize(
  const int* __restrict__ jp, const int* __restrict__ ip, int off,
  const float* __restrict__ S, const float* __restrict__ edb, const float* __restrict__ ecv,
  const float* __restrict__ rb, const ushortT* __restrict__ rhid, const ushortT* __restrict__ remb,
  const float* __restrict__ w1, const float* __restrict__ b1,
  const float* __restrict__ w2, const float* __restrict__ b2,
  ushortT* __restrict__ ew)
{
  int el = blockIdx.x;
  int which = blockIdx.y;
  int h = threadIdx.x;
  int g = off + el;
  int n = (which == 0) ? ip[g] : jp[g];
  float f00 = edb[3*el], f01 = edb[3*el+1], f02 = edb[3*el+2];
  float f10 = ecv[6*el], f11 = ecv[6*el+1], f12 = ecv[6*el+2];
  float f20 = ecv[6*el+3], f21 = ecv[6*el+4], f22 = ecv[6*el+5];
  const float* Sn = &S[(size_t)n*384];
  float S0 = Sn[h], S1 = Sn[128+h], S2 = Sn[256+h];
  float v0 = S0*f00 + S1*f01 + S2*f02;
  float v1 = fabsf(S0*f10 + S1*f11 + S2*f12);
  float v2 = S0*f20 + S1*f21 + S2*f22;
  float out = b2[0];
  #pragma unroll
  for (int u = 0; u < 32; ++u){
    float t = v0*w1[u] + v1*w1[32+u] + v2*w1[64+u] + b1[u];
    t = silu_f(t);
    out += t * w2[u];
  }
  float scal = out + v0;
  ushortT* ewr = &ew[(size_t)el*480];
  ewr[which*128 + h] = f2b(scal * rb[el]);
  if (which == 0){
    ewr[256 + h] = rhid[(size_t)el*HIDDIM + h];
    if (h < NRAD) ewr[384 + h] = remb[(size_t)el*NRAD + h];
  }
}

// ---------------- bf16 MFMA GEMM ----------------
// A: MxK bf16 row-major; BT: NxK bf16 row-major. N%128==0, K%32==0.
// epi: 0 none, 1 silu, 2 *rowscale[row], 3 *mul1b[row,col]*xhpb[jidx[row],col]
__global__ __launch_bounds__(256) void mgemm(
  const ushortT* __restrict__ A, const ushortT* __restrict__ BT,
  const float* __restrict__ bias,
  float* __restrict__ Cf, ushortT* __restrict__ Cb,
  int M, int N, int K, int epi,
  const float* __restrict__ rowscale,
  const ushortT* __restrict__ mul1b,
  const ushortT* __restrict__ xhpb,
  const int* __restrict__ jidx)
{
  __shared__ short As[128*48];
  __shared__ short Bs[128*48];
  const int tid = threadIdx.x;
  const int w = tid >> 6;
  const int lane = tid & 63;
  const int l15 = lane & 15;
  const int q = lane >> 4;
  const int wm = w & 1, wn = w >> 1;
  const int rowBase = blockIdx.y * 128;
  const int colBase = blockIdx.x * 128;

  const int r0 = tid >> 2,         s0 = (tid & 3) << 3;
  const int r1 = (tid + 256) >> 2, s1 = ((tid + 256) & 3) << 3;

  f4_t acc[4][4] = {};

  for (int k0 = 0; k0 < K; k0 += 32){
    int4 a0v = make_int4(0,0,0,0), a1v = make_int4(0,0,0,0);
    if (rowBase + r0 < M) a0v = *(const int4*)&A[(size_t)(rowBase + r0)*K + k0 + s0];
    if (rowBase + r1 < M) a1v = *(const int4*)&A[(size_t)(rowBase + r1)*K + k0 + s1];
    int4 b0v = *(const int4*)&BT[(size_t)(colBase + r0)*K + k0 + s0];
    int4 b1v = *(const int4*)&BT[(size_t)(colBase + r1)*K + k0 + s1];
    __syncthreads();
    *(int4*)&As[r0*48 + s0] = a0v;
    *(int4*)&As[r1*48 + s1] = a1v;
    *(int4*)&Bs[r0*48 + s0] = b0v;
    *(int4*)&Bs[r1*48 + s1] = b1v;
    __syncthreads();
    bf8_t a[4], b[4];
    #pragma unroll
    for (int mt = 0; mt < 4; ++mt)
      a[mt] = *(const bf8_t*)&As[(wm*64 + mt*16 + l15)*48 + q*8];
    #pragma unroll
    for (int nt = 0; nt < 4; ++nt)
      b[nt] = *(const bf8_t*)&Bs[(wn*64 + nt*16 + l15)*48 + q*8];
    #pragma unroll
    for (int mt = 0; mt < 4; ++mt){
      #pragma unroll
      for (int nt = 0; nt < 4; ++nt)
        acc[mt][nt] = __builtin_amdgcn_mfma_f32_16x16x32_bf16(a[mt], b[nt], acc[mt][nt], 0, 0, 0);
    }
  }

  #pragma unroll
  for (int mt = 0; mt < 4; ++mt){
    int row = rowBase + wm*64 + mt*16 + q*4;
    #pragma unroll
    for (int nt = 0; nt < 4; ++nt){
      int col = colBase + wn*64 + nt*16 + l15;
      float bv = bias ? bias[col] : 0.f;
      #pragma unroll
      for (int r = 0; r < 4; ++r){
        int rr = row + r;
        if (rr >= M) continue;
        float x = acc[mt][nt][r] + bv;
        if (epi == 1) x = silu_f(x);
        else if (epi == 2) x *= rowscale[rr];
        else if (epi == 3) x = x * b2f(mul1b[(size_t)rr*N + col]) * b2f(xhpb[(size_t)jidx[rr]*N + col]);
        if (Cb) Cb[(size_t)rr*N + col] = f2b(x);
        else    Cf[(size_t)rr*N + col] = x;
      }
    }
  }
}

// ---------------- fte prep ----------------
__global__ __launch_bounds__(128) void k_fte_pre(const float* __restrict__ vpc,
    const float* __restrict__ s, ushortT* __restrict__ catb, float* __restrict__ vdot,
    int no)
{
  int nl = blockIdx.x, h = threadIdx.x;
  int n = no + nl;
  const float* base = &vpc[(size_t)nl*768];
  float a0 = base[h],       a1 = base[256+h],     a2 = base[512+h];
  float c0 = base[128+h],   c1 = base[384+h],     c2 = base[640+h];
  float scal = sqrtf(a0*a0 + a1*a1 + a2*a2 + 1e-10f);
  float vd = (a0*c0 + a1*c1 + a2*c2) * 0.08838834764831845f;
  catb[(size_t)n*256 + h] = f2b(s[(size_t)n*HIDDIM + h]);
  catb[(size_t)n*256 + 128 + h] = f2b(scal);
  vdot[(size_t)n*HIDDIM + h] = vd;
}

// ---------------- final ----------------
__global__ __launch_bounds__(128) void k_out(const float* __restrict__ xh2,
    const float* __restrict__ vdot, const float* __restrict__ s,
    const float* __restrict__ ow, const float* __restrict__ ob,
    float* __restrict__ nodeout)
{
  int n = blockIdx.x, h = threadIdx.x;
  float a1 = xh2[(size_t)n*384 + h];
  float a2 = xh2[(size_t)n*384 + 128 + h];
  float sv = s[(size_t)n*HIDDIM + h] + (a1 + a2*vdot[(size_t)n*HIDDIM + h]) * 0.7071067811865476f;
  __shared__ float red[128];
  red[h] = sv * ow[h];
  __syncthreads();
  for (int o = 64; o > 0; o >>= 1){ if (h < o) red[h] += red[h+o]; __syncthreads(); }
  if (h == 0) nodeout[n] = red[0] + ob[0];
}

__global__ __launch_bounds__(256) void k_final(const float* __restrict__ nodeout,
    const int* __restrict__ batch, void* __restrict__ out, int Nn, const int* flags)
{
  int g = blockIdx.x;
  __shared__ float rs[256], rc[256];
  float sm = 0.f, c = 0.f;
  for (int n = threadIdx.x; n < Nn; n += 256){
    if (batch[n] == g){ sm += nodeout[n]; c += 1.f; }
  }
  rs[threadIdx.x] = sm; rc[threadIdx.x] = c;
  __syncthreads();
  for (int o = 128; o > 0; o >>= 1){
    if (threadIdx.x < o){ rs[threadIdx.x] += rs[threadIdx.x+o]; rc[threadIdx.x] += rc[threadIdx.x+o]; }
    __syncthreads();
  }
  if (threadIdx.x == 0){
    float v = (rc[0] > 0.f) ? rs[0]/rc[0] : 0.f;
    if (flags[0]) ((__hip_bfloat16*)out)[g] = __float2bfloat16(v);
    else ((float*)out)[g] = v;
  }
}

// =====================================================================
extern "C" void kernel_launch(void* const* d_in, const int* in_sizes, int n_in,
                              void* d_out, int out_size, void* d_ws, size_t ws_size,
                              hipStream_t stream)
{
  const int N = in_sizes[0] / 3;
  const int E = in_sizes[3] / 2;

  size_t off = 0;
  auto alloc = [&](size_t n)->float*{
    float* p = (float*)d_ws + off;
    off += (n + 3) & ~(size_t)3;
    return p;
  };
  auto allocU = [&](size_t n)->ushortT*{ return (ushortT*)alloc((n + 1) / 2); };

  int* flags = (int*)alloc(4);
  int* zi    = (int*)alloc((size_t)N);
  int* bi    = (int*)alloc((size_t)N);
  int* eii   = (int*)alloc((size_t)2*E);
  // CSR
  int* deg    = (int*)alloc((size_t)N);   // deg+cursor contiguous for one zero
  int* cursor = (int*)alloc((size_t)N);
  int* rowptr = (int*)alloc((size_t)N + 4);
  int* jp     = (int*)alloc((size_t)E);
  int* ipp    = (int*)alloc((size_t)E);

  float* pos = alloc((size_t)N*3);
  float* w[31];
  for (int t = 0; t < 31; ++t) w[t] = alloc((size_t)in_sizes[4+t]);
  float* rl_b1=w[1];  float* rl_b2=w[3];
  float* ne_w =w[4];  float* ne_b =w[5];  float* sv_b =w[7];
  float* l3_w1=w[8];  float* l3_b1=w[9];  float* l3_w2=w[10]; float* l3_b2=w[11];
  float* mp_w =w[12]; float* mp_b =w[13]; float* xp_b1=w[15];
  float* xp_b2=w[17]; float* rp_b =w[19];
  float* ip_b1=w[21]; float* ip_b2=w[23];
  float* fte_b1=w[26];float* fte_b2=w[28];float* out_w=w[29]; float* out_b=w[30];

  ushortT* wt_rl1 = allocU(96*128);
  ushortT* wt_rl2 = allocU(128*128);
  ushortT* wt_sv  = allocU(128*128);
  ushortT* wt_xp1 = allocU(128*128);
  ushortT* wt_xp2 = allocU((size_t)128*384);
  ushortT* wt_rp  = allocU((size_t)96*384);
  ushortT* wt_ip1 = allocU((size_t)480*384);
  ushortT* wt_ip2 = allocU((size_t)384*384);
  ushortT* wt_feq = allocU((size_t)128*256);
  ushortT* wt_ft1 = allocU((size_t)256*128);
  ushortT* wt_ft2 = allocU((size_t)128*384);

  float* s    = alloc((size_t)N*HIDDIM);
  float* h0   = alloc((size_t)N*HIDDIM);      // dead after seg1 -> vdot overlay
  ushortT* sb     = allocU((size_t)N*HIDDIM);
  ushortT* slin_b = allocU((size_t)N*HIDDIM);
  ushortT* xln_b  = allocU((size_t)N*HIDDIM);
  ushortT* hb     = allocU((size_t)N*HIDDIM);
  float* S    = alloc((size_t)N*384);         // dead after scalarize -> xh2 overlay
  float* vecacc = alloc((size_t)N*384);       // contiguous with S for zeroing
  ushortT* xh_b = allocU((size_t)N*384);
  ushortT* vab  = allocU((size_t)N*384);
  ushortT* catb = allocU((size_t)N*256);
  float* nodeout = alloc((size_t)N);
  float* vdot = h0;
  float* xh2  = S;

  size_t wsF = ws_size / sizeof(float);
  size_t availF = (wsF > off) ? (wsF - off) : 0;
  size_t edgeP = (size_t)E*(64+3);            // rhid bf16 + edb fp32, permuted
  bool persist = false; int C = 0;
  for (int c = 32768; c >= 1024; c >>= 1)
    if (edgeP + (size_t)c*874 + 64 <= availF){ persist = true; C = c; break; }
  if (!persist)
    for (int c = 32768; c >= 256; c >>= 1)
      if ((size_t)c*938 + 64 <= availF){ C = c; break; }
  if (C == 0){
    k_sentinel<<<1, 64, 0, stream>>>((__hip_bfloat16*)d_out, out_size,
                                     (float)(double)(ws_size >> 20));
    return;
  }

  ushortT* rhid_a = nullptr; float* edb_a = nullptr;
  if (persist){
    rhid_a = allocU((size_t)E*128);
    edb_a  = alloc((size_t)3*E);
  }
  float* scratch0 = (float*)d_ws + off;
  float* edb_l  = alloc((size_t)3*C);
  float* ecv_l  = alloc((size_t)6*C);
  float* rb_l   = alloc((size_t)C);
  ushortT* remb_l = allocU((size_t)C*96);
  ushortT* rhid_l = persist ? nullptr : allocU((size_t)C*128);
  ushortT* ew_b = allocU((size_t)C*480);
  ushortT* R2b  = allocU((size_t)C*384);
  ushortT* R1b  = allocU((size_t)C*384);
  ushortT* Rmb  = allocU((size_t)C*384);
  float* vpc = scratch0;                      // phase-F overlay on chunk scratch
  size_t scratchF = (size_t)C*874;

  auto mg = [&](const ushortT* A, const ushortT* BT, const float* bias,
                float* Cf, ushortT* Cb, int M, int Nc, int K, int epi,
                const float* rowscale = nullptr, const ushortT* mul1b = nullptr,
                const ushortT* xhpb = nullptr, const int* jidx = nullptr){
    dim3 grid(Nc/128, (M + 127)/128);
    mgemm<<<grid, 256, 0, stream>>>(A, BT, bias, Cf, Cb, M, Nc, K, epi,
                                    rowscale, mul1b, xhpb, jidx);
  };
  auto geom = [&](int o, int Cc, float* edb_p){
    k_geom<<<(Cc + 255)/256, 256, 0, stream>>>(pos, jp, ipp, o, Cc, edb_p, ecv_l, rb_l, remb_l);
  };
  auto rl = [&](ushortT* rhid_p, int Cc){
    mg(remb_l, wt_rl1, rl_b1, nullptr, R2b, Cc, 128, 96, 1);
    mg(R2b, wt_rl2, rl_b2, nullptr, rhid_p, Cc, 128, 128, 2, rb_l);
  };

  // 0) dtype detect + int normalize
  k_detect<<<1, 256, 0, stream>>>((const ushortT*)d_in[0], in_sizes[0],
                                  (const int*)d_in[2], in_sizes[2], flags);
  k_iconv<<<1024, 256, 0, stream>>>((const int*)d_in[1], (const int*)d_in[2],
                                    (const int*)d_in[3], zi, bi, eii, N, 2*E, flags);

  // 1) float conversions + transposed bf16 weights
  ConvArgs ca;
  ca.d[0] = { (const ushortT*)d_in[0], pos, in_sizes[0] };
  for (int t = 0; t < 31; ++t)
    ca.d[1+t] = { (const ushortT*)d_in[4+t], w[t], in_sizes[4+t] };
  k_conv<<<dim3(32, 32), 256, 0, stream>>>(ca, 32, flags);

  TArgs ta;
  ta.d[0]  = { (const ushortT*)d_in[4],  wt_rl1, 96, 128 };
  ta.d[1]  = { (const ushortT*)d_in[6],  wt_rl2, 128, 128 };
  ta.d[2]  = { (const ushortT*)d_in[10], wt_sv,  128, 128 };
  ta.d[3]  = { (const ushortT*)d_in[18], wt_xp1, 128, 128 };
  ta.d[4]  = { (const ushortT*)d_in[20], wt_xp2, 128, 384 };
  ta.d[5]  = { (const ushortT*)d_in[22], wt_rp,  96, 384 };
  ta.d[6]  = { (const ushortT*)d_in[24], wt_ip1, 480, 384 };
  ta.d[7]  = { (const ushortT*)d_in[26], wt_ip2, 384, 384 };
  ta.d[8]  = { (const ushortT*)d_in[28], wt_feq, 128, 256 };
  ta.d[9]  = { (const ushortT*)d_in[29], wt_ft1, 256, 128 };
  ta.d[10] = { (const ushortT*)d_in[31], wt_ft2, 128, 384 };
  k_wt<<<dim3(48, 11), 256, 0, stream>>>(ta, 11, flags);

  // 2) CSR build (sorted by destination i)
  k_zero<<<64, 256, 0, stream>>>((float*)deg, 2*N);     // deg + cursor
  k_csr_deg<<<(E + 255)/256, 256, 0, stream>>>(eii, E, deg);
  k_csr_scan<<<1, 256, 0, stream>>>(deg, rowptr, N);
  k_csr_scatter<<<(E + 255)/256, 256, 0, stream>>>(eii, E, rowptr, cursor, jp, ipp);

  // 3) zero accumulators, node embedding
  k_zero<<<2048, 256, 0, stream>>>(S, N*384*2);
  k_embed<<<N, 128, 0, stream>>>(zi, ne_w, ne_b, s, h0, N);

  if (persist){
    // rl MLP once for all E (chunked), geom writes edb_a persistently
    for (int o = 0; o < E; o += C){
      int Cc = (E - o < C) ? (E - o) : C;
      geom(o, Cc, edb_a + (size_t)3*o);
      rl(rhid_a + (size_t)o*128, Cc);
    }
    k_seg1_run<<<((size_t)E*128 + 255)/256, 256, 0, stream>>>(jp, ipp, 0, E, h0, rhid_a, s);
  } else {
    for (int o = 0; o < E; o += C){
      int Cc = (E - o < C) ? (E - o) : C;
      geom(o, Cc, edb_l);
      rl(rhid_l, Cc);
      k_seg1_run<<<((size_t)Cc*128 + 255)/256, 256, 0, stream>>>(jp, ipp, o, Cc, h0, rhid_l, s);
    }
  }

  // Phase C: slin, xln, xh
  k_f2b<<<1024, 256, 0, stream>>>(s, sb, N*HIDDIM);
  mg(sb, wt_sv, sv_b, nullptr, slin_b, N, 128, 128, 1);
  k_ln<<<N, 128, 0, stream>>>(s, xln_b, mp_w, mp_b);
  mg(xln_b, wt_xp1, xp_b1, nullptr, hb, N, 128, 128, 1);
  mg(hb, wt_xp2, xp_b2, nullptr, xh_b, N, 384, 128, 0);

  // Phase D: seg2
  if (persist){
    k_seg2_run<<<((size_t)E*128 + 255)/256, 256, 0, stream>>>(jp, ipp, 0, E, slin_b, rhid_a, edb_a, S);
  } else {
    for (int o = 0; o < E; o += C){
      int Cc = (E - o < C) ? (E - o) : C;
      geom(o, Cc, edb_l);
      rl(rhid_l, Cc);
      k_seg2_run<<<((size_t)Cc*128 + 255)/256, 256, 0, stream>>>(jp, ipp, o, Cc, slin_b, rhid_l, edb_l, S);
    }
  }

  // Phase E: per-edge big MLPs + seg3 (geom recomputed per chunk)
  for (int o = 0; o < E; o += C){
    int Cc = (E - o < C) ? (E - o) : C;
    geom(o, Cc, edb_l);
    const ushortT* rhid_p;
    if (persist) rhid_p = rhid_a + (size_t)o*128;
    else { rl(rhid_l, Cc); rhid_p = rhid_l; }
    k_scalarize<<<dim3(Cc, 2), 128, 0, stream>>>(jp, ipp, o, S, edb_l, ecv_l, rb_l,
                                                 rhid_p, remb_l,
                                                 l3_w1, l3_b1, l3_w2, l3_b2, ew_b);
    mg(remb_l, wt_rp, rp_b, nullptr, R1b, Cc, 384, 96, 0);
    mg(ew_b, wt_ip1, ip_b1, nullptr, R2b, Cc, 384, 480, 1);
    mg(R2b, wt_ip2, ip_b2, nullptr, Rmb, Cc, 384, 384, 3, nullptr, R1b, xh_b, jp + o);
    k_seg3_run<<<((size_t)Cc*128 + 255)/256, 256, 0, stream>>>(ipp, o, Cc, Rmb, edb_l, s, vecacc);
  }

  // Phase F: fte
  k_f2b<<<1024, 256, 0, stream>>>(vecacc, vab, N*384);
  int Cn = (int)(scratchF / 768);
  if (Cn > N) Cn = N;
  for (int no = 0; no < N; no += Cn){
    int Cc = (N - no < Cn) ? (N - no) : Cn;
    mg(vab + (size_t)no*384, wt_feq, nullptr, vpc, nullptr, 3*Cc, 256, 128, 0);
    k_fte_pre<<<Cc, 128, 0, stream>>>(vpc, s, catb, vdot, no);
  }
  mg(catb, wt_ft1, fte_b1, nullptr, hb, N, 128, 256, 1);
  mg(hb, wt_ft2, fte_b2, xh2, nullptr, N, 384, 128, 0);

  // Phase G
  k_out<<<N, 128, 0, stream>>>(xh2, vdot, s, out_w, out_b, nodeout);
  k_final<<<out_size, 256, 0, stream>>>(nodeout, bi, d_out, N, flags);
}

// Round 6
// 2783.928 us; speedup vs baseline: 2.8229x; 1.2299x over previous
//
#include <hip/hip_runtime.h>
#include <hip/hip_bf16.h>
#include <math.h>

#define NRAD 96
#define HIDDIM 128
typedef unsigned short ushortT;

typedef __attribute__((ext_vector_type(8))) short bf8_t;   // 8 bf16 (4 VGPRs)
typedef __attribute__((ext_vector_type(4))) float f4_t;    // 4 fp32 acc

__device__ __forceinline__ float silu_f(float x){ return x / (1.f + __expf(-x)); }
__device__ __forceinline__ float b2f(ushortT u){ return __uint_as_float(((unsigned int)u) << 16); }
__device__ __forceinline__ ushortT f2b(float x){
  unsigned int u = __float_as_uint(x);
  unsigned int r = (u + 0x7fffu + ((u >> 16) & 1u)) >> 16;
  return (ushortT)r;
}

// ---------------- dtype detection (parallel) ----------------
// flags[2] = nonzero if floats are fp32 ("bad bf16 pattern" found)
// flags[3] = nonzero if ints are int32 (odd words nonzero)
__global__ void k_detect(const ushortT* posw, int npos,
                         const int* batchw, int nb, int* flags){
  int tot = (npos < 4096 ? npos : 4096);
  int big = tot > nb ? tot : nb;
  int bad = 0, orv = 0;
  for (int t = blockIdx.x*blockDim.x + threadIdx.x; t < big; t += gridDim.x*blockDim.x){
    if (t < tot){
      float x = b2f(posw[t]);
      if (!(fabsf(x) <= 1000.f)) bad = 1;
    }
    if (t < nb && (t & 1)) orv |= batchw[t];
  }
  if (bad) atomicOr(&flags[2], 1);
  if (orv) atomicOr(&flags[3], 1);
}

// normalize int inputs to int32; also builds CSR degree histogram
__global__ void k_iconv(const int* zsrc, const int* bsrc, const int* esrc,
                        int* zi, int* bi, int* eii, int Nn, int E, const int* flags,
                        int* deg){
  int f = (flags[3] == 0) ? 1 : 0;   // 1 => int64
  int total = 2*Nn + 2*E;
  for (int t = blockIdx.x*blockDim.x + threadIdx.x; t < total; t += gridDim.x*blockDim.x){
    if (t < Nn) zi[t] = zsrc[(size_t)t << f];
    else if (t < 2*Nn) bi[t-Nn] = bsrc[(size_t)(t-Nn) << f];
    else {
      int e = t - 2*Nn;
      int v = esrc[(size_t)e << f];
      eii[e] = v;
      if (e >= E) atomicAdd(&deg[v], 1);   // destination i half
    }
  }
}

// ---------------- conversion: (bf16|f32) -> f32 ----------------
struct ConvDesc { const ushortT* src; float* dst; int n; };
struct ConvArgs { ConvDesc d[32]; };

__global__ void k_conv(ConvArgs a, int cnt, const int* flags){
  int y = blockIdx.y;
  if (y >= cnt) return;
  int f = (flags[2] == 0) ? 1 : 0;    // 1 => bf16
  const ushortT* s = a.d[y].src;
  float* dst = a.d[y].dst;
  int n = a.d[y].n;
  if (f){
    for (int t = blockIdx.x*blockDim.x + threadIdx.x; t < n; t += gridDim.x*blockDim.x)
      dst[t] = b2f(s[t]);
  } else {
    const float* sf = (const float*)s;
    for (int t = blockIdx.x*blockDim.x + threadIdx.x; t < n; t += gridDim.x*blockDim.x)
      dst[t] = sf[t];
  }
}

// ---------------- weight transpose -> bf16 [N][K] ----------------
struct TDesc { const ushortT* src; ushortT* dst; int K, N; };
struct TArgs { TDesc d[12]; };

__global__ void k_wt(TArgs a, int cnt, const int* flags){
  int y = blockIdx.y;
  if (y >= cnt) return;
  int f = (flags[2] == 0) ? 1 : 0;
  const ushortT* s = a.d[y].src;
  ushortT* dst = a.d[y].dst;
  int K = a.d[y].K, N = a.d[y].N, tot = K*N;
  for (int t = blockIdx.x*blockDim.x + threadIdx.x; t < tot; t += gridDim.x*blockDim.x){
    int k = t / N, n = t - k*N;
    ushortT v = f ? s[t] : f2b(((const float*)s)[t]);
    dst[(size_t)n*K + k] = v;
  }
}

__global__ void k_f2b(const float* __restrict__ src, ushortT* __restrict__ dst, int n){
  for (int t = blockIdx.x*blockDim.x + threadIdx.x; t < n; t += gridDim.x*blockDim.x)
    dst[t] = f2b(src[t]);
}

__global__ void k_zero(float* __restrict__ p, int n){
  int t = blockIdx.x*blockDim.x + threadIdx.x;
  int stride = gridDim.x*blockDim.x;
  for (; t < n; t += stride) p[t] = 0.f;
}

__global__ void k_sentinel(__hip_bfloat16* out, int n, float val){
  int t = threadIdx.x;
  if (t < n) out[t] = __float2bfloat16(val);
}

// ---------------- CSR scan + scatter ----------------
__global__ void k_csr_scan(const int* __restrict__ deg, int* __restrict__ rowptr, int Nn){
  __shared__ int sh[256];
  __shared__ int carry;
  if (threadIdx.x == 0){ carry = 0; rowptr[0] = 0; }
  __syncthreads();
  for (int t0 = 0; t0 < Nn; t0 += 256){
    int idx = t0 + threadIdx.x;
    int v = (idx < Nn) ? deg[idx] : 0;
    sh[threadIdx.x] = v; __syncthreads();
    for (int o = 1; o < 256; o <<= 1){
      int u = (threadIdx.x >= o) ? sh[threadIdx.x - o] : 0;
      __syncthreads();
      sh[threadIdx.x] += u; __syncthreads();
    }
    if (idx < Nn) rowptr[idx + 1] = carry + sh[threadIdx.x];
    __syncthreads();
    if (threadIdx.x == 0) carry += sh[255];
    __syncthreads();
  }
}

__global__ void k_csr_scatter(const int* __restrict__ eii, int E,
                              const int* __restrict__ rowptr, int* __restrict__ cursor,
                              int* __restrict__ jp, int* __restrict__ ip){
  int e = blockIdx.x*blockDim.x + threadIdx.x;
  if (e >= E) return;
  int i = eii[E+e];
  int p = atomicAdd(&cursor[i], 1);
  int k = rowptr[i] + p;
  jp[k] = eii[e];
  ip[k] = i;
}

// ---------------- geometry + RBF (permuted) ----------------
__global__ void k_geom(const float* __restrict__ pos,
                       const int* __restrict__ jp, const int* __restrict__ ip,
                       int off, int Cc,
                       float* __restrict__ edb, float* __restrict__ ecv,
                       float* __restrict__ rb, ushortT* __restrict__ remb)
{
  int el = blockIdx.x*blockDim.x + threadIdx.x;
  if (el >= Cc) return;
  int g = off + el;
  int j = jp[g], i = ip[g];
  float pjx = pos[3*j], pjy = pos[3*j+1], pjz = pos[3*j+2];
  float pix = pos[3*i], piy = pos[3*i+1], piz = pos[3*i+2];
  float vx = pjx-pix, vy = pjy-piy, vz = pjz-piz;
  float d = sqrtf(vx*vx + vy*vy + vz*vz);
  float inv = 1.f/(d + 1e-10f);
  float edx = vx*inv, edy = vy*inv, edz = vz*inv;
  float cx = piy*pjz - piz*pjy;
  float cy = piz*pjx - pix*pjz;
  float cz = pix*pjy - piy*pjx;
  float cn = sqrtf(cx*cx + cy*cy + cz*cz);
  float inv2 = 1.f/(cn + 1e-10f);
  cx *= inv2; cy *= inv2; cz *= inv2;
  float evx = edy*cz - edz*cy;
  float evy = edz*cx - edx*cz;
  float evz = edx*cy - edy*cx;
  edb[3*el]=edx; edb[3*el+1]=edy; edb[3*el+2]=edz;
  ecv[6*el]=cx; ecv[6*el+1]=cy; ecv[6*el+2]=cz;
  ecv[6*el+3]=evx; ecv[6*el+4]=evy; ecv[6*el+5]=evz;
  float rbv = 0.5f*(cosf(d*0.52359877559829887f) + 1.f);
  rb[el] = rbv;
  float env = (d < 6.f) ? rbv : 0.f;
  const double st = 0.0024787521766663585;      // exp(-6)
  const double pr = (2.0/96.0)*(1.0 - st);
  float beta = (float)(1.0/(pr*pr));
  float emd = expf(-d);
  for (int k = 0; k < NRAD; ++k){
    float mu = (float)(st + (1.0 - st)*((double)k/95.0));
    float t = emd - mu;
    remb[(size_t)el*NRAD + k] = f2b(env * expf(-beta*t*t));
  }
}

// ---------------- node embedding + layernorm (+ fused accumulator zeroing) ----------------
__global__ __launch_bounds__(128) void k_embed(const int* __restrict__ z,
    const float* __restrict__ ne_w, const float* __restrict__ ne_b,
    float* __restrict__ s, float* __restrict__ h0,
    float* __restrict__ S, float* __restrict__ vecacc)
{
  int n = blockIdx.x; int h = threadIdx.x;
  float x = ne_w[(size_t)z[n]*HIDDIM + h] + ne_b[h];
  __shared__ float red[128];
  red[h] = x; __syncthreads();
  for (int o = 64; o > 0; o >>= 1){ if (h < o) red[h] += red[h+o]; __syncthreads(); }
  float mean = red[0] * (1.f/128.f);
  __syncthreads();
  float dx = x - mean;
  red[h] = dx*dx; __syncthreads();
  for (int o = 64; o > 0; o >>= 1){ if (h < o) red[h] += red[h+o]; __syncthreads(); }
  float var = red[0] * (1.f/128.f);
  float y = dx * rsqrtf(var + 1e-5f);
  s[(size_t)n*HIDDIM + h] = y;
  h0[(size_t)n*HIDDIM + h] = y;
  float* Sr = &S[(size_t)n*384 + h];
  float* Vr = &vecacc[(size_t)n*384 + h];
  Sr[0]=0.f; Sr[128]=0.f; Sr[256]=0.f;
  Vr[0]=0.f; Vr[128]=0.f; Vr[256]=0.f;
}

// LN -> xln_b, plus fused s -> sb conversion
__global__ __launch_bounds__(128) void k_ln(const float* __restrict__ src, ushortT* __restrict__ dst,
    const float* __restrict__ g, const float* __restrict__ b, ushortT* __restrict__ sb)
{
  int n = blockIdx.x; int h = threadIdx.x;
  float x = src[(size_t)n*HIDDIM + h];
  sb[(size_t)n*HIDDIM + h] = f2b(x);
  __shared__ float red[128];
  red[h] = x; __syncthreads();
  for (int o = 64; o > 0; o >>= 1){ if (h < o) red[h] += red[h+o]; __syncthreads(); }
  float mean = red[0] * (1.f/128.f);
  __syncthreads();
  float dx = x - mean;
  red[h] = dx*dx; __syncthreads();
  for (int o = 64; o > 0; o >>= 1){ if (h < o) red[h] += red[h+o]; __syncthreads(); }
  float var = red[0] * (1.f/128.f);
  float y = dx * rsqrtf(var + 1e-5f);
  dst[(size_t)n*HIDDIM + h] = f2b(y * g[h] + b[h]);
}

// ---------------- run-leader segment sums (no atomics) ----------------
__global__ void k_seg1_run(const int* __restrict__ jp, const int* __restrict__ ip,
                           int off, int Cc,
                           const float* __restrict__ h0,
                           const ushortT* __restrict__ rhid,   // local idx
                           float* __restrict__ s)
{
  int t = blockIdx.x*blockDim.x + threadIdx.x;
  if (t >= Cc*HIDDIM) return;
  int el = t >> 7, h = t & 127;
  int i = ip[off+el];
  if (el > 0 && ip[off+el-1] == i) return;
  float acc = 0.f;
  for (int m = el; m < Cc && ip[off+m] == i; ++m)
    acc += h0[(size_t)jp[off+m]*HIDDIM + h] * b2f(rhid[(size_t)m*HIDDIM + h]);
  s[(size_t)i*HIDDIM + h] += acc;
}

__global__ void k_seg2_run(const int* __restrict__ jp, const int* __restrict__ ip,
                           int off, int Cc,
                           const ushortT* __restrict__ slin,
                           const ushortT* __restrict__ rhid,   // local idx
                           const float* __restrict__ edb,      // local idx
                           float* __restrict__ S)
{
  int t = blockIdx.x*blockDim.x + threadIdx.x;
  if (t >= Cc*HIDDIM) return;
  int el = t >> 7, h = t & 127;
  int i = ip[off+el];
  if (el > 0 && ip[off+el-1] == i) return;
  float a0 = 0.f, a1 = 0.f, a2 = 0.f;
  for (int m = el; m < Cc && ip[off+m] == i; ++m){
    float val = b2f(slin[(size_t)jp[off+m]*HIDDIM + h]) * b2f(rhid[(size_t)m*HIDDIM + h]);
    a0 += val*edb[3*m]; a1 += val*edb[3*m+1]; a2 += val*edb[3*m+2];
  }
  float* base = &S[(size_t)i*384 + h];
  base[0]   += a0;
  base[128] += a1;
  base[256] += a2;
}

__global__ void k_seg3_run(const int* __restrict__ ip,
                           int off, int Cc,
                           const ushortT* __restrict__ mb,     // local idx, 384/edge
                           const float* __restrict__ edb,      // local idx
                           float* __restrict__ s, float* __restrict__ vecacc)
{
  int t = blockIdx.x*blockDim.x + threadIdx.x;
  if (t >= Cc*HIDDIM) return;
  int el = t >> 7, h = t & 127;
  int i = ip[off+el];
  if (el > 0 && ip[off+el-1] == i) return;
  const float is128 = 0.08838834764831845f;
  float am = 0.f, v0 = 0.f, v1 = 0.f, v2 = 0.f;
  for (int m = el; m < Cc && ip[off+m] == i; ++m){
    float m1 = b2f(mb[(size_t)m*384 + h]);
    float mm = b2f(mb[(size_t)m*384 + 256 + h]) * is128;
    am += m1;
    v0 += mm*edb[3*m]; v1 += mm*edb[3*m+1]; v2 += mm*edb[3*m+2];
  }
  s[(size_t)i*HIDDIM + h] += am;
  float* base = &vecacc[(size_t)i*384 + h];
  base[0]   += v0;
  base[128] += v1;
  base[256] += v2;
}

// ---------------- scalarize + ew assembly (both halves per block) ----------------
__global__ __launch_bounds__(256) void k_scalarize(
  const int* __restrict__ jp, const int* __restrict__ ip, int off,
  const float* __restrict__ S, const float* __restrict__ edb, const float* __restrict__ ecv,
  const float* __restrict__ rb, const ushortT* __restrict__ rhid, const ushortT* __restrict__ remb,
  const float* __restrict__ w1, const float* __restrict__ b1,
  const float* __restrict__ w2, const float* __restrict__ b2,
  ushortT* __restrict__ ew)
{
  int el = blockIdx.x;
  int which = threadIdx.x >> 7;
  int h = threadIdx.x & 127;
  int g = off + el;
  int n = (which == 0) ? ip[g] : jp[g];
  float f00 = edb[3*el], f01 = edb[3*el+1], f02 = edb[3*el+2];
  float f10 = ecv[6*el], f11 = ecv[6*el+1], f12 = ecv[6*el+2];
  float f20 = ecv[6*el+3], f21 = ecv[6*el+4], f22 = ecv[6*el+5];
  const float* Sn = &S[(size_t)n*384];
  float S0 = Sn[h], S1 = Sn[128+h], S2 = Sn[256+h];
  float v0 = S0*f00 + S1*f01 + S2*f02;
  float v1 = fabsf(S0*f10 + S1*f11 + S2*f12);
  float v2 = S0*f20 + S1*f21 + S2*f22;
  float out = b2[0];
  #pragma unroll
  for (int u = 0; u < 32; ++u){
    float t = v0*w1[u] + v1*w1[32+u] + v2*w1[64+u] + b1[u];
    t = silu_f(t);
    out += t * w2[u];
  }
  float scal = out + v0;
  ushortT* ewr = &ew[(size_t)el*480];
  ewr[which*128 + h] = f2b(scal * rb[el]);
  if (which == 0){
    ewr[256 + h] = rhid[(size_t)el*HIDDIM + h];
    if (h < NRAD) ewr[384 + h] = remb[(size_t)el*NRAD + h];
  }
}

// ---------------- bf16 MFMA GEMM ----------------
// A: MxK bf16 row-major; BT: NxK bf16 row-major. N%128==0, K%32==0.
// epi: 0 none, 1 silu, 2 *rowscale[row], 3 *mul1b[row,col]*xhpb[jidx[row],col]
__global__ __launch_bounds__(256) void mgemm(
  const ushortT* __restrict__ A, const ushortT* __restrict__ BT,
  const float* __restrict__ bias,
  float* __restrict__ Cf, ushortT* __restrict__ Cb,
  int M, int N, int K, int epi,
  const float* __restrict__ rowscale,
  const ushortT* __restrict__ mul1b,
  const ushortT* __restrict__ xhpb,
  const int* __restrict__ jidx)
{
  __shared__ short As[128*48];
  __shared__ short Bs[128*48];
  const int tid = threadIdx.x;
  const int w = tid >> 6;
  const int lane = tid & 63;
  const int l15 = lane & 15;
  const int q = lane >> 4;
  const int wm = w & 1, wn = w >> 1;
  const int rowBase = blockIdx.y * 128;
  const int colBase = blockIdx.x * 128;

  const int r0 = tid >> 2,         s0 = (tid & 3) << 3;
  const int r1 = (tid + 256) >> 2, s1 = ((tid + 256) & 3) << 3;

  f4_t acc[4][4] = {};

  for (int k0 = 0; k0 < K; k0 += 32){
    int4 a0v = make_int4(0,0,0,0), a1v = make_int4(0,0,0,0);
    if (rowBase + r0 < M) a0v = *(const int4*)&A[(size_t)(rowBase + r0)*K + k0 + s0];
    if (rowBase + r1 < M) a1v = *(const int4*)&A[(size_t)(rowBase + r1)*K + k0 + s1];
    int4 b0v = *(const int4*)&BT[(size_t)(colBase + r0)*K + k0 + s0];
    int4 b1v = *(const int4*)&BT[(size_t)(colBase + r1)*K + k0 + s1];
    __syncthreads();
    *(int4*)&As[r0*48 + s0] = a0v;
    *(int4*)&As[r1*48 + s1] = a1v;
    *(int4*)&Bs[r0*48 + s0] = b0v;
    *(int4*)&Bs[r1*48 + s1] = b1v;
    __syncthreads();
    bf8_t a[4], b[4];
    #pragma unroll
    for (int mt = 0; mt < 4; ++mt)
      a[mt] = *(const bf8_t*)&As[(wm*64 + mt*16 + l15)*48 + q*8];
    #pragma unroll
    for (int nt = 0; nt < 4; ++nt)
      b[nt] = *(const bf8_t*)&Bs[(wn*64 + nt*16 + l15)*48 + q*8];
    #pragma unroll
    for (int mt = 0; mt < 4; ++mt){
      #pragma unroll
      for (int nt = 0; nt < 4; ++nt)
        acc[mt][nt] = __builtin_amdgcn_mfma_f32_16x16x32_bf16(a[mt], b[nt], acc[mt][nt], 0, 0, 0);
    }
  }

  #pragma unroll
  for (int mt = 0; mt < 4; ++mt){
    int row = rowBase + wm*64 + mt*16 + q*4;
    #pragma unroll
    for (int nt = 0; nt < 4; ++nt){
      int col = colBase + wn*64 + nt*16 + l15;
      float bv = bias ? bias[col] : 0.f;
      #pragma unroll
      for (int r = 0; r < 4; ++r){
        int rr = row + r;
        if (rr >= M) continue;
        float x = acc[mt][nt][r] + bv;
        if (epi == 1) x = silu_f(x);
        else if (epi == 2) x *= rowscale[rr];
        else if (epi == 3) x = x * b2f(mul1b[(size_t)rr*N + col]) * b2f(xhpb[(size_t)jidx[rr]*N + col]);
        if (Cb) Cb[(size_t)rr*N + col] = f2b(x);
        else    Cf[(size_t)rr*N + col] = x;
      }
    }
  }
}

// ---------------- fte prep ----------------
__global__ __launch_bounds__(128) void k_fte_pre(const float* __restrict__ vpc,
    const float* __restrict__ s, ushortT* __restrict__ catb, float* __restrict__ vdot,
    int no)
{
  int nl = blockIdx.x, h = threadIdx.x;
  int n = no + nl;
  const float* base = &vpc[(size_t)nl*768];
  float a0 = base[h],       a1 = base[256+h],     a2 = base[512+h];
  float c0 = base[128+h],   c1 = base[384+h],     c2 = base[640+h];
  float scal = sqrtf(a0*a0 + a1*a1 + a2*a2 + 1e-10f);
  float vd = (a0*c0 + a1*c1 + a2*c2) * 0.08838834764831845f;
  catb[(size_t)n*256 + h] = f2b(s[(size_t)n*HIDDIM + h]);
  catb[(size_t)n*256 + 128 + h] = f2b(scal);
  vdot[(size_t)n*HIDDIM + h] = vd;
}

// ---------------- final ----------------
__global__ __launch_bounds__(128) void k_out(const float* __restrict__ xh2,
    const float* __restrict__ vdot, const float* __restrict__ s,
    const float* __restrict__ ow, const float* __restrict__ ob,
    float* __restrict__ nodeout)
{
  int n = blockIdx.x, h = threadIdx.x;
  float a1 = xh2[(size_t)n*384 + h];
  float a2 = xh2[(size_t)n*384 + 128 + h];
  float sv = s[(size_t)n*HIDDIM + h] + (a1 + a2*vdot[(size_t)n*HIDDIM + h]) * 0.7071067811865476f;
  __shared__ float red[128];
  red[h] = sv * ow[h];
  __syncthreads();
  for (int o = 64; o > 0; o >>= 1){ if (h < o) red[h] += red[h+o]; __syncthreads(); }
  if (h == 0) nodeout[n] = red[0] + ob[0];
}

__global__ __launch_bounds__(256) void k_final(const float* __restrict__ nodeout,
    const int* __restrict__ batch, void* __restrict__ out, int Nn, const int* flags)
{
  int g = blockIdx.x;
  __shared__ float rs[256], rc[256];
  float sm = 0.f, c = 0.f;
  for (int n = threadIdx.x; n < Nn; n += 256){
    if (batch[n] == g){ sm += nodeout[n]; c += 1.f; }
  }
  rs[threadIdx.x] = sm; rc[threadIdx.x] = c;
  __syncthreads();
  for (int o = 128; o > 0; o >>= 1){
    if (threadIdx.x < o){ rs[threadIdx.x] += rs[threadIdx.x+o]; rc[threadIdx.x] += rc[threadIdx.x+o]; }
    __syncthreads();
  }
  if (threadIdx.x == 0){
    float v = (rc[0] > 0.f) ? rs[0]/rc[0] : 0.f;
    if (flags[2] == 0) ((__hip_bfloat16*)out)[g] = __float2bfloat16(v);
    else ((float*)out)[g] = v;
  }
}

// =====================================================================
extern "C" void kernel_launch(void* const* d_in, const int* in_sizes, int n_in,
                              void* d_out, int out_size, void* d_ws, size_t ws_size,
                              hipStream_t stream)
{
  const int N = in_sizes[0] / 3;
  const int E = in_sizes[3] / 2;

  size_t off = 0;
  auto alloc = [&](size_t n)->float*{
    float* p = (float*)d_ws + off;
    off += (n + 3) & ~(size_t)3;
    return p;
  };
  auto allocU = [&](size_t n)->ushortT*{ return (ushortT*)alloc((n + 1) / 2); };

  // flags + deg + cursor contiguous: one zeroing launch covers all
  int* flags  = (int*)alloc(4);
  int* deg    = (int*)alloc((size_t)N);
  int* cursor = (int*)alloc((size_t)N);
  size_t zeroHdr = off;                   // floats from d_ws start == ints
  int* zi     = (int*)alloc((size_t)N);
  int* bi     = (int*)alloc((size_t)N);
  int* eii    = (int*)alloc((size_t)2*E);
  int* rowptr = (int*)alloc((size_t)N + 4);
  int* jp     = (int*)alloc((size_t)E);
  int* ipp    = (int*)alloc((size_t)E);

  float* pos = alloc((size_t)N*3);
  float* w[31];
  for (int t = 0; t < 31; ++t) w[t] = alloc((size_t)in_sizes[4+t]);
  float* rl_b1=w[1];  float* rl_b2=w[3];
  float* ne_w =w[4];  float* ne_b =w[5];  float* sv_b =w[7];
  float* l3_w1=w[8];  float* l3_b1=w[9];  float* l3_w2=w[10]; float* l3_b2=w[11];
  float* mp_w =w[12]; float* mp_b =w[13]; float* xp_b1=w[15];
  float* xp_b2=w[17]; float* rp_b =w[19];
  float* ip_b1=w[21]; float* ip_b2=w[23];
  float* fte_b1=w[26];float* fte_b2=w[28];float* out_w=w[29]; float* out_b=w[30];

  ushortT* wt_rl1 = allocU(96*128);
  ushortT* wt_rl2 = allocU(128*128);
  ushortT* wt_sv  = allocU(128*128);
  ushortT* wt_xp1 = allocU(128*128);
  ushortT* wt_xp2 = allocU((size_t)128*384);
  ushortT* wt_rp  = allocU((size_t)96*384);
  ushortT* wt_ip1 = allocU((size_t)480*384);
  ushortT* wt_ip2 = allocU((size_t)384*384);
  ushortT* wt_feq = allocU((size_t)128*256);
  ushortT* wt_ft1 = allocU((size_t)256*128);
  ushortT* wt_ft2 = allocU((size_t)128*384);

  float* s    = alloc((size_t)N*HIDDIM);
  float* h0   = alloc((size_t)N*HIDDIM);      // dead after seg1 -> vdot overlay
  ushortT* sb     = allocU((size_t)N*HIDDIM);
  ushortT* slin_b = allocU((size_t)N*HIDDIM);
  ushortT* xln_b  = allocU((size_t)N*HIDDIM);
  ushortT* hb     = allocU((size_t)N*HIDDIM);
  float* S    = alloc((size_t)N*384);         // dead after scalarize -> xh2 overlay
  float* vecacc = alloc((size_t)N*384);
  ushortT* xh_b = allocU((size_t)N*384);
  ushortT* vab  = allocU((size_t)N*384);
  ushortT* catb = allocU((size_t)N*256);
  float* nodeout = alloc((size_t)N);
  float* vdot = h0;
  float* xh2  = S;

  size_t wsF = ws_size / sizeof(float);
  size_t availF = (wsF > off) ? (wsF - off) : 0;

  // tier2: persist all per-edge geometry (122 f/edge) + phase-E scratch (816 f/edge-chunk)
  const size_t persistP = (size_t)E*(3+6+1+48+64);
  bool tier2 = false; int C = 0;
  for (int c = 65536; c >= 4096; c >>= 1)
    if (persistP + (size_t)c*816 + 64 <= availF){ tier2 = true; C = c; break; }
  if (!tier2)
    for (int c = 32768; c >= 256; c >>= 1)
      if ((size_t)c*938 + 64 <= availF){ C = c; break; }
  if (C == 0){
    k_sentinel<<<1, 64, 0, stream>>>((__hip_bfloat16*)d_out, out_size,
                                     (float)(double)(ws_size >> 20));
    return;
  }

  // persistent per-edge arrays (tier2)
  float *edb_a=nullptr, *ecv_a=nullptr, *rb_a=nullptr;
  ushortT *remb_a=nullptr, *rhid_a=nullptr;
  if (tier2){
    edb_a  = alloc((size_t)3*E);
    ecv_a  = alloc((size_t)6*E);
    rb_a   = alloc((size_t)E);
    remb_a = allocU((size_t)E*96);
    rhid_a = allocU((size_t)E*128);
  }
  float* scratch0 = (float*)d_ws + off;
  // tier1 locals
  float *edb_l=nullptr, *ecv_l=nullptr, *rb_l=nullptr;
  ushortT *remb_l=nullptr, *rhid_l=nullptr;
  if (!tier2){
    edb_l  = alloc((size_t)3*C);
    ecv_l  = alloc((size_t)6*C);
    rb_l   = alloc((size_t)C);
    remb_l = allocU((size_t)C*96);
    rhid_l = allocU((size_t)C*128);
  }
  ushortT* ew_b = allocU((size_t)C*480);
  ushortT* R2b  = allocU((size_t)C*384);
  ushortT* R1b  = allocU((size_t)C*384);
  ushortT* Rmb  = allocU((size_t)C*384);
  float* vpc = scratch0;                  // phase-F overlay on chunk scratch
  size_t scratchF = (size_t)C*(tier2 ? 816 : 938);

  auto mg = [&](const ushortT* A, const ushortT* BT, const float* bias,
                float* Cf, ushortT* Cb, int M, int Nc, int K, int epi,
                const float* rowscale = nullptr, const ushortT* mul1b = nullptr,
                const ushortT* xhpb = nullptr, const int* jidx = nullptr){
    dim3 grid(Nc/128, (M + 127)/128);
    mgemm<<<grid, 256, 0, stream>>>(A, BT, bias, Cf, Cb, M, Nc, K, epi,
                                    rowscale, mul1b, xhpb, jidx);
  };

  // 0) zero flags+deg+cursor, detect dtypes, int-normalize (+deg histogram)
  k_zero<<<64, 256, 0, stream>>>((float*)flags, (int)(zeroHdr));
  k_detect<<<64, 256, 0, stream>>>((const ushortT*)d_in[0], in_sizes[0],
                                   (const int*)d_in[2], in_sizes[2], flags);
  k_iconv<<<1024, 256, 0, stream>>>((const int*)d_in[1], (const int*)d_in[2],
                                    (const int*)d_in[3], zi, bi, eii, N, E, flags, deg);

  // 1) float conversions + transposed bf16 weights
  ConvArgs ca;
  ca.d[0] = { (const ushortT*)d_in[0], pos, in_sizes[0] };
  for (int t = 0; t < 31; ++t)
    ca.d[1+t] = { (const ushortT*)d_in[4+t], w[t], in_sizes[4+t] };
  k_conv<<<dim3(32, 32), 256, 0, stream>>>(ca, 32, flags);

  TArgs ta;
  ta.d[0]  = { (const ushortT*)d_in[4],  wt_rl1, 96, 128 };
  ta.d[1]  = { (const ushortT*)d_in[6],  wt_rl2, 128, 128 };
  ta.d[2]  = { (const ushortT*)d_in[10], wt_sv,  128, 128 };
  ta.d[3]  = { (const ushortT*)d_in[18], wt_xp1, 128, 128 };
  ta.d[4]  = { (const ushortT*)d_in[20], wt_xp2, 128, 384 };
  ta.d[5]  = { (const ushortT*)d_in[22], wt_rp,  96, 384 };
  ta.d[6]  = { (const ushortT*)d_in[24], wt_ip1, 480, 384 };
  ta.d[7]  = { (const ushortT*)d_in[26], wt_ip2, 384, 384 };
  ta.d[8]  = { (const ushortT*)d_in[28], wt_feq, 128, 256 };
  ta.d[9]  = { (const ushortT*)d_in[29], wt_ft1, 256, 128 };
  ta.d[10] = { (const ushortT*)d_in[31], wt_ft2, 128, 384 };
  k_wt<<<dim3(48, 11), 256, 0, stream>>>(ta, 11, flags);

  // 2) CSR scan + scatter
  k_csr_scan<<<1, 256, 0, stream>>>(deg, rowptr, N);
  k_csr_scatter<<<(E + 255)/256, 256, 0, stream>>>(eii, E, rowptr, cursor, jp, ipp);

  // 3) node embedding (+ S/vecacc zero fused)
  k_embed<<<N, 128, 0, stream>>>(zi, ne_w, ne_b, s, h0, S, vecacc);

  if (tier2){
    // geometry once, rl MLP in as few chunks as the scratch allows
    k_geom<<<(E + 255)/256, 256, 0, stream>>>(pos, jp, ipp, 0, E, edb_a, ecv_a, rb_a, remb_a);
    int Crl = (int)(scratchF / 64);      // bf16 C x 128 temp inside scratch
    if (Crl > E) Crl = E;
    ushortT* R2rl = (ushortT*)scratch0;
    for (int o = 0; o < E; o += Crl){
      int Cc = (E - o < Crl) ? (E - o) : Crl;
      mg(remb_a + (size_t)o*96, wt_rl1, rl_b1, nullptr, R2rl, Cc, 128, 96, 1);
      mg(R2rl, wt_rl2, rl_b2, nullptr, rhid_a + (size_t)o*128, Cc, 128, 128, 2, rb_a + o);
    }
    k_seg1_run<<<((size_t)E*128 + 255)/256, 256, 0, stream>>>(jp, ipp, 0, E, h0, rhid_a, s);
  } else {
    for (int o = 0; o < E; o += C){
      int Cc = (E - o < C) ? (E - o) : C;
      k_geom<<<(Cc + 255)/256, 256, 0, stream>>>(pos, jp, ipp, o, Cc, edb_l, ecv_l, rb_l, remb_l);
      mg(remb_l, wt_rl1, rl_b1, nullptr, R2b, Cc, 128, 96, 1);
      mg(R2b, wt_rl2, rl_b2, nullptr, rhid_l, Cc, 128, 128, 2, rb_l);
      k_seg1_run<<<((size_t)Cc*128 + 255)/256, 256, 0, stream>>>(jp, ipp, o, Cc, h0, rhid_l, s);
    }
  }

  // Phase C: slin, xln(+sb), xh
  k_ln<<<N, 128, 0, stream>>>(s, xln_b, mp_w, mp_b, sb);
  mg(sb, wt_sv, sv_b, nullptr, slin_b, N, 128, 128, 1);
  mg(xln_b, wt_xp1, xp_b1, nullptr, hb, N, 128, 128, 1);
  mg(hb, wt_xp2, xp_b2, nullptr, xh_b, N, 384, 128, 0);

  // Phase D: seg2
  if (tier2){
    k_seg2_run<<<((size_t)E*128 + 255)/256, 256, 0, stream>>>(jp, ipp, 0, E, slin_b, rhid_a, edb_a, S);
  } else {
    for (int o = 0; o < E; o += C){
      int Cc = (E - o < C) ? (E - o) : C;
      k_geom<<<(Cc + 255)/256, 256, 0, stream>>>(pos, jp, ipp, o, Cc, edb_l, ecv_l, rb_l, remb_l);
      mg(remb_l, wt_rl1, rl_b1, nullptr, R2b, Cc, 128, 96, 1);
      mg(R2b, wt_rl2, rl_b2, nullptr, rhid_l, Cc, 128, 128, 2, rb_l);
      k_seg2_run<<<((size_t)Cc*128 + 255)/256, 256, 0, stream>>>(jp, ipp, o, Cc, slin_b, rhid_l, edb_l, S);
    }
  }

  // Phase E: per-edge big MLPs + seg3
  for (int o = 0; o < E; o += C){
    int Cc = (E - o < C) ? (E - o) : C;
    const float *edb_p, *ecv_p, *rb_p; const ushortT *remb_p, *rhid_p;
    if (tier2){
      edb_p = edb_a + (size_t)3*o; ecv_p = ecv_a + (size_t)6*o; rb_p = rb_a + o;
      remb_p = remb_a + (size_t)o*96; rhid_p = rhid_a + (size_t)o*128;
    } else {
      k_geom<<<(Cc + 255)/256, 256, 0, stream>>>(pos, jp, ipp, o, Cc, edb_l, ecv_l, rb_l, remb_l);
      mg(remb_l, wt_rl1, rl_b1, nullptr, R2b, Cc, 128, 96, 1);
      mg(R2b, wt_rl2, rl_b2, nullptr, rhid_l, Cc, 128, 128, 2, rb_l);
      edb_p = edb_l; ecv_p = ecv_l; rb_p = rb_l; remb_p = remb_l; rhid_p = rhid_l;
    }
    k_scalarize<<<Cc, 256, 0, stream>>>(jp, ipp, o, S, edb_p, ecv_p, rb_p,
                                        rhid_p, remb_p,
                                        l3_w1, l3_b1, l3_w2, l3_b2, ew_b);
    mg(remb_p, wt_rp, rp_b, nullptr, R1b, Cc, 384, 96, 0);
    mg(ew_b, wt_ip1, ip_b1, nullptr, R2b, Cc, 384, 480, 1);
    mg(R2b, wt_ip2, ip_b2, nullptr, Rmb, Cc, 384, 384, 3, nullptr, R1b, xh_b, jp + o);
    k_seg3_run<<<((size_t)Cc*128 + 255)/256, 256, 0, stream>>>(ipp, o, Cc, Rmb, edb_p, s, vecacc);
  }

  // Phase F: fte
  k_f2b<<<1024, 256, 0, stream>>>(vecacc, vab, N*384);
  int Cn = (int)(scratchF / 768);
  if (Cn > N) Cn = N;
  for (int no = 0; no < N; no += Cn){
    int Cc = (N - no < Cn) ? (N - no) : Cn;
    mg(vab + (size_t)no*384, wt_feq, nullptr, vpc, nullptr, 3*Cc, 256, 128, 0);
    k_fte_pre<<<Cc, 128, 0, stream>>>(vpc, s, catb, vdot, no);
  }
  mg(catb, wt_ft1, fte_b1, nullptr, hb, N, 128, 256, 1);
  mg(hb, wt_ft2, fte_b2, xh2, nullptr, N, 384, 128, 0);

  // Phase G
  k_out<<<N, 128, 0, stream>>>(xh2, vdot, s, out_w, out_b, nodeout);
  k_final<<<out_size, 256, 0, stream>>>(nodeout, bi, d_out, N, flags);
}

// Round 7
// 2562.697 us; speedup vs baseline: 3.0665x; 1.0863x over previous
//
#include <hip/hip_runtime.h>
#include <hip/hip_bf16.h>
#include <math.h>

#define NRAD 96
#define HIDDIM 128
typedef unsigned short ushortT;

typedef __attribute__((ext_vector_type(8))) short bf8_t;   // 8 bf16 (4 VGPRs)
typedef __attribute__((ext_vector_type(4))) float f4_t;    // 4 fp32 acc

#if defined(__has_builtin)
#  if __has_builtin(__builtin_amdgcn_global_load_lds)
#    define HAVE_GLDS 1
#  endif
#endif

__device__ __forceinline__ float silu_f(float x){ return x / (1.f + __expf(-x)); }
__device__ __forceinline__ float b2f(ushortT u){ return __uint_as_float(((unsigned int)u) << 16); }
__device__ __forceinline__ ushortT f2b(float x){
  unsigned int u = __float_as_uint(x);
  unsigned int r = (u + 0x7fffu + ((u >> 16) & 1u)) >> 16;
  return (ushortT)r;
}

#ifdef HAVE_GLDS
__device__ __forceinline__ void glds16(const ushortT* g, ushortT* l){
  __builtin_amdgcn_global_load_lds(
      (const __attribute__((address_space(1))) ushortT*)g,
      (__attribute__((address_space(3))) ushortT*)l, 16, 0, 0);
}
#endif

// ---------------- dtype detection (parallel) ----------------
// flags[2] != 0  => floats are fp32 ; flags[3] != 0 => ints are int32
__global__ void k_detect(const ushortT* posw, int npos,
                         const int* batchw, int nb, int* flags){
  int tot = (npos < 4096 ? npos : 4096);
  int big = tot > nb ? tot : nb;
  int bad = 0, orv = 0;
  for (int t = blockIdx.x*blockDim.x + threadIdx.x; t < big; t += gridDim.x*blockDim.x){
    if (t < tot){
      float x = b2f(posw[t]);
      if (!(fabsf(x) <= 1000.f)) bad = 1;
    }
    if (t < nb && (t & 1)) orv |= batchw[t];
  }
  if (bad) atomicOr(&flags[2], 1);
  if (orv) atomicOr(&flags[3], 1);
}

// normalize int inputs to int32; also builds CSR degree histogram
__global__ void k_iconv(const int* zsrc, const int* bsrc, const int* esrc,
                        int* zi, int* bi, int* eii, int Nn, int E, const int* flags,
                        int* deg){
  int f = (flags[3] == 0) ? 1 : 0;   // 1 => int64
  int total = 2*Nn + 2*E;
  for (int t = blockIdx.x*blockDim.x + threadIdx.x; t < total; t += gridDim.x*blockDim.x){
    if (t < Nn) zi[t] = zsrc[(size_t)t << f];
    else if (t < 2*Nn) bi[t-Nn] = bsrc[(size_t)(t-Nn) << f];
    else {
      int e = t - 2*Nn;
      int v = esrc[(size_t)e << f];
      eii[e] = v;
      if (e >= E) atomicAdd(&deg[v], 1);
    }
  }
}

// ---------------- conversion: (bf16|f32) -> f32 ----------------
struct ConvDesc { const ushortT* src; float* dst; int n; };
struct ConvArgs { ConvDesc d[32]; };

__global__ void k_conv(ConvArgs a, int cnt, const int* flags){
  int y = blockIdx.y;
  if (y >= cnt) return;
  int f = (flags[2] == 0) ? 1 : 0;    // 1 => bf16
  const ushortT* s = a.d[y].src;
  float* dst = a.d[y].dst;
  int n = a.d[y].n;
  if (f){
    for (int t = blockIdx.x*blockDim.x + threadIdx.x; t < n; t += gridDim.x*blockDim.x)
      dst[t] = b2f(s[t]);
  } else {
    const float* sf = (const float*)s;
    for (int t = blockIdx.x*blockDim.x + threadIdx.x; t < n; t += gridDim.x*blockDim.x)
      dst[t] = sf[t];
  }
}

// ---------------- weight transpose -> bf16 [N][K] ----------------
struct TDesc { const ushortT* src; ushortT* dst; int K, N; };
struct TArgs { TDesc d[12]; };

__global__ void k_wt(TArgs a, int cnt, const int* flags){
  int y = blockIdx.y;
  if (y >= cnt) return;
  int f = (flags[2] == 0) ? 1 : 0;
  const ushortT* s = a.d[y].src;
  ushortT* dst = a.d[y].dst;
  int K = a.d[y].K, N = a.d[y].N, tot = K*N;
  for (int t = blockIdx.x*blockDim.x + threadIdx.x; t < tot; t += gridDim.x*blockDim.x){
    int k = t / N, n = t - k*N;
    ushortT v = f ? s[t] : f2b(((const float*)s)[t]);
    dst[(size_t)n*K + k] = v;
  }
}

__global__ void k_f2b(const float* __restrict__ src, ushortT* __restrict__ dst, int n){
  for (int t = blockIdx.x*blockDim.x + threadIdx.x; t < n; t += gridDim.x*blockDim.x)
    dst[t] = f2b(src[t]);
}

__global__ void k_zero(float* __restrict__ p, int n){
  int t = blockIdx.x*blockDim.x + threadIdx.x;
  int stride = gridDim.x*blockDim.x;
  for (; t < n; t += stride) p[t] = 0.f;
}

__global__ void k_sentinel(__hip_bfloat16* out, int n, float val){
  int t = threadIdx.x;
  if (t < n) out[t] = __float2bfloat16(val);
}

// ---------------- CSR scan + scatter ----------------
__global__ void k_csr_scan(const int* __restrict__ deg, int* __restrict__ rowptr, int Nn){
  __shared__ int sh[256];
  __shared__ int carry;
  if (threadIdx.x == 0){ carry = 0; rowptr[0] = 0; }
  __syncthreads();
  for (int t0 = 0; t0 < Nn; t0 += 256){
    int idx = t0 + threadIdx.x;
    int v = (idx < Nn) ? deg[idx] : 0;
    sh[threadIdx.x] = v; __syncthreads();
    for (int o = 1; o < 256; o <<= 1){
      int u = (threadIdx.x >= o) ? sh[threadIdx.x - o] : 0;
      __syncthreads();
      sh[threadIdx.x] += u; __syncthreads();
    }
    if (idx < Nn) rowptr[idx + 1] = carry + sh[threadIdx.x];
    __syncthreads();
    if (threadIdx.x == 0) carry += sh[255];
    __syncthreads();
  }
}

__global__ void k_csr_scatter(const int* __restrict__ eii, int E,
                              const int* __restrict__ rowptr, int* __restrict__ cursor,
                              int* __restrict__ jp, int* __restrict__ ip){
  int e = blockIdx.x*blockDim.x + threadIdx.x;
  if (e >= E) return;
  int i = eii[E+e];
  int p = atomicAdd(&cursor[i], 1);
  int k = rowptr[i] + p;
  jp[k] = eii[e];
  ip[k] = i;
}

// ---------------- geometry + RBF (pre-pass / tier0) ----------------
__global__ void k_geom(const float* __restrict__ pos,
                       const int* __restrict__ jp, const int* __restrict__ ip,
                       int off, int Cc,
                       float* __restrict__ edb, float* __restrict__ ecv,
                       float* __restrict__ rb, ushortT* __restrict__ remb)
{
  int el = blockIdx.x*blockDim.x + threadIdx.x;
  if (el >= Cc) return;
  int g = off + el;
  int j = jp[g], i = ip[g];
  float pjx = pos[3*j], pjy = pos[3*j+1], pjz = pos[3*j+2];
  float pix = pos[3*i], piy = pos[3*i+1], piz = pos[3*i+2];
  float vx = pjx-pix, vy = pjy-piy, vz = pjz-piz;
  float d = sqrtf(vx*vx + vy*vy + vz*vz);
  float inv = 1.f/(d + 1e-10f);
  float edx = vx*inv, edy = vy*inv, edz = vz*inv;
  float cx = piy*pjz - piz*pjy;
  float cy = piz*pjx - pix*pjz;
  float cz = pix*pjy - piy*pjx;
  float cn = sqrtf(cx*cx + cy*cy + cz*cz);
  float inv2 = 1.f/(cn + 1e-10f);
  cx *= inv2; cy *= inv2; cz *= inv2;
  float evx = edy*cz - edz*cy;
  float evy = edz*cx - edx*cz;
  float evz = edx*cy - edy*cx;
  edb[3*el]=edx; edb[3*el+1]=edy; edb[3*el+2]=edz;
  ecv[6*el]=cx; ecv[6*el+1]=cy; ecv[6*el+2]=cz;
  ecv[6*el+3]=evx; ecv[6*el+4]=evy; ecv[6*el+5]=evz;
  float rbv = 0.5f*(cosf(d*0.52359877559829887f) + 1.f);
  rb[el] = rbv;
  float env = (d < 6.f) ? rbv : 0.f;
  const float stf = 0.0024787522f;
  const float prf = (2.0f/96.0f)*(1.0f - stf);
  const float beta = 1.0f/(prf*prf);
  float emd = __expf(-d);
  for (int k = 0; k < NRAD; ++k){
    float mu = stf + (1.0f - stf)*((float)k*(1.0f/95.0f));
    float t = emd - mu;
    remb[(size_t)el*NRAD + k] = f2b(env * __expf(-beta*t*t));
  }
}

// ---------------- node embedding + layernorm (+ fused accumulator zeroing) ----------------
__global__ __launch_bounds__(128) void k_embed(const int* __restrict__ z,
    const float* __restrict__ ne_w, const float* __restrict__ ne_b,
    float* __restrict__ s, float* __restrict__ h0,
    float* __restrict__ S, float* __restrict__ vecacc)
{
  int n = blockIdx.x; int h = threadIdx.x;
  float x = ne_w[(size_t)z[n]*HIDDIM + h] + ne_b[h];
  __shared__ float red[128];
  red[h] = x; __syncthreads();
  for (int o = 64; o > 0; o >>= 1){ if (h < o) red[h] += red[h+o]; __syncthreads(); }
  float mean = red[0] * (1.f/128.f);
  __syncthreads();
  float dx = x - mean;
  red[h] = dx*dx; __syncthreads();
  for (int o = 64; o > 0; o >>= 1){ if (h < o) red[h] += red[h+o]; __syncthreads(); }
  float var = red[0] * (1.f/128.f);
  float y = dx * rsqrtf(var + 1e-5f);
  s[(size_t)n*HIDDIM + h] = y;
  h0[(size_t)n*HIDDIM + h] = y;
  float* Sr = &S[(size_t)n*384 + h];
  float* Vr = &vecacc[(size_t)n*384 + h];
  Sr[0]=0.f; Sr[128]=0.f; Sr[256]=0.f;
  Vr[0]=0.f; Vr[128]=0.f; Vr[256]=0.f;
}

// LN -> xln_b, plus fused s -> sb conversion
__global__ __launch_bounds__(128) void k_ln(const float* __restrict__ src, ushortT* __restrict__ dst,
    const float* __restrict__ g, const float* __restrict__ b, ushortT* __restrict__ sb)
{
  int n = blockIdx.x; int h = threadIdx.x;
  float x = src[(size_t)n*HIDDIM + h];
  sb[(size_t)n*HIDDIM + h] = f2b(x);
  __shared__ float red[128];
  red[h] = x; __syncthreads();
  for (int o = 64; o > 0; o >>= 1){ if (h < o) red[h] += red[h+o]; __syncthreads(); }
  float mean = red[0] * (1.f/128.f);
  __syncthreads();
  float dx = x - mean;
  red[h] = dx*dx; __syncthreads();
  for (int o = 64; o > 0; o >>= 1){ if (h < o) red[h] += red[h+o]; __syncthreads(); }
  float var = red[0] * (1.f/128.f);
  float y = dx * rsqrtf(var + 1e-5f);
  dst[(size_t)n*HIDDIM + h] = f2b(y * g[h] + b[h]);
}

// ---------------- rowptr-based segment sums (one block per node) ----------------
// window [o, o+Cc); per-edge arrays indexed locally (m - o)
__global__ __launch_bounds__(128) void k_seg1n(const int* __restrict__ rowptr,
    const int* __restrict__ jp, int o, int Cc,
    const float* __restrict__ h0, const ushortT* __restrict__ rhid,
    float* __restrict__ s)
{
  int i = blockIdx.x, h = threadIdx.x;
  int b = rowptr[i], e = rowptr[i+1];
  if (b < o) b = o;
  int hi = o + Cc; if (e > hi) e = hi;
  if (b >= e) return;
  float acc = 0.f;
  int m = b;
  for (; m + 1 < e; m += 2){
    int j0 = jp[m], j1 = jp[m+1];
    float r0 = b2f(rhid[(size_t)(m-o)*HIDDIM + h]);
    float r1 = b2f(rhid[(size_t)(m+1-o)*HIDDIM + h]);
    acc += h0[(size_t)j0*HIDDIM + h]*r0 + h0[(size_t)j1*HIDDIM + h]*r1;
  }
  if (m < e) acc += h0[(size_t)jp[m]*HIDDIM + h] * b2f(rhid[(size_t)(m-o)*HIDDIM + h]);
  s[(size_t)i*HIDDIM + h] += acc;
}

__global__ __launch_bounds__(128) void k_seg2n(const int* __restrict__ rowptr,
    const int* __restrict__ jp, int o, int Cc,
    const ushortT* __restrict__ slin, const ushortT* __restrict__ rhid,
    const float* __restrict__ edb, float* __restrict__ S)
{
  int i = blockIdx.x, h = threadIdx.x;
  int b = rowptr[i], e = rowptr[i+1];
  if (b < o) b = o;
  int hi = o + Cc; if (e > hi) e = hi;
  if (b >= e) return;
  float a0 = 0.f, a1 = 0.f, a2 = 0.f;
  for (int m = b; m < e; ++m){
    int ml = m - o;
    float val = b2f(slin[(size_t)jp[m]*HIDDIM + h]) * b2f(rhid[(size_t)ml*HIDDIM + h]);
    a0 += val*edb[3*ml]; a1 += val*edb[3*ml+1]; a2 += val*edb[3*ml+2];
  }
  float* base = &S[(size_t)i*384 + h];
  base[0]   += a0;
  base[128] += a1;
  base[256] += a2;
}

__global__ __launch_bounds__(128) void k_seg3n(const int* __restrict__ rowptr,
    int o, int Cc,
    const ushortT* __restrict__ mb, const float* __restrict__ edb,
    float* __restrict__ s, float* __restrict__ vecacc)
{
  int i = blockIdx.x, h = threadIdx.x;
  int b = rowptr[i], e = rowptr[i+1];
  if (b < o) b = o;
  int hi = o + Cc; if (e > hi) e = hi;
  if (b >= e) return;
  const float is128 = 0.08838834764831845f;
  float am = 0.f, v0 = 0.f, v1 = 0.f, v2 = 0.f;
  for (int m = b; m < e; ++m){
    int ml = m - o;
    float m1 = b2f(mb[(size_t)ml*384 + h]);
    float mm = b2f(mb[(size_t)ml*384 + 256 + h]) * is128;
    am += m1;
    v0 += mm*edb[3*ml]; v1 += mm*edb[3*ml+1]; v2 += mm*edb[3*ml+2];
  }
  s[(size_t)i*HIDDIM + h] += am;
  float* base = &vecacc[(size_t)i*384 + h];
  base[0]   += v0;
  base[128] += v1;
  base[256] += v2;
}

// ---------------- fused geometry + scalarize + ew assembly ----------------
// block = 1 edge, 256 threads: which = t>>7 (0 -> S[i], 1 -> S[j]), h = t&127
__global__ __launch_bounds__(256) void k_scal2(
  const int* __restrict__ jp, const int* __restrict__ ip, int off,
  const float* __restrict__ pos, const float* __restrict__ S,
  const ushortT* __restrict__ rhid,
  const float* __restrict__ w1, const float* __restrict__ b1,
  const float* __restrict__ w2, const float* __restrict__ b2,
  ushortT* __restrict__ ew, ushortT* __restrict__ remb)
{
  int el = blockIdx.x;
  int g = off + el;
  int which = threadIdx.x >> 7;
  int h = threadIdx.x & 127;
  int j = jp[g], i = ip[g];
  float pjx = pos[3*j], pjy = pos[3*j+1], pjz = pos[3*j+2];
  float pix = pos[3*i], piy = pos[3*i+1], piz = pos[3*i+2];
  float vx = pjx-pix, vy = pjy-piy, vz = pjz-piz;
  float d = sqrtf(vx*vx + vy*vy + vz*vz);
  float inv = 1.f/(d + 1e-10f);
  float f00 = vx*inv, f01 = vy*inv, f02 = vz*inv;
  float cx = piy*pjz - piz*pjy;
  float cy = piz*pjx - pix*pjz;
  float cz = pix*pjy - piy*pjx;
  float cn = sqrtf(cx*cx + cy*cy + cz*cz);
  float inv2 = 1.f/(cn + 1e-10f);
  float f10 = cx*inv2, f11 = cy*inv2, f12 = cz*inv2;
  float f20 = f01*f12 - f02*f11;
  float f21 = f02*f10 - f00*f12;
  float f22 = f00*f11 - f01*f10;
  float rbv = 0.5f*(cosf(d*0.52359877559829887f) + 1.f);
  int n = which ? j : i;
  const float* Sn = &S[(size_t)n*384];
  float S0 = Sn[h], S1 = Sn[128+h], S2 = Sn[256+h];
  float v0 = S0*f00 + S1*f01 + S2*f02;
  float v1 = fabsf(S0*f10 + S1*f11 + S2*f12);
  float v2 = S0*f20 + S1*f21 + S2*f22;
  float out = b2[0];
  #pragma unroll
  for (int u = 0; u < 32; ++u){
    float t = v0*w1[u] + v1*w1[32+u] + v2*w1[64+u] + b1[u];
    out += silu_f(t) * w2[u];
  }
  float scal = out + v0;
  ushortT* ewr = &ew[(size_t)el*480];
  ewr[which*128 + h] = f2b(scal * rbv);
  if (which == 0){
    ewr[256 + h] = rhid[(size_t)el*HIDDIM + h];
    if (h < NRAD){
      float env = (d < 6.f) ? rbv : 0.f;
      const float stf = 0.0024787522f;
      const float prf = (2.0f/96.0f)*(1.0f - stf);
      const float beta = 1.0f/(prf*prf);
      float mu = stf + (1.0f - stf)*((float)h*(1.0f/95.0f));
      float t = __expf(-d) - mu;
      ushortT rv = f2b(env * __expf(-beta*t*t));
      ewr[384 + h] = rv;
      remb[(size_t)el*NRAD + h] = rv;
    }
  }
}

// ---------------- bf16 MFMA GEMM ----------------
// A: MxK bf16 row-major; BT: NxK bf16 row-major. N%128==0, K%32==0.
// epi: 0 none, 1 silu, 2 *rowscale[row], 3 *mul1b[row,col]*xhpb[jidx[row],col]
__global__ __launch_bounds__(256) void mgemm(
  const ushortT* __restrict__ A, const ushortT* __restrict__ BT,
  const float* __restrict__ bias,
  float* __restrict__ Cf, ushortT* __restrict__ Cb,
  int M, int N, int K, int epi,
  const float* __restrict__ rowscale,
  const ushortT* __restrict__ mul1b,
  const ushortT* __restrict__ xhpb,
  const int* __restrict__ jidx)
{
  const int tid = threadIdx.x;
  const int w = tid >> 6;
  const int lane = tid & 63;
  const int l15 = lane & 15;
  const int q = lane >> 4;
  const int wm = w & 1, wn = w >> 1;
  const int rowBase = blockIdx.y * 128;
  const int colBase = blockIdx.x * 128;
  f4_t acc[4][4] = {};

#ifdef HAVE_GLDS
  __shared__ ushortT As[128*32];
  __shared__ ushortT Bs[128*32];
  const int rS = 32*w + (lane >> 2);
  const int kS = (lane & 3) << 3;
  ushortT* lA0 = &As[(32*w)*32];
  ushortT* lA1 = &As[(32*w+16)*32];
  ushortT* lB0 = &Bs[(32*w)*32];
  ushortT* lB1 = &Bs[(32*w+16)*32];
  int ra0 = rowBase + rS;      if (ra0 >= M) ra0 = M-1;
  int ra1 = rowBase + rS + 16; if (ra1 >= M) ra1 = M-1;
  const ushortT* gA0 = A  + (size_t)ra0*K + kS;
  const ushortT* gA1 = A  + (size_t)ra1*K + kS;
  const ushortT* gB0 = BT + (size_t)(colBase + rS)*K + kS;
  const ushortT* gB1 = BT + (size_t)(colBase + rS + 16)*K + kS;
  for (int k0 = 0; k0 < K; k0 += 32){
    glds16(gA0 + k0, lA0);
    glds16(gA1 + k0, lA1);
    glds16(gB0 + k0, lB0);
    glds16(gB1 + k0, lB1);
    __syncthreads();
    bf8_t a[4], b[4];
    #pragma unroll
    for (int mt = 0; mt < 4; ++mt)
      a[mt] = *(const bf8_t*)&As[(wm*64 + mt*16 + l15)*32 + q*8];
    #pragma unroll
    for (int nt = 0; nt < 4; ++nt)
      b[nt] = *(const bf8_t*)&Bs[(wn*64 + nt*16 + l15)*32 + q*8];
    #pragma unroll
    for (int mt = 0; mt < 4; ++mt){
      #pragma unroll
      for (int nt = 0; nt < 4; ++nt)
        acc[mt][nt] = __builtin_amdgcn_mfma_f32_16x16x32_bf16(a[mt], b[nt], acc[mt][nt], 0, 0, 0);
    }
    __syncthreads();
  }
#else
  __shared__ ushortT As[128*48];
  __shared__ ushortT Bs[128*48];
  const int r0 = tid >> 2,         s0 = (tid & 3) << 3;
  const int r1 = (tid + 256) >> 2, s1 = ((tid + 256) & 3) << 3;
  for (int k0 = 0; k0 < K; k0 += 32){
    int4 a0v = make_int4(0,0,0,0), a1v = make_int4(0,0,0,0);
    if (rowBase + r0 < M) a0v = *(const int4*)&A[(size_t)(rowBase + r0)*K + k0 + s0];
    if (rowBase + r1 < M) a1v = *(const int4*)&A[(size_t)(rowBase + r1)*K + k0 + s1];
    int4 b0v = *(const int4*)&BT[(size_t)(colBase + r0)*K + k0 + s0];
    int4 b1v = *(const int4*)&BT[(size_t)(colBase + r1)*K + k0 + s1];
    __syncthreads();
    *(int4*)&As[r0*48 + s0] = a0v;
    *(int4*)&As[r1*48 + s1] = a1v;
    *(int4*)&Bs[r0*48 + s0] = b0v;
    *(int4*)&Bs[r1*48 + s1] = b1v;
    __syncthreads();
    bf8_t a[4], b[4];
    #pragma unroll
    for (int mt = 0; mt < 4; ++mt)
      a[mt] = *(const bf8_t*)&As[(wm*64 + mt*16 + l15)*48 + q*8];
    #pragma unroll
    for (int nt = 0; nt < 4; ++nt)
      b[nt] = *(const bf8_t*)&Bs[(wn*64 + nt*16 + l15)*48 + q*8];
    #pragma unroll
    for (int mt = 0; mt < 4; ++mt){
      #pragma unroll
      for (int nt = 0; nt < 4; ++nt)
        acc[mt][nt] = __builtin_amdgcn_mfma_f32_16x16x32_bf16(a[mt], b[nt], acc[mt][nt], 0, 0, 0);
    }
  }
#endif

  #pragma unroll
  for (int mt = 0; mt < 4; ++mt){
    int row = rowBase + wm*64 + mt*16 + q*4;
    #pragma unroll
    for (int nt = 0; nt < 4; ++nt){
      int col = colBase + wn*64 + nt*16 + l15;
      float bv = bias ? bias[col] : 0.f;
      #pragma unroll
      for (int r = 0; r < 4; ++r){
        int rr = row + r;
        if (rr >= M) continue;
        float x = acc[mt][nt][r] + bv;
        if (epi == 1) x = silu_f(x);
        else if (epi == 2) x *= rowscale[rr];
        else if (epi == 3) x = x * b2f(mul1b[(size_t)rr*N + col]) * b2f(xhpb[(size_t)jidx[rr]*N + col]);
        if (Cb) Cb[(size_t)rr*N + col] = f2b(x);
        else    Cf[(size_t)rr*N + col] = x;
      }
    }
  }
}

// ---------------- fte prep ----------------
__global__ __launch_bounds__(128) void k_fte_pre(const float* __restrict__ vpc,
    const float* __restrict__ s, ushortT* __restrict__ catb, float* __restrict__ vdot,
    int no)
{
  int nl = blockIdx.x, h = threadIdx.x;
  int n = no + nl;
  const float* base = &vpc[(size_t)nl*768];
  float a0 = base[h],       a1 = base[256+h],     a2 = base[512+h];
  float c0 = base[128+h],   c1 = base[384+h],     c2 = base[640+h];
  float scal = sqrtf(a0*a0 + a1*a1 + a2*a2 + 1e-10f);
  float vd = (a0*c0 + a1*c1 + a2*c2) * 0.08838834764831845f;
  catb[(size_t)n*256 + h] = f2b(s[(size_t)n*HIDDIM + h]);
  catb[(size_t)n*256 + 128 + h] = f2b(scal);
  vdot[(size_t)n*HIDDIM + h] = vd;
}

// ---------------- final ----------------
__global__ __launch_bounds__(128) void k_out(const float* __restrict__ xh2,
    const float* __restrict__ vdot, const float* __restrict__ s,
    const float* __restrict__ ow, const float* __restrict__ ob,
    float* __restrict__ nodeout)
{
  int n = blockIdx.x, h = threadIdx.x;
  float a1 = xh2[(size_t)n*384 + h];
  float a2 = xh2[(size_t)n*384 + 128 + h];
  float sv = s[(size_t)n*HIDDIM + h] + (a1 + a2*vdot[(size_t)n*HIDDIM + h]) * 0.7071067811865476f;
  __shared__ float red[128];
  red[h] = sv * ow[h];
  __syncthreads();
  for (int o = 64; o > 0; o >>= 1){ if (h < o) red[h] += red[h+o]; __syncthreads(); }
  if (h == 0) nodeout[n] = red[0] + ob[0];
}

__global__ __launch_bounds__(256) void k_final(const float* __restrict__ nodeout,
    const int* __restrict__ batch, void* __restrict__ out, int Nn, const int* flags)
{
  int g = blockIdx.x;
  __shared__ float rs[256], rc[256];
  float sm = 0.f, c = 0.f;
  for (int n = threadIdx.x; n < Nn; n += 256){
    if (batch[n] == g){ sm += nodeout[n]; c += 1.f; }
  }
  rs[threadIdx.x] = sm; rc[threadIdx.x] = c;
  __syncthreads();
  for (int o = 128; o > 0; o >>= 1){
    if (threadIdx.x < o){ rs[threadIdx.x] += rs[threadIdx.x+o]; rc[threadIdx.x] += rc[threadIdx.x+o]; }
    __syncthreads();
  }
  if (threadIdx.x == 0){
    float v = (rc[0] > 0.f) ? rs[0]/rc[0] : 0.f;
    if (flags[2] == 0) ((__hip_bfloat16*)out)[g] = __float2bfloat16(v);
    else ((float*)out)[g] = v;
  }
}

// =====================================================================
extern "C" void kernel_launch(void* const* d_in, const int* in_sizes, int n_in,
                              void* d_out, int out_size, void* d_ws, size_t ws_size,
                              hipStream_t stream)
{
  const int N = in_sizes[0] / 3;
  const int E = in_sizes[3] / 2;

  size_t off = 0;
  auto alloc = [&](size_t n)->float*{
    float* p = (float*)d_ws + off;
    off += (n + 3) & ~(size_t)3;
    return p;
  };
  auto allocU = [&](size_t n)->ushortT*{ return (ushortT*)alloc((n + 1) / 2); };

  int* flags  = (int*)alloc(4);
  int* deg    = (int*)alloc((size_t)N);
  int* cursor = (int*)alloc((size_t)N);
  size_t zeroHdr = off;
  int* zi     = (int*)alloc((size_t)N);
  int* bi     = (int*)alloc((size_t)N);
  int* eii    = (int*)alloc((size_t)2*E);
  int* rowptr = (int*)alloc((size_t)N + 4);
  int* jp     = (int*)alloc((size_t)E);
  int* ipp    = (int*)alloc((size_t)E);

  float* pos = alloc((size_t)N*3);
  float* w[31];
  for (int t = 0; t < 31; ++t) w[t] = alloc((size_t)in_sizes[4+t]);
  float* rl_b1=w[1];  float* rl_b2=w[3];
  float* ne_w =w[4];  float* ne_b =w[5];  float* sv_b =w[7];
  float* l3_w1=w[8];  float* l3_b1=w[9];  float* l3_w2=w[10]; float* l3_b2=w[11];
  float* mp_w =w[12]; float* mp_b =w[13]; float* xp_b1=w[15];
  float* xp_b2=w[17]; float* rp_b =w[19];
  float* ip_b1=w[21]; float* ip_b2=w[23];
  float* fte_b1=w[26];float* fte_b2=w[28];float* out_w=w[29]; float* out_b=w[30];

  ushortT* wt_rl1 = allocU(96*128);
  ushortT* wt_rl2 = allocU(128*128);
  ushortT* wt_sv  = allocU(128*128);
  ushortT* wt_xp1 = allocU(128*128);
  ushortT* wt_xp2 = allocU((size_t)128*384);
  ushortT* wt_rp  = allocU((size_t)96*384);
  ushortT* wt_ip1 = allocU((size_t)480*384);
  ushortT* wt_ip2 = allocU((size_t)384*384);
  ushortT* wt_feq = allocU((size_t)128*256);
  ushortT* wt_ft1 = allocU((size_t)256*128);
  ushortT* wt_ft2 = allocU((size_t)128*384);

  float* s    = alloc((size_t)N*HIDDIM);
  float* h0   = alloc((size_t)N*HIDDIM);      // -> vdot overlay after seg1
  ushortT* sb     = allocU((size_t)N*HIDDIM); // sb+slin_b contiguous -> catb overlay
  ushortT* slin_b = allocU((size_t)N*HIDDIM);
  ushortT* xln_b  = allocU((size_t)N*HIDDIM);
  ushortT* hb     = allocU((size_t)N*HIDDIM);
  float* S    = alloc((size_t)N*384);         // -> vab overlay in phase F
  float* vecacc = alloc((size_t)N*384);       // -> xh2 overlay after f2b
  ushortT* xh_b = allocU((size_t)N*384);
  float* nodeout = alloc((size_t)N);
  float* vdot = h0;
  ushortT* catb = sb;
  ushortT* vab = (ushortT*)S;
  float* xh2 = vecacc;

  size_t wsF = ws_size / sizeof(float);

  // tier selection: tier1 persists rhid (bf16) + edb (fp32) for all E
  int tier = 0;
  size_t p = 739;                         // per-edge chunk floats (tier0)
  if (off + 67ULL*(size_t)E + 16 + 1024ULL*672 <= wsF){ tier = 1; p = 672; }
  ushortT* rhid_a = nullptr; float* edb_a = nullptr;
  if (tier == 1){
    rhid_a = allocU((size_t)E*128);
    edb_a  = alloc((size_t)3*E);
  }
  size_t availF = (wsF > off) ? (wsF - off) : 0;
  if (availF < 256*p){
    k_sentinel<<<1, 64, 0, stream>>>((__hip_bfloat16*)d_out, out_size,
                                     (float)(double)(ws_size >> 20));
    return;
  }
  size_t Cs = availF / p; if (Cs > (size_t)E) Cs = E;
  int C = (int)(Cs & ~(size_t)15);
  if (C < 256) C = 256;

  float* scratch0 = (float*)d_ws + off;
  ushortT* remb_l = allocU((size_t)C*96);     // 48C
  float* edb_l = nullptr; ushortT* rhid_l = nullptr;
  if (tier == 0){
    edb_l  = alloc((size_t)3*C);
    rhid_l = allocU((size_t)C*128);
  }
  ushortT* ew_b = allocU((size_t)C*480);      // 240C ; Rm overlays; geom dumps overlay
  ushortT* R2b  = allocU((size_t)C*384);      // 192C ; R2rl overlays
  ushortT* R1b  = allocU((size_t)C*384);      // 192C
  ushortT* Rmb  = ew_b;
  float* ecv_d  = (float*)ew_b;               // pre-pass dump (6C)
  float* rb_d   = (float*)ew_b + (size_t)6*C; // pre-pass rowscale (C)
  ushortT* R2rl = R2b;
  float* vpc = scratch0;
  size_t scratchF = (size_t)C*p;

  auto mg = [&](const ushortT* A, const ushortT* BT, const float* bias,
                float* Cf, ushortT* Cb, int M, int Nc, int K, int epi,
                const float* rowscale = nullptr, const ushortT* mul1b = nullptr,
                const ushortT* xhpb = nullptr, const int* jidx = nullptr){
    dim3 grid(Nc/128, (M + 127)/128);
    mgemm<<<grid, 256, 0, stream>>>(A, BT, bias, Cf, Cb, M, Nc, K, epi,
                                    rowscale, mul1b, xhpb, jidx);
  };

  // 0) zero header, detect dtypes, int-normalize (+deg histogram)
  k_zero<<<64, 256, 0, stream>>>((float*)flags, (int)zeroHdr);
  k_detect<<<64, 256, 0, stream>>>((const ushortT*)d_in[0], in_sizes[0],
                                   (const int*)d_in[2], in_sizes[2], flags);
  k_iconv<<<1024, 256, 0, stream>>>((const int*)d_in[1], (const int*)d_in[2],
                                    (const int*)d_in[3], zi, bi, eii, N, E, flags, deg);

  // 1) float conversions + transposed bf16 weights
  ConvArgs ca;
  ca.d[0] = { (const ushortT*)d_in[0], pos, in_sizes[0] };
  for (int t = 0; t < 31; ++t)
    ca.d[1+t] = { (const ushortT*)d_in[4+t], w[t], in_sizes[4+t] };
  k_conv<<<dim3(32, 32), 256, 0, stream>>>(ca, 32, flags);

  TArgs ta;
  ta.d[0]  = { (const ushortT*)d_in[4],  wt_rl1, 96, 128 };
  ta.d[1]  = { (const ushortT*)d_in[6],  wt_rl2, 128, 128 };
  ta.d[2]  = { (const ushortT*)d_in[10], wt_sv,  128, 128 };
  ta.d[3]  = { (const ushortT*)d_in[18], wt_xp1, 128, 128 };
  ta.d[4]  = { (const ushortT*)d_in[20], wt_xp2, 128, 384 };
  ta.d[5]  = { (const ushortT*)d_in[22], wt_rp,  96, 384 };
  ta.d[6]  = { (const ushortT*)d_in[24], wt_ip1, 480, 384 };
  ta.d[7]  = { (const ushortT*)d_in[26], wt_ip2, 384, 384 };
  ta.d[8]  = { (const ushortT*)d_in[28], wt_feq, 128, 256 };
  ta.d[9]  = { (const ushortT*)d_in[29], wt_ft1, 256, 128 };
  ta.d[10] = { (const ushortT*)d_in[31], wt_ft2, 128, 384 };
  k_wt<<<dim3(48, 11), 256, 0, stream>>>(ta, 11, flags);

  // 2) CSR scan + scatter
  k_csr_scan<<<1, 256, 0, stream>>>(deg, rowptr, N);
  k_csr_scatter<<<(E + 255)/256, 256, 0, stream>>>(eii, E, rowptr, cursor, jp, ipp);

  // 3) node embedding (+ S/vecacc zero fused)
  k_embed<<<N, 128, 0, stream>>>(zi, ne_w, ne_b, s, h0, S, vecacc);

  if (tier == 1){
    // pre-pass: geometry persist + rl MLP -> rhid_a
    for (int o = 0; o < E; o += C){
      int Cc = (E - o < C) ? (E - o) : C;
      k_geom<<<(Cc + 255)/256, 256, 0, stream>>>(pos, jp, ipp, o, Cc,
                                                 edb_a + (size_t)3*o, ecv_d, rb_d, remb_l);
      mg(remb_l, wt_rl1, rl_b1, nullptr, R2rl, Cc, 128, 96, 1);
      mg(R2rl, wt_rl2, rl_b2, nullptr, rhid_a + (size_t)o*128, Cc, 128, 128, 2, rb_d);
    }
    // Phase B: single launch
    k_seg1n<<<N, 128, 0, stream>>>(rowptr, jp, 0, E, h0, rhid_a, s);
  } else {
    for (int o = 0; o < E; o += C){
      int Cc = (E - o < C) ? (E - o) : C;
      k_geom<<<(Cc + 255)/256, 256, 0, stream>>>(pos, jp, ipp, o, Cc,
                                                 edb_l, ecv_d, rb_d, remb_l);
      mg(remb_l, wt_rl1, rl_b1, nullptr, R2rl, Cc, 128, 96, 1);
      mg(R2rl, wt_rl2, rl_b2, nullptr, rhid_l, Cc, 128, 128, 2, rb_d);
      k_seg1n<<<N, 128, 0, stream>>>(rowptr, jp, o, Cc, h0, rhid_l, s);
    }
  }

  // Phase C: slin, xln(+sb), xh
  k_ln<<<N, 128, 0, stream>>>(s, xln_b, mp_w, mp_b, sb);
  mg(sb, wt_sv, sv_b, nullptr, slin_b, N, 128, 128, 1);
  mg(xln_b, wt_xp1, xp_b1, nullptr, hb, N, 128, 128, 1);
  mg(hb, wt_xp2, xp_b2, nullptr, xh_b, N, 384, 128, 0);

  // Phase D: seg2
  if (tier == 1){
    k_seg2n<<<N, 128, 0, stream>>>(rowptr, jp, 0, E, slin_b, rhid_a, edb_a, S);
  } else {
    for (int o = 0; o < E; o += C){
      int Cc = (E - o < C) ? (E - o) : C;
      k_geom<<<(Cc + 255)/256, 256, 0, stream>>>(pos, jp, ipp, o, Cc,
                                                 edb_l, ecv_d, rb_d, remb_l);
      mg(remb_l, wt_rl1, rl_b1, nullptr, R2rl, Cc, 128, 96, 1);
      mg(R2rl, wt_rl2, rl_b2, nullptr, rhid_l, Cc, 128, 128, 2, rb_d);
      k_seg2n<<<N, 128, 0, stream>>>(rowptr, jp, o, Cc, slin_b, rhid_l, edb_l, S);
    }
  }

  // Phase E: per-edge big MLPs + seg3
  for (int o = 0; o < E; o += C){
    int Cc = (E - o < C) ? (E - o) : C;
    const ushortT* rhid_p; const float* edb_p;
    if (tier == 1){
      rhid_p = rhid_a + (size_t)o*128;
      edb_p  = edb_a + (size_t)3*o;
    } else {
      k_geom<<<(Cc + 255)/256, 256, 0, stream>>>(pos, jp, ipp, o, Cc,
                                                 edb_l, ecv_d, rb_d, remb_l);
      mg(remb_l, wt_rl1, rl_b1, nullptr, R2rl, Cc, 128, 96, 1);
      mg(R2rl, wt_rl2, rl_b2, nullptr, rhid_l, Cc, 128, 128, 2, rb_d);
      rhid_p = rhid_l; edb_p = edb_l;
    }
    k_scal2<<<Cc, 256, 0, stream>>>(jp, ipp, o, pos, S, rhid_p,
                                    l3_w1, l3_b1, l3_w2, l3_b2, ew_b, remb_l);
    mg(remb_l, wt_rp, rp_b, nullptr, R1b, Cc, 384, 96, 0);
    mg(ew_b, wt_ip1, ip_b1, nullptr, R2b, Cc, 384, 480, 1);
    mg(R2b, wt_ip2, ip_b2, nullptr, Rmb, Cc, 384, 384, 3, nullptr, R1b, xh_b, jp + o);
    k_seg3n<<<N, 128, 0, stream>>>(rowptr, o, Cc, Rmb, edb_p, s, vecacc);
  }

  // Phase F: fte
  k_f2b<<<1024, 256, 0, stream>>>(vecacc, vab, N*384);
  int Cn = (int)(scratchF / 768);
  if (Cn > N) Cn = N;
  for (int no = 0; no < N; no += Cn){
    int Cc = (N - no < Cn) ? (N - no) : Cn;
    mg(vab + (size_t)no*384, wt_feq, nullptr, vpc, nullptr, 3*Cc, 256, 128, 0);
    k_fte_pre<<<Cc, 128, 0, stream>>>(vpc, s, catb, vdot, no);
  }
  mg(catb, wt_ft1, fte_b1, nullptr, hb, N, 128, 256, 1);
  mg(hb, wt_ft2, fte_b2, xh2, nullptr, N, 384, 128, 0);

  // Phase G
  k_out<<<N, 128, 0, stream>>>(xh2, vdot, s, out_w, out_b, nodeout);
  k_final<<<out_size, 256, 0, stream>>>(nodeout, bi, d_out, N, flags);
}

// Round 8
// 2167.162 us; speedup vs baseline: 3.6262x; 1.1825x over previous
//
#include <hip/hip_runtime.h>
#include <hip/hip_bf16.h>
#include <math.h>

#define NRAD 96
#define HIDDIM 128
typedef unsigned short ushortT;

typedef __attribute__((ext_vector_type(8))) short bf8_t;   // 8 bf16 (4 VGPRs)
typedef __attribute__((ext_vector_type(4))) float f4_t;    // 4 fp32 acc

#if defined(__has_builtin)
#  if __has_builtin(__builtin_amdgcn_global_load_lds)
#    define HAVE_GLDS 1
#  endif
#  if __has_builtin(__builtin_amdgcn_rcpf)
#    define RCPF(x) __builtin_amdgcn_rcpf(x)
#  endif
#  if __has_builtin(__builtin_amdgcn_exp2f)
#    define EXP2F(x) __builtin_amdgcn_exp2f(x)
#  endif
#  if __has_builtin(__builtin_amdgcn_cosf)
#    define COSR(x) __builtin_amdgcn_cosf(x)   /* cos(2*pi*x) */
#  endif
#endif
#ifndef RCPF
#  define RCPF(x) (1.f/(x))
#endif
#ifndef EXP2F
#  define EXP2F(x) exp2f(x)
#endif
#ifndef COSR
#  define COSR(x) cosf(6.2831853071795864f*(x))
#endif
#define LOG2E 1.44269504088896f

__device__ __forceinline__ float silu_f(float x){
  return x * RCPF(1.f + EXP2F(-LOG2E*x));
}
__device__ __forceinline__ float b2f(ushortT u){ return __uint_as_float(((unsigned int)u) << 16); }
__device__ __forceinline__ ushortT f2b(float x){
  unsigned int u = __float_as_uint(x);
  unsigned int r = (u + 0x7fffu + ((u >> 16) & 1u)) >> 16;
  return (ushortT)r;
}

#ifdef HAVE_GLDS
__device__ __forceinline__ void glds16(const ushortT* g, ushortT* l){
  __builtin_amdgcn_global_load_lds(
      (const __attribute__((address_space(1))) ushortT*)g,
      (__attribute__((address_space(3))) ushortT*)l, 16, 0, 0);
}
#endif

// ---------------- dtype detection (parallel) ----------------
// flags[2] != 0  => floats are fp32 ; flags[3] != 0 => ints are int32
__global__ void k_detect(const ushortT* posw, int npos,
                         const int* batchw, int nb, int* flags){
  int tot = (npos < 4096 ? npos : 4096);
  int big = tot > nb ? tot : nb;
  int bad = 0, orv = 0;
  for (int t = blockIdx.x*blockDim.x + threadIdx.x; t < big; t += gridDim.x*blockDim.x){
    if (t < tot){
      float x = b2f(posw[t]);
      if (!(fabsf(x) <= 1000.f)) bad = 1;
    }
    if (t < nb && (t & 1)) orv |= batchw[t];
  }
  if (bad) atomicOr(&flags[2], 1);
  if (orv) atomicOr(&flags[3], 1);
}

// normalize int inputs to int32; also builds CSR degree histogram
__global__ void k_iconv(const int* zsrc, const int* bsrc, const int* esrc,
                        int* zi, int* bi, int* eii, int Nn, int E, const int* flags,
                        int* deg){
  int f = (flags[3] == 0) ? 1 : 0;   // 1 => int64
  int total = 2*Nn + 2*E;
  for (int t = blockIdx.x*blockDim.x + threadIdx.x; t < total; t += gridDim.x*blockDim.x){
    if (t < Nn) zi[t] = zsrc[(size_t)t << f];
    else if (t < 2*Nn) bi[t-Nn] = bsrc[(size_t)(t-Nn) << f];
    else {
      int e = t - 2*Nn;
      int v = esrc[(size_t)e << f];
      eii[e] = v;
      if (e >= E) atomicAdd(&deg[v], 1);
    }
  }
}

// ---------------- conversion: (bf16|f32) -> f32 ----------------
struct ConvDesc { const ushortT* src; float* dst; int n; };
struct ConvArgs { ConvDesc d[32]; };

__global__ void k_conv(ConvArgs a, int cnt, const int* flags){
  int y = blockIdx.y;
  if (y >= cnt) return;
  int f = (flags[2] == 0) ? 1 : 0;    // 1 => bf16
  const ushortT* s = a.d[y].src;
  float* dst = a.d[y].dst;
  int n = a.d[y].n;
  if (f){
    for (int t = blockIdx.x*blockDim.x + threadIdx.x; t < n; t += gridDim.x*blockDim.x)
      dst[t] = b2f(s[t]);
  } else {
    const float* sf = (const float*)s;
    for (int t = blockIdx.x*blockDim.x + threadIdx.x; t < n; t += gridDim.x*blockDim.x)
      dst[t] = sf[t];
  }
}

// ---------------- weight transpose -> bf16 [N][K] ----------------
struct TDesc { const ushortT* src; ushortT* dst; int K, N; };
struct TArgs { TDesc d[12]; };

__global__ void k_wt(TArgs a, int cnt, const int* flags){
  int y = blockIdx.y;
  if (y >= cnt) return;
  int f = (flags[2] == 0) ? 1 : 0;
  const ushortT* s = a.d[y].src;
  ushortT* dst = a.d[y].dst;
  int K = a.d[y].K, N = a.d[y].N, tot = K*N;
  for (int t = blockIdx.x*blockDim.x + threadIdx.x; t < tot; t += gridDim.x*blockDim.x){
    int k = t / N, n = t - k*N;
    ushortT v = f ? s[t] : f2b(((const float*)s)[t]);
    dst[(size_t)n*K + k] = v;
  }
}

__global__ void k_f2b(const float* __restrict__ src, ushortT* __restrict__ dst, int n){
  for (int t = blockIdx.x*blockDim.x + threadIdx.x; t < n; t += gridDim.x*blockDim.x)
    dst[t] = f2b(src[t]);
}

__global__ void k_zero(float* __restrict__ p, int n){
  int t = blockIdx.x*blockDim.x + threadIdx.x;
  int stride = gridDim.x*blockDim.x;
  for (; t < n; t += stride) p[t] = 0.f;
}

__global__ void k_sentinel(__hip_bfloat16* out, int n, float val){
  int t = threadIdx.x;
  if (t < n) out[t] = __float2bfloat16(val);
}

// ---------------- CSR scan + scatter ----------------
__global__ void k_csr_scan(const int* __restrict__ deg, int* __restrict__ rowptr, int Nn){
  __shared__ int sh[256];
  __shared__ int carry;
  if (threadIdx.x == 0){ carry = 0; rowptr[0] = 0; }
  __syncthreads();
  for (int t0 = 0; t0 < Nn; t0 += 256){
    int idx = t0 + threadIdx.x;
    int v = (idx < Nn) ? deg[idx] : 0;
    sh[threadIdx.x] = v; __syncthreads();
    for (int o = 1; o < 256; o <<= 1){
      int u = (threadIdx.x >= o) ? sh[threadIdx.x - o] : 0;
      __syncthreads();
      sh[threadIdx.x] += u; __syncthreads();
    }
    if (idx < Nn) rowptr[idx + 1] = carry + sh[threadIdx.x];
    __syncthreads();
    if (threadIdx.x == 0) carry += sh[255];
    __syncthreads();
  }
}

__global__ void k_csr_scatter(const int* __restrict__ eii, int E,
                              const int* __restrict__ rowptr, int* __restrict__ cursor,
                              int* __restrict__ jp, int* __restrict__ ip){
  int e = blockIdx.x*blockDim.x + threadIdx.x;
  if (e >= E) return;
  int i = eii[E+e];
  int p = atomicAdd(&cursor[i], 1);
  int k = rowptr[i] + p;
  jp[k] = eii[e];
  ip[k] = i;
}

// ---------------- geometry + RBF (pre-pass / tier0) ----------------
__global__ void k_geom(const float* __restrict__ pos,
                       const int* __restrict__ jp, const int* __restrict__ ip,
                       int off, int Cc,
                       float* __restrict__ edb, float* __restrict__ ecv,
                       float* __restrict__ rb, ushortT* __restrict__ remb)
{
  int el = blockIdx.x*blockDim.x + threadIdx.x;
  if (el >= Cc) return;
  int g = off + el;
  int j = jp[g], i = ip[g];
  float pjx = pos[3*j], pjy = pos[3*j+1], pjz = pos[3*j+2];
  float pix = pos[3*i], piy = pos[3*i+1], piz = pos[3*i+2];
  float vx = pjx-pix, vy = pjy-piy, vz = pjz-piz;
  float d = sqrtf(vx*vx + vy*vy + vz*vz);
  float inv = RCPF(d + 1e-10f);
  float edx = vx*inv, edy = vy*inv, edz = vz*inv;
  float cx = piy*pjz - piz*pjy;
  float cy = piz*pjx - pix*pjz;
  float cz = pix*pjy - piy*pjx;
  float cn = sqrtf(cx*cx + cy*cy + cz*cz);
  float inv2 = RCPF(cn + 1e-10f);
  cx *= inv2; cy *= inv2; cz *= inv2;
  float evx = edy*cz - edz*cy;
  float evy = edz*cx - edx*cz;
  float evz = edx*cy - edy*cx;
  edb[3*el]=edx; edb[3*el+1]=edy; edb[3*el+2]=edz;
  ecv[6*el]=cx; ecv[6*el+1]=cy; ecv[6*el+2]=cz;
  ecv[6*el+3]=evx; ecv[6*el+4]=evy; ecv[6*el+5]=evz;
  float rbv = 0.5f*(COSR(d*0.08333333333f) + 1.f);   // cos(d*pi/6)
  rb[el] = rbv;
  float env = (d < 6.f) ? rbv : 0.f;
  const float stf = 0.0024787522f;
  const float prf = (2.0f/96.0f)*(1.0f - stf);
  const float betaL = LOG2E/(prf*prf);
  float emd = EXP2F(-LOG2E*d);
  for (int k = 0; k < NRAD; ++k){
    float mu = stf + (1.0f - stf)*((float)k*(1.0f/95.0f));
    float t = emd - mu;
    remb[(size_t)el*NRAD + k] = f2b(env * EXP2F(-betaL*t*t));
  }
}

// ---------------- node embedding + layernorm (+ fused accumulator zeroing) ----------------
__global__ __launch_bounds__(128) void k_embed(const int* __restrict__ z,
    const float* __restrict__ ne_w, const float* __restrict__ ne_b,
    float* __restrict__ s, float* __restrict__ h0,
    float* __restrict__ S, float* __restrict__ vecacc)
{
  int n = blockIdx.x; int h = threadIdx.x;
  float x = ne_w[(size_t)z[n]*HIDDIM + h] + ne_b[h];
  __shared__ float red[128];
  red[h] = x; __syncthreads();
  for (int o = 64; o > 0; o >>= 1){ if (h < o) red[h] += red[h+o]; __syncthreads(); }
  float mean = red[0] * (1.f/128.f);
  __syncthreads();
  float dx = x - mean;
  red[h] = dx*dx; __syncthreads();
  for (int o = 64; o > 0; o >>= 1){ if (h < o) red[h] += red[h+o]; __syncthreads(); }
  float var = red[0] * (1.f/128.f);
  float y = dx * rsqrtf(var + 1e-5f);
  s[(size_t)n*HIDDIM + h] = y;
  h0[(size_t)n*HIDDIM + h] = y;
  float* Sr = &S[(size_t)n*384 + h];
  float* Vr = &vecacc[(size_t)n*384 + h];
  Sr[0]=0.f; Sr[128]=0.f; Sr[256]=0.f;
  Vr[0]=0.f; Vr[128]=0.f; Vr[256]=0.f;
}

// LN -> xln_b, plus fused s -> sb conversion
__global__ __launch_bounds__(128) void k_ln(const float* __restrict__ src, ushortT* __restrict__ dst,
    const float* __restrict__ g, const float* __restrict__ b, ushortT* __restrict__ sb)
{
  int n = blockIdx.x; int h = threadIdx.x;
  float x = src[(size_t)n*HIDDIM + h];
  sb[(size_t)n*HIDDIM + h] = f2b(x);
  __shared__ float red[128];
  red[h] = x; __syncthreads();
  for (int o = 64; o > 0; o >>= 1){ if (h < o) red[h] += red[h+o]; __syncthreads(); }
  float mean = red[0] * (1.f/128.f);
  __syncthreads();
  float dx = x - mean;
  red[h] = dx*dx; __syncthreads();
  for (int o = 64; o > 0; o >>= 1){ if (h < o) red[h] += red[h+o]; __syncthreads(); }
  float var = red[0] * (1.f/128.f);
  float y = dx * rsqrtf(var + 1e-5f);
  dst[(size_t)n*HIDDIM + h] = f2b(y * g[h] + b[h]);
}

// ---------------- rowptr-based segment sums (one block per node) ----------------
__global__ __launch_bounds__(128) void k_seg1n(const int* __restrict__ rowptr,
    const int* __restrict__ jp, int o, int Cc,
    const float* __restrict__ h0, const ushortT* __restrict__ rhid,
    float* __restrict__ s)
{
  int i = blockIdx.x, h = threadIdx.x;
  int b = rowptr[i], e = rowptr[i+1];
  if (b < o) b = o;
  int hi = o + Cc; if (e > hi) e = hi;
  if (b >= e) return;
  float acc = 0.f;
  int m = b;
  for (; m + 1 < e; m += 2){
    int j0 = jp[m], j1 = jp[m+1];
    float r0 = b2f(rhid[(size_t)(m-o)*HIDDIM + h]);
    float r1 = b2f(rhid[(size_t)(m+1-o)*HIDDIM + h]);
    acc += h0[(size_t)j0*HIDDIM + h]*r0 + h0[(size_t)j1*HIDDIM + h]*r1;
  }
  if (m < e) acc += h0[(size_t)jp[m]*HIDDIM + h] * b2f(rhid[(size_t)(m-o)*HIDDIM + h]);
  s[(size_t)i*HIDDIM + h] += acc;
}

__global__ __launch_bounds__(128) void k_seg2n(const int* __restrict__ rowptr,
    const int* __restrict__ jp, int o, int Cc,
    const ushortT* __restrict__ slin, const ushortT* __restrict__ rhid,
    const float* __restrict__ edb, float* __restrict__ S)
{
  int i = blockIdx.x, h = threadIdx.x;
  int b = rowptr[i], e = rowptr[i+1];
  if (b < o) b = o;
  int hi = o + Cc; if (e > hi) e = hi;
  if (b >= e) return;
  float a0 = 0.f, a1 = 0.f, a2 = 0.f;
  for (int m = b; m < e; ++m){
    int ml = m - o;
    float val = b2f(slin[(size_t)jp[m]*HIDDIM + h]) * b2f(rhid[(size_t)ml*HIDDIM + h]);
    a0 += val*edb[3*ml]; a1 += val*edb[3*ml+1]; a2 += val*edb[3*ml+2];
  }
  float* base = &S[(size_t)i*384 + h];
  base[0]   += a0;
  base[128] += a1;
  base[256] += a2;
}

__global__ __launch_bounds__(128) void k_seg3n(const int* __restrict__ rowptr,
    int o, int Cc,
    const ushortT* __restrict__ mb, const float* __restrict__ edb,
    float* __restrict__ s, float* __restrict__ vecacc)
{
  int i = blockIdx.x, h = threadIdx.x;
  int b = rowptr[i], e = rowptr[i+1];
  if (b < o) b = o;
  int hi = o + Cc; if (e > hi) e = hi;
  if (b >= e) return;
  const float is128 = 0.08838834764831845f;
  float am = 0.f, v0 = 0.f, v1 = 0.f, v2 = 0.f;
  for (int m = b; m < e; ++m){
    int ml = m - o;
    float m1 = b2f(mb[(size_t)ml*384 + h]);
    float mm = b2f(mb[(size_t)ml*384 + 256 + h]) * is128;
    am += m1;
    v0 += mm*edb[3*ml]; v1 += mm*edb[3*ml+1]; v2 += mm*edb[3*ml+2];
  }
  s[(size_t)i*HIDDIM + h] += am;
  float* base = &vecacc[(size_t)i*384 + h];
  base[0]   += v0;
  base[128] += v1;
  base[256] += v2;
}

// ---------------- fused geometry + scalarize + ew assembly ----------------
__global__ __launch_bounds__(256) void k_scal2(
  const int* __restrict__ jp, const int* __restrict__ ip, int off,
  const float* __restrict__ pos, const float* __restrict__ S,
  const ushortT* __restrict__ rhid,
  const float* __restrict__ w1, const float* __restrict__ b1,
  const float* __restrict__ w2, const float* __restrict__ b2,
  ushortT* __restrict__ ew, ushortT* __restrict__ remb)
{
  int el = blockIdx.x;
  int g = off + el;
  int which = threadIdx.x >> 7;
  int h = threadIdx.x & 127;
  int j = jp[g], i = ip[g];
  float pjx = pos[3*j], pjy = pos[3*j+1], pjz = pos[3*j+2];
  float pix = pos[3*i], piy = pos[3*i+1], piz = pos[3*i+2];
  float vx = pjx-pix, vy = pjy-piy, vz = pjz-piz;
  float d = sqrtf(vx*vx + vy*vy + vz*vz);
  float inv = RCPF(d + 1e-10f);
  float f00 = vx*inv, f01 = vy*inv, f02 = vz*inv;
  float cx = piy*pjz - piz*pjy;
  float cy = piz*pjx - pix*pjz;
  float cz = pix*pjy - piy*pjx;
  float cn = sqrtf(cx*cx + cy*cy + cz*cz);
  float inv2 = RCPF(cn + 1e-10f);
  float f10 = cx*inv2, f11 = cy*inv2, f12 = cz*inv2;
  float f20 = f01*f12 - f02*f11;
  float f21 = f02*f10 - f00*f12;
  float f22 = f00*f11 - f01*f10;
  float rbv = 0.5f*(COSR(d*0.08333333333f) + 1.f);
  int n = which ? j : i;
  const float* Sn = &S[(size_t)n*384];
  float S0 = Sn[h], S1 = Sn[128+h], S2 = Sn[256+h];
  float v0 = S0*f00 + S1*f01 + S2*f02;
  float v1 = fabsf(S0*f10 + S1*f11 + S2*f12);
  float v2 = S0*f20 + S1*f21 + S2*f22;
  float out = b2[0];
  #pragma unroll
  for (int u = 0; u < 32; ++u){
    float t = v0*w1[u] + v1*w1[32+u] + v2*w1[64+u] + b1[u];
    out += silu_f(t) * w2[u];
  }
  float scal = out + v0;
  ushortT* ewr = &ew[(size_t)el*480];
  ewr[which*128 + h] = f2b(scal * rbv);
  if (which == 0){
    ewr[256 + h] = rhid[(size_t)el*HIDDIM + h];
    if (h < NRAD){
      float env = (d < 6.f) ? rbv : 0.f;
      const float stf = 0.0024787522f;
      const float prf = (2.0f/96.0f)*(1.0f - stf);
      const float betaL = LOG2E/(prf*prf);
      float mu = stf + (1.0f - stf)*((float)h*(1.0f/95.0f));
      float t = EXP2F(-LOG2E*d) - mu;
      ushortT rv = f2b(env * EXP2F(-betaL*t*t));
      ewr[384 + h] = rv;
      remb[(size_t)el*NRAD + h] = rv;
    }
  }
}

// ---------------- bf16 MFMA GEMM ----------------
// A: MxK bf16 row-major; BT: NxK bf16 row-major. N%128==0, K%32==0.
// epi: 0 none, 1 silu, 2 *rowscale[row], 3 *mul1b[row,col]*xhpb[jidx[row],col]
__global__ __launch_bounds__(256) void mgemm(
  const ushortT* __restrict__ A, const ushortT* __restrict__ BT,
  const float* __restrict__ bias,
  float* __restrict__ Cf, ushortT* __restrict__ Cb,
  int M, int N, int K, int epi,
  const float* __restrict__ rowscale,
  const ushortT* __restrict__ mul1b,
  const ushortT* __restrict__ xhpb,
  const int* __restrict__ jidx)
{
  const int tid = threadIdx.x;
  const int w = tid >> 6;
  const int lane = tid & 63;
  const int l15 = lane & 15;
  const int q = lane >> 4;
  const int wm = w & 1, wn = w >> 1;
  const int rowBase = blockIdx.y * 128;
  const int colBase = blockIdx.x * 128;
  f4_t acc[4][4] = {};

#ifdef HAVE_GLDS
  __shared__ ushortT As[128*32];
  __shared__ ushortT Bs[128*32];
  const int rS = 32*w + (lane >> 2);
  const int kS = (lane & 3) << 3;
  ushortT* lA0 = &As[(32*w)*32];
  ushortT* lA1 = &As[(32*w+16)*32];
  ushortT* lB0 = &Bs[(32*w)*32];
  ushortT* lB1 = &Bs[(32*w+16)*32];
  int ra0 = rowBase + rS;      if (ra0 >= M) ra0 = M-1;
  int ra1 = rowBase + rS + 16; if (ra1 >= M) ra1 = M-1;
  const ushortT* gA0 = A  + (size_t)ra0*K + kS;
  const ushortT* gA1 = A  + (size_t)ra1*K + kS;
  const ushortT* gB0 = BT + (size_t)(colBase + rS)*K + kS;
  const ushortT* gB1 = BT + (size_t)(colBase + rS + 16)*K + kS;
  for (int k0 = 0; k0 < K; k0 += 32){
    glds16(gA0 + k0, lA0);
    glds16(gA1 + k0, lA1);
    glds16(gB0 + k0, lB0);
    glds16(gB1 + k0, lB1);
    __syncthreads();
    bf8_t a[4], b[4];
    #pragma unroll
    for (int mt = 0; mt < 4; ++mt)
      a[mt] = *(const bf8_t*)&As[(wm*64 + mt*16 + l15)*32 + q*8];
    #pragma unroll
    for (int nt = 0; nt < 4; ++nt)
      b[nt] = *(const bf8_t*)&Bs[(wn*64 + nt*16 + l15)*32 + q*8];
    #pragma unroll
    for (int mt = 0; mt < 4; ++mt){
      #pragma unroll
      for (int nt = 0; nt < 4; ++nt)
        acc[mt][nt] = __builtin_amdgcn_mfma_f32_16x16x32_bf16(a[mt], b[nt], acc[mt][nt], 0, 0, 0);
    }
    __syncthreads();
  }
#else
  __shared__ ushortT As[128*48];
  __shared__ ushortT Bs[128*48];
  const int r0 = tid >> 2,         s0 = (tid & 3) << 3;
  const int r1 = (tid + 256) >> 2, s1 = ((tid + 256) & 3) << 3;
  for (int k0 = 0; k0 < K; k0 += 32){
    int4 a0v = make_int4(0,0,0,0), a1v = make_int4(0,0,0,0);
    if (rowBase + r0 < M) a0v = *(const int4*)&A[(size_t)(rowBase + r0)*K + k0 + s0];
    if (rowBase + r1 < M) a1v = *(const int4*)&A[(size_t)(rowBase + r1)*K + k0 + s1];
    int4 b0v = *(const int4*)&BT[(size_t)(colBase + r0)*K + k0 + s0];
    int4 b1v = *(const int4*)&BT[(size_t)(colBase + r1)*K + k0 + s1];
    __syncthreads();
    *(int4*)&As[r0*48 + s0] = a0v;
    *(int4*)&As[r1*48 + s1] = a1v;
    *(int4*)&Bs[r0*48 + s0] = b0v;
    *(int4*)&Bs[r1*48 + s1] = b1v;
    __syncthreads();
    bf8_t a[4], b[4];
    #pragma unroll
    for (int mt = 0; mt < 4; ++mt)
      a[mt] = *(const bf8_t*)&As[(wm*64 + mt*16 + l15)*48 + q*8];
    #pragma unroll
    for (int nt = 0; nt < 4; ++nt)
      b[nt] = *(const bf8_t*)&Bs[(wn*64 + nt*16 + l15)*48 + q*8];
    #pragma unroll
    for (int mt = 0; mt < 4; ++mt){
      #pragma unroll
      for (int nt = 0; nt < 4; ++nt)
        acc[mt][nt] = __builtin_amdgcn_mfma_f32_16x16x32_bf16(a[mt], b[nt], acc[mt][nt], 0, 0, 0);
    }
  }
#endif

  #pragma unroll
  for (int mt = 0; mt < 4; ++mt){
    int row = rowBase + wm*64 + mt*16 + q*4;
    #pragma unroll
    for (int nt = 0; nt < 4; ++nt){
      int col = colBase + wn*64 + nt*16 + l15;
      float bv = bias ? bias[col] : 0.f;
      #pragma unroll
      for (int r = 0; r < 4; ++r){
        int rr = row + r;
        if (rr >= M) continue;
        float x = acc[mt][nt][r] + bv;
        if (epi == 1) x = silu_f(x);
        else if (epi == 2) x *= rowscale[rr];
        else if (epi == 3) x = x * b2f(mul1b[(size_t)rr*N + col]) * b2f(xhpb[(size_t)jidx[rr]*N + col]);
        if (Cb) Cb[(size_t)rr*N + col] = f2b(x);
        else    Cf[(size_t)rr*N + col] = x;
      }
    }
  }
}

// ---------------- fte prep ----------------
__global__ __launch_bounds__(128) void k_fte_pre(const float* __restrict__ vpc,
    const float* __restrict__ s, ushortT* __restrict__ catb, float* __restrict__ vdot,
    int no)
{
  int nl = blockIdx.x, h = threadIdx.x;
  int n = no + nl;
  const float* base = &vpc[(size_t)nl*768];
  float a0 = base[h],       a1 = base[256+h],     a2 = base[512+h];
  float c0 = base[128+h],   c1 = base[384+h],     c2 = base[640+h];
  float scal = sqrtf(a0*a0 + a1*a1 + a2*a2 + 1e-10f);
  float vd = (a0*c0 + a1*c1 + a2*c2) * 0.08838834764831845f;
  catb[(size_t)n*256 + h] = f2b(s[(size_t)n*HIDDIM + h]);
  catb[(size_t)n*256 + 128 + h] = f2b(scal);
  vdot[(size_t)n*HIDDIM + h] = vd;
}

// ---------------- final ----------------
__global__ __launch_bounds__(128) void k_out(const float* __restrict__ xh2,
    const float* __restrict__ vdot, const float* __restrict__ s,
    const float* __restrict__ ow, const float* __restrict__ ob,
    float* __restrict__ nodeout)
{
  int n = blockIdx.x, h = threadIdx.x;
  float a1 = xh2[(size_t)n*384 + h];
  float a2 = xh2[(size_t)n*384 + 128 + h];
  float sv = s[(size_t)n*HIDDIM + h] + (a1 + a2*vdot[(size_t)n*HIDDIM + h]) * 0.7071067811865476f;
  __shared__ float red[128];
  red[h] = sv * ow[h];
  __syncthreads();
  for (int o = 64; o > 0; o >>= 1){ if (h < o) red[h] += red[h+o]; __syncthreads(); }
  if (h == 0) nodeout[n] = red[0] + ob[0];
}

__global__ __launch_bounds__(256) void k_final(const float* __restrict__ nodeout,
    const int* __restrict__ batch, void* __restrict__ out, int Nn, const int* flags)
{
  int g = blockIdx.x;
  __shared__ float rs[256], rc[256];
  float sm = 0.f, c = 0.f;
  for (int n = threadIdx.x; n < Nn; n += 256){
    if (batch[n] == g){ sm += nodeout[n]; c += 1.f; }
  }
  rs[threadIdx.x] = sm; rc[threadIdx.x] = c;
  __syncthreads();
  for (int o = 128; o > 0; o >>= 1){
    if (threadIdx.x < o){ rs[threadIdx.x] += rs[threadIdx.x+o]; rc[threadIdx.x] += rc[threadIdx.x+o]; }
    __syncthreads();
  }
  if (threadIdx.x == 0){
    float v = (rc[0] > 0.f) ? rs[0]/rc[0] : 0.f;
    if (flags[2] == 0) ((__hip_bfloat16*)out)[g] = __float2bfloat16(v);
    else ((float*)out)[g] = v;
  }
}

// =====================================================================
extern "C" void kernel_launch(void* const* d_in, const int* in_sizes, int n_in,
                              void* d_out, int out_size, void* d_ws, size_t ws_size,
                              hipStream_t stream)
{
  const int N = in_sizes[0] / 3;
  const int E = in_sizes[3] / 2;

  size_t off = 0;
  auto alloc = [&](size_t n)->float*{
    float* p = (float*)d_ws + off;
    off += (n + 3) & ~(size_t)3;
    return p;
  };
  auto allocU = [&](size_t n)->ushortT*{ return (ushortT*)alloc((n + 1) / 2); };

  int* flags  = (int*)alloc(4);
  int* deg    = (int*)alloc((size_t)N);
  int* cursor = (int*)alloc((size_t)N);
  size_t zeroHdr = off;
  int* zi     = (int*)alloc((size_t)N);
  int* bi     = (int*)alloc((size_t)N);
  int* eii    = (int*)alloc((size_t)2*E);
  int* rowptr = (int*)alloc((size_t)N + 4);
  int* jp     = (int*)alloc((size_t)E);
  int* ipp    = (int*)alloc((size_t)E);

  float* pos = alloc((size_t)N*3);
  float* w[31];
  for (int t = 0; t < 31; ++t) w[t] = alloc((size_t)in_sizes[4+t]);
  float* rl_b1=w[1];  float* rl_b2=w[3];
  float* ne_w =w[4];  float* ne_b =w[5];  float* sv_b =w[7];
  float* l3_w1=w[8];  float* l3_b1=w[9];  float* l3_w2=w[10]; float* l3_b2=w[11];
  float* mp_w =w[12]; float* mp_b =w[13]; float* xp_b1=w[15];
  float* xp_b2=w[17]; float* rp_b =w[19];
  float* ip_b1=w[21]; float* ip_b2=w[23];
  float* fte_b1=w[26];float* fte_b2=w[28];float* out_w=w[29]; float* out_b=w[30];

  ushortT* wt_rl1 = allocU(96*128);
  ushortT* wt_rl2 = allocU(128*128);
  ushortT* wt_sv  = allocU(128*128);
  ushortT* wt_xp1 = allocU(128*128);
  ushortT* wt_xp2 = allocU((size_t)128*384);
  ushortT* wt_rp  = allocU((size_t)96*384);
  ushortT* wt_ip1 = allocU((size_t)480*384);
  ushortT* wt_ip2 = allocU((size_t)384*384);
  ushortT* wt_feq = allocU((size_t)128*256);
  ushortT* wt_ft1 = allocU((size_t)256*128);
  ushortT* wt_ft2 = allocU((size_t)128*384);

  float* s    = alloc((size_t)N*HIDDIM);
  float* h0   = alloc((size_t)N*HIDDIM);      // -> vdot overlay after seg1
  ushortT* sb     = allocU((size_t)N*HIDDIM); // sb+slin_b contiguous -> catb overlay
  ushortT* slin_b = allocU((size_t)N*HIDDIM);
  ushortT* xln_b  = allocU((size_t)N*HIDDIM);
  ushortT* hb     = allocU((size_t)N*HIDDIM);
  float* S    = alloc((size_t)N*384);         // -> vab overlay in phase F
  float* vecacc = alloc((size_t)N*384);       // -> xh2 overlay after f2b
  ushortT* xh_b = allocU((size_t)N*384);
  float* nodeout = alloc((size_t)N);
  float* vdot = h0;
  ushortT* catb = sb;
  ushortT* vab = (ushortT*)S;
  float* xh2 = vecacc;

  size_t wsF = ws_size / sizeof(float);

  // tier selection: tier1 persists rhid (bf16) + edb (fp32) for all E
  int tier = 0;
  size_t p = 739;                         // per-edge chunk floats (tier0)
  if (off + 67ULL*(size_t)E + 16 + 1024ULL*672 <= wsF){ tier = 1; p = 672; }
  ushortT* rhid_a = nullptr; float* edb_a = nullptr;
  if (tier == 1){
    rhid_a = allocU((size_t)E*128);
    edb_a  = alloc((size_t)3*E);
  }
  size_t availF = (wsF > off) ? (wsF - off) : 0;
  if (availF < 256*p){
    k_sentinel<<<1, 64, 0, stream>>>((__hip_bfloat16*)d_out, out_size,
                                     (float)(double)(ws_size >> 20));
    return;
  }
  size_t Cs = availF / p; if (Cs > (size_t)E) Cs = E;
  int C = (int)(Cs & ~(size_t)15);
  if (C < 256) C = 256;

  float* scratch0 = (float*)d_ws + off;
  ushortT* remb_l = allocU((size_t)C*96);     // 48C
  float* edb_l = nullptr; ushortT* rhid_l = nullptr;
  if (tier == 0){
    edb_l  = alloc((size_t)3*C);
    rhid_l = allocU((size_t)C*128);
  }
  ushortT* ew_b = allocU((size_t)C*480);      // 240C ; Rm overlays; geom dumps overlay
  ushortT* R2b  = allocU((size_t)C*384);      // 192C ; R2rl overlays
  ushortT* R1b  = allocU((size_t)C*384);      // 192C
  ushortT* Rmb  = ew_b;
  float* ecv_d  = (float*)ew_b;               // pre-pass dump (6C)
  float* rb_d   = (float*)ew_b + (size_t)6*C; // pre-pass rowscale (C)
  ushortT* R2rl = R2b;
  float* vpc = scratch0;
  size_t scratchF = (size_t)C*p;

  auto mg = [&](const ushortT* A, const ushortT* BT, const float* bias,
                float* Cf, ushortT* Cb, int M, int Nc, int K, int epi,
                const float* rowscale = nullptr, const ushortT* mul1b = nullptr,
                const ushortT* xhpb = nullptr, const int* jidx = nullptr){
    dim3 grid(Nc/128, (M + 127)/128);
    mgemm<<<grid, 256, 0, stream>>>(A, BT, bias, Cf, Cb, M, Nc, K, epi,
                                    rowscale, mul1b, xhpb, jidx);
  };

  // 0) zero header, detect dtypes, int-normalize (+deg histogram)
  k_zero<<<64, 256, 0, stream>>>((float*)flags, (int)zeroHdr);
  k_detect<<<64, 256, 0, stream>>>((const ushortT*)d_in[0], in_sizes[0],
                                   (const int*)d_in[2], in_sizes[2], flags);
  k_iconv<<<1024, 256, 0, stream>>>((const int*)d_in[1], (const int*)d_in[2],
                                    (const int*)d_in[3], zi, bi, eii, N, E, flags, deg);

  // 1) float conversions + transposed bf16 weights
  ConvArgs ca;
  ca.d[0] = { (const ushortT*)d_in[0], pos, in_sizes[0] };
  for (int t = 0; t < 31; ++t)
    ca.d[1+t] = { (const ushortT*)d_in[4+t], w[t], in_sizes[4+t] };
  k_conv<<<dim3(32, 32), 256, 0, stream>>>(ca, 32, flags);

  TArgs ta;
  ta.d[0]  = { (const ushortT*)d_in[4],  wt_rl1, 96, 128 };
  ta.d[1]  = { (const ushortT*)d_in[6],  wt_rl2, 128, 128 };
  ta.d[2]  = { (const ushortT*)d_in[10], wt_sv,  128, 128 };
  ta.d[3]  = { (const ushortT*)d_in[18], wt_xp1, 128, 128 };
  ta.d[4]  = { (const ushortT*)d_in[20], wt_xp2, 128, 384 };
  ta.d[5]  = { (const ushortT*)d_in[22], wt_rp,  96, 384 };
  ta.d[6]  = { (const ushortT*)d_in[24], wt_ip1, 480, 384 };
  ta.d[7]  = { (const ushortT*)d_in[26], wt_ip2, 384, 384 };
  ta.d[8]  = { (const ushortT*)d_in[28], wt_feq, 128, 256 };
  ta.d[9]  = { (const ushortT*)d_in[29], wt_ft1, 256, 128 };
  ta.d[10] = { (const ushortT*)d_in[31], wt_ft2, 128, 384 };
  k_wt<<<dim3(48, 11), 256, 0, stream>>>(ta, 11, flags);

  // 2) CSR scan + scatter
  k_csr_scan<<<1, 256, 0, stream>>>(deg, rowptr, N);
  k_csr_scatter<<<(E + 255)/256, 256, 0, stream>>>(eii, E, rowptr, cursor, jp, ipp);

  // 3) node embedding (+ S/vecacc zero fused)
  k_embed<<<N, 128, 0, stream>>>(zi, ne_w, ne_b, s, h0, S, vecacc);

  if (tier == 1){
    for (int o = 0; o < E; o += C){
      int Cc = (E - o < C) ? (E - o) : C;
      k_geom<<<(Cc + 255)/256, 256, 0, stream>>>(pos, jp, ipp, o, Cc,
                                                 edb_a + (size_t)3*o, ecv_d, rb_d, remb_l);
      mg(remb_l, wt_rl1, rl_b1, nullptr, R2rl, Cc, 128, 96, 1);
      mg(R2rl, wt_rl2, rl_b2, nullptr, rhid_a + (size_t)o*128, Cc, 128, 128, 2, rb_d);
    }
    k_seg1n<<<N, 128, 0, stream>>>(rowptr, jp, 0, E, h0, rhid_a, s);
  } else {
    for (int o = 0; o < E; o += C){
      int Cc = (E - o < C) ? (E - o) : C;
      k_geom<<<(Cc + 255)/256, 256, 0, stream>>>(pos, jp, ipp, o, Cc,
                                                 edb_l, ecv_d, rb_d, remb_l);
      mg(remb_l, wt_rl1, rl_b1, nullptr, R2rl, Cc, 128, 96, 1);
      mg(R2rl, wt_rl2, rl_b2, nullptr, rhid_l, Cc, 128, 128, 2, rb_d);
      k_seg1n<<<N, 128, 0, stream>>>(rowptr, jp, o, Cc, h0, rhid_l, s);
    }
  }

  // Phase C: slin, xln(+sb), xh
  k_ln<<<N, 128, 0, stream>>>(s, xln_b, mp_w, mp_b, sb);
  mg(sb, wt_sv, sv_b, nullptr, slin_b, N, 128, 128, 1);
  mg(xln_b, wt_xp1, xp_b1, nullptr, hb, N, 128, 128, 1);
  mg(hb, wt_xp2, xp_b2, nullptr, xh_b, N, 384, 128, 0);

  // Phase D: seg2
  if (tier == 1){
    k_seg2n<<<N, 128, 0, stream>>>(rowptr, jp, 0, E, slin_b, rhid_a, edb_a, S);
  } else {
    for (int o = 0; o < E; o += C){
      int Cc = (E - o < C) ? (E - o) : C;
      k_geom<<<(Cc + 255)/256, 256, 0, stream>>>(pos, jp, ipp, o, Cc,
                                                 edb_l, ecv_d, rb_d, remb_l);
      mg(remb_l, wt_rl1, rl_b1, nullptr, R2rl, Cc, 128, 96, 1);
      mg(R2rl, wt_rl2, rl_b2, nullptr, rhid_l, Cc, 128, 128, 2, rb_d);
      k_seg2n<<<N, 128, 0, stream>>>(rowptr, jp, o, Cc, slin_b, rhid_l, edb_l, S);
    }
  }

  // Phase E: per-edge big MLPs + seg3
  for (int o = 0; o < E; o += C){
    int Cc = (E - o < C) ? (E - o) : C;
    const ushortT* rhid_p; const float* edb_p;
    if (tier == 1){
      rhid_p = rhid_a + (size_t)o*128;
      edb_p  = edb_a + (size_t)3*o;
    } else {
      k_geom<<<(Cc + 255)/256, 256, 0, stream>>>(pos, jp, ipp, o, Cc,
                                                 edb_l, ecv_d, rb_d, remb_l);
      mg(remb_l, wt_rl1, rl_b1, nullptr, R2rl, Cc, 128, 96, 1);
      mg(R2rl, wt_rl2, rl_b2, nullptr, rhid_l, Cc, 128, 128, 2, rb_d);
      rhid_p = rhid_l; edb_p = edb_l;
    }
    k_scal2<<<Cc, 256, 0, stream>>>(jp, ipp, o, pos, S, rhid_p,
                                    l3_w1, l3_b1, l3_w2, l3_b2, ew_b, remb_l);
    mg(remb_l, wt_rp, rp_b, nullptr, R1b, Cc, 384, 96, 0);
    mg(ew_b, wt_ip1, ip_b1, nullptr, R2b, Cc, 384, 480, 1);
    mg(R2b, wt_ip2, ip_b2, nullptr, Rmb, Cc, 384, 384, 3, nullptr, R1b, xh_b, jp + o);
    k_seg3n<<<N, 128, 0, stream>>>(rowptr, o, Cc, Rmb, edb_p, s, vecacc);
  }

  // Phase F: fte
  k_f2b<<<1024, 256, 0, stream>>>(vecacc, vab, N*384);
  int Cn = (int)(scratchF / 768);
  if (Cn > N) Cn = N;
  for (int no = 0; no < N; no += Cn){
    int Cc = (N - no < Cn) ? (N - no) : Cn;
    mg(vab + (size_t)no*384, wt_feq, nullptr, vpc, nullptr, 3*Cc, 256, 128, 0);
    k_fte_pre<<<Cc, 128, 0, stream>>>(vpc, s, catb, vdot, no);
  }
  mg(catb, wt_ft1, fte_b1, nullptr, hb, N, 128, 256, 1);
  mg(hb, wt_ft2, fte_b2, xh2, nullptr, N, 384, 128, 0);

  // Phase G
  k_out<<<N, 128, 0, stream>>>(xh2, vdot, s, out_w, out_b, nodeout);
  k_final<<<out_size, 256, 0, stream>>>(nodeout, bi, d_out, N, flags);
}

// Round 9
// 2024.304 us; speedup vs baseline: 3.8821x; 1.0706x over previous
//
#include <hip/hip_runtime.h>
#include <hip/hip_bf16.h>
#include <math.h>

#define NRAD 96
#define HIDDIM 128
typedef unsigned short ushortT;

typedef __attribute__((ext_vector_type(8))) short bf8_t;   // 8 bf16 (4 VGPRs)
typedef __attribute__((ext_vector_type(4))) float f4_t;    // 4 fp32 acc

#if defined(__has_builtin)
#  if __has_builtin(__builtin_amdgcn_global_load_lds)
#    define HAVE_GLDS 1
#  endif
#  if __has_builtin(__builtin_amdgcn_rcpf)
#    define RCPF(x) __builtin_amdgcn_rcpf(x)
#  endif
#  if __has_builtin(__builtin_amdgcn_exp2f)
#    define EXP2F(x) __builtin_amdgcn_exp2f(x)
#  endif
#  if __has_builtin(__builtin_amdgcn_cosf)
#    define COSR(x) __builtin_amdgcn_cosf(x)   /* cos(2*pi*x) */
#  endif
#endif
#ifndef RCPF
#  define RCPF(x) (1.f/(x))
#endif
#ifndef EXP2F
#  define EXP2F(x) exp2f(x)
#endif
#ifndef COSR
#  define COSR(x) cosf(6.2831853071795864f*(x))
#endif
#define LOG2E 1.44269504088896f
#define LN2   0.69314718055995f

__device__ __forceinline__ float silu_f(float x){
  return x * RCPF(1.f + EXP2F(-LOG2E*x));
}
__device__ __forceinline__ float b2f(ushortT u){ return __uint_as_float(((unsigned int)u) << 16); }
__device__ __forceinline__ ushortT f2b(float x){
  unsigned int u = __float_as_uint(x);
  unsigned int r = (u + 0x7fffu + ((u >> 16) & 1u)) >> 16;
  return (ushortT)r;
}

#ifdef HAVE_GLDS
__device__ __forceinline__ void glds16(const ushortT* g, ushortT* l){
  __builtin_amdgcn_global_load_lds(
      (const __attribute__((address_space(1))) ushortT*)g,
      (__attribute__((address_space(3))) ushortT*)l, 16, 0, 0);
}
#endif

// ---------------- dtype detection (parallel) ----------------
__global__ void k_detect(const ushortT* posw, int npos,
                         const int* batchw, int nb, int* flags){
  int tot = (npos < 4096 ? npos : 4096);
  int big = tot > nb ? tot : nb;
  int bad = 0, orv = 0;
  for (int t = blockIdx.x*blockDim.x + threadIdx.x; t < big; t += gridDim.x*blockDim.x){
    if (t < tot){
      float x = b2f(posw[t]);
      if (!(fabsf(x) <= 1000.f)) bad = 1;
    }
    if (t < nb && (t & 1)) orv |= batchw[t];
  }
  if (bad) atomicOr(&flags[2], 1);
  if (orv) atomicOr(&flags[3], 1);
}

__global__ void k_iconv(const int* zsrc, const int* bsrc, const int* esrc,
                        int* zi, int* bi, int* eii, int Nn, int E, const int* flags,
                        int* deg){
  int f = (flags[3] == 0) ? 1 : 0;   // 1 => int64
  int total = 2*Nn + 2*E;
  for (int t = blockIdx.x*blockDim.x + threadIdx.x; t < total; t += gridDim.x*blockDim.x){
    if (t < Nn) zi[t] = zsrc[(size_t)t << f];
    else if (t < 2*Nn) bi[t-Nn] = bsrc[(size_t)(t-Nn) << f];
    else {
      int e = t - 2*Nn;
      int v = esrc[(size_t)e << f];
      eii[e] = v;
      if (e >= E) atomicAdd(&deg[v], 1);
    }
  }
}

// ---------------- conversion: (bf16|f32) -> f32 ----------------
struct ConvDesc { const ushortT* src; float* dst; int n; };
struct ConvArgs { ConvDesc d[32]; };

__global__ void k_conv(ConvArgs a, int cnt, const int* flags){
  int y = blockIdx.y;
  if (y >= cnt) return;
  int f = (flags[2] == 0) ? 1 : 0;    // 1 => bf16
  const ushortT* s = a.d[y].src;
  float* dst = a.d[y].dst;
  int n = a.d[y].n;
  if (f){
    for (int t = blockIdx.x*blockDim.x + threadIdx.x; t < n; t += gridDim.x*blockDim.x)
      dst[t] = b2f(s[t]);
  } else {
    const float* sf = (const float*)s;
    for (int t = blockIdx.x*blockDim.x + threadIdx.x; t < n; t += gridDim.x*blockDim.x)
      dst[t] = sf[t];
  }
}

// ---------------- weight transpose -> bf16 [N][K] ----------------
struct TDesc { const ushortT* src; ushortT* dst; int K, N; };
struct TArgs { TDesc d[12]; };

__global__ void k_wt(TArgs a, int cnt, const int* flags){
  int y = blockIdx.y;
  if (y >= cnt) return;
  int f = (flags[2] == 0) ? 1 : 0;
  const ushortT* s = a.d[y].src;
  ushortT* dst = a.d[y].dst;
  int K = a.d[y].K, N = a.d[y].N, tot = K*N;
  for (int t = blockIdx.x*blockDim.x + threadIdx.x; t < tot; t += gridDim.x*blockDim.x){
    int k = t / N, n = t - k*N;
    ushortT v = f ? s[t] : f2b(((const float*)s)[t]);
    dst[(size_t)n*K + k] = v;
  }
}

__global__ void k_f2b(const float* __restrict__ src, ushortT* __restrict__ dst, int n){
  for (int t = blockIdx.x*blockDim.x + threadIdx.x; t < n; t += gridDim.x*blockDim.x)
    dst[t] = f2b(src[t]);
}

__global__ void k_zero(float* __restrict__ p, int n){
  int t = blockIdx.x*blockDim.x + threadIdx.x;
  int stride = gridDim.x*blockDim.x;
  for (; t < n; t += stride) p[t] = 0.f;
}

__global__ void k_sentinel(__hip_bfloat16* out, int n, float val){
  int t = threadIdx.x;
  if (t < n) out[t] = __float2bfloat16(val);
}

// ---------------- CSR scan + scatter ----------------
__global__ void k_csr_scan(const int* __restrict__ deg, int* __restrict__ rowptr, int Nn){
  __shared__ int sh[256];
  __shared__ int carry;
  if (threadIdx.x == 0){ carry = 0; rowptr[0] = 0; }
  __syncthreads();
  for (int t0 = 0; t0 < Nn; t0 += 256){
    int idx = t0 + threadIdx.x;
    int v = (idx < Nn) ? deg[idx] : 0;
    sh[threadIdx.x] = v; __syncthreads();
    for (int o = 1; o < 256; o <<= 1){
      int u = (threadIdx.x >= o) ? sh[threadIdx.x - o] : 0;
      __syncthreads();
      sh[threadIdx.x] += u; __syncthreads();
    }
    if (idx < Nn) rowptr[idx + 1] = carry + sh[threadIdx.x];
    __syncthreads();
    if (threadIdx.x == 0) carry += sh[255];
    __syncthreads();
  }
}

__global__ void k_csr_scatter(const int* __restrict__ eii, int E,
                              const int* __restrict__ rowptr, int* __restrict__ cursor,
                              int* __restrict__ jp, int* __restrict__ ip){
  int e = blockIdx.x*blockDim.x + threadIdx.x;
  if (e >= E) return;
  int i = eii[E+e];
  int p = atomicAdd(&cursor[i], 1);
  int k = rowptr[i] + p;
  jp[k] = eii[e];
  ip[k] = i;
}

// ---------------- geometry + RBF ----------------
__global__ void k_geom(const float* __restrict__ pos,
                       const int* __restrict__ jp, const int* __restrict__ ip,
                       int off, int Cc,
                       float* __restrict__ edb, float* __restrict__ ecv,
                       float* __restrict__ rb, ushortT* __restrict__ remb)
{
  int el = blockIdx.x*blockDim.x + threadIdx.x;
  if (el >= Cc) return;
  int g = off + el;
  int j = jp[g], i = ip[g];
  float pjx = pos[3*j], pjy = pos[3*j+1], pjz = pos[3*j+2];
  float pix = pos[3*i], piy = pos[3*i+1], piz = pos[3*i+2];
  float vx = pjx-pix, vy = pjy-piy, vz = pjz-piz;
  float d = sqrtf(vx*vx + vy*vy + vz*vz);
  float inv = RCPF(d + 1e-10f);
  float edx = vx*inv, edy = vy*inv, edz = vz*inv;
  edb[3*el]=edx; edb[3*el+1]=edy; edb[3*el+2]=edz;
  if (ecv){
    float cx = piy*pjz - piz*pjy;
    float cy = piz*pjx - pix*pjz;
    float cz = pix*pjy - piy*pjx;
    float cn = sqrtf(cx*cx + cy*cy + cz*cz);
    float inv2 = RCPF(cn + 1e-10f);
    cx *= inv2; cy *= inv2; cz *= inv2;
    ecv[6*el]=cx; ecv[6*el+1]=cy; ecv[6*el+2]=cz;
    ecv[6*el+3]=edy*cz - edz*cy;
    ecv[6*el+4]=edz*cx - edx*cz;
    ecv[6*el+5]=edx*cy - edy*cx;
  }
  float rbv = 0.5f*(COSR(d*0.08333333333f) + 1.f);   // cos(d*pi/6)
  rb[el] = rbv;
  float env = (d < 6.f) ? rbv : 0.f;
  const float stf = 0.0024787522f;
  const float prf = (2.0f/96.0f)*(1.0f - stf);
  const float betaL = LOG2E/(prf*prf);
  float emd = EXP2F(-LOG2E*d);
  for (int k = 0; k < NRAD; ++k){
    float mu = stf + (1.0f - stf)*((float)k*(1.0f/95.0f));
    float t = emd - mu;
    remb[(size_t)el*NRAD + k] = f2b(env * EXP2F(-betaL*t*t));
  }
}

// ---------------- node embedding + layernorm (+ fused accumulator zeroing) ----------------
__global__ __launch_bounds__(128) void k_embed(const int* __restrict__ z,
    const float* __restrict__ ne_w, const float* __restrict__ ne_b,
    float* __restrict__ s, float* __restrict__ h0,
    float* __restrict__ S, float* __restrict__ vecacc)
{
  int n = blockIdx.x; int h = threadIdx.x;
  float x = ne_w[(size_t)z[n]*HIDDIM + h] + ne_b[h];
  __shared__ float red[128];
  red[h] = x; __syncthreads();
  for (int o = 64; o > 0; o >>= 1){ if (h < o) red[h] += red[h+o]; __syncthreads(); }
  float mean = red[0] * (1.f/128.f);
  __syncthreads();
  float dx = x - mean;
  red[h] = dx*dx; __syncthreads();
  for (int o = 64; o > 0; o >>= 1){ if (h < o) red[h] += red[h+o]; __syncthreads(); }
  float var = red[0] * (1.f/128.f);
  float y = dx * rsqrtf(var + 1e-5f);
  s[(size_t)n*HIDDIM + h] = y;
  h0[(size_t)n*HIDDIM + h] = y;
  float* Sr = &S[(size_t)n*384 + h];
  float* Vr = &vecacc[(size_t)n*384 + h];
  Sr[0]=0.f; Sr[128]=0.f; Sr[256]=0.f;
  Vr[0]=0.f; Vr[128]=0.f; Vr[256]=0.f;
}

// LN -> xln_b, plus fused s -> sb conversion
__global__ __launch_bounds__(128) void k_ln(const float* __restrict__ src, ushortT* __restrict__ dst,
    const float* __restrict__ g, const float* __restrict__ b, ushortT* __restrict__ sb)
{
  int n = blockIdx.x; int h = threadIdx.x;
  float x = src[(size_t)n*HIDDIM + h];
  sb[(size_t)n*HIDDIM + h] = f2b(x);
  __shared__ float red[128];
  red[h] = x; __syncthreads();
  for (int o = 64; o > 0; o >>= 1){ if (h < o) red[h] += red[h+o]; __syncthreads(); }
  float mean = red[0] * (1.f/128.f);
  __syncthreads();
  float dx = x - mean;
  red[h] = dx*dx; __syncthreads();
  for (int o = 64; o > 0; o >>= 1){ if (h < o) red[h] += red[h+o]; __syncthreads(); }
  float var = red[0] * (1.f/128.f);
  float y = dx * rsqrtf(var + 1e-5f);
  dst[(size_t)n*HIDDIM + h] = f2b(y * g[h] + b[h]);
}

// ---------------- rowptr-based segment sums (one block per node) ----------------
__global__ __launch_bounds__(128) void k_seg1n(const int* __restrict__ rowptr,
    const int* __restrict__ jp, int o, int Cc,
    const float* __restrict__ h0, const ushortT* __restrict__ rhid,
    float* __restrict__ s)
{
  int i = blockIdx.x, h = threadIdx.x;
  int b = rowptr[i], e = rowptr[i+1];
  if (b < o) b = o;
  int hi = o + Cc; if (e > hi) e = hi;
  if (b >= e) return;
  float acc = 0.f;
  int m = b;
  for (; m + 1 < e; m += 2){
    int j0 = jp[m], j1 = jp[m+1];
    float r0 = b2f(rhid[(size_t)(m-o)*HIDDIM + h]);
    float r1 = b2f(rhid[(size_t)(m+1-o)*HIDDIM + h]);
    acc += h0[(size_t)j0*HIDDIM + h]*r0 + h0[(size_t)j1*HIDDIM + h]*r1;
  }
  if (m < e) acc += h0[(size_t)jp[m]*HIDDIM + h] * b2f(rhid[(size_t)(m-o)*HIDDIM + h]);
  s[(size_t)i*HIDDIM + h] += acc;
}

__global__ __launch_bounds__(128) void k_seg2n(const int* __restrict__ rowptr,
    const int* __restrict__ jp, int o, int Cc,
    const ushortT* __restrict__ slin, const ushortT* __restrict__ rhid,
    const float* __restrict__ edb, float* __restrict__ S)
{
  int i = blockIdx.x, h = threadIdx.x;
  int b = rowptr[i], e = rowptr[i+1];
  if (b < o) b = o;
  int hi = o + Cc; if (e > hi) e = hi;
  if (b >= e) return;
  float a0 = 0.f, a1 = 0.f, a2 = 0.f;
  int m = b;
  for (; m + 1 < e; m += 2){
    int ml = m - o, ml2 = ml + 1;
    float u0 = b2f(slin[(size_t)jp[m]*HIDDIM + h])   * b2f(rhid[(size_t)ml*HIDDIM + h]);
    float u1 = b2f(slin[(size_t)jp[m+1]*HIDDIM + h]) * b2f(rhid[(size_t)ml2*HIDDIM + h]);
    a0 += u0*edb[3*ml]   + u1*edb[3*ml2];
    a1 += u0*edb[3*ml+1] + u1*edb[3*ml2+1];
    a2 += u0*edb[3*ml+2] + u1*edb[3*ml2+2];
  }
  if (m < e){
    int ml = m - o;
    float u0 = b2f(slin[(size_t)jp[m]*HIDDIM + h]) * b2f(rhid[(size_t)ml*HIDDIM + h]);
    a0 += u0*edb[3*ml]; a1 += u0*edb[3*ml+1]; a2 += u0*edb[3*ml+2];
  }
  float* base = &S[(size_t)i*384 + h];
  base[0]   += a0;
  base[128] += a1;
  base[256] += a2;
}

__global__ __launch_bounds__(128) void k_seg3n(const int* __restrict__ rowptr,
    int o, int Cc,
    const ushortT* __restrict__ mb, const float* __restrict__ edb,
    float* __restrict__ s, float* __restrict__ vecacc)
{
  int i = blockIdx.x, h = threadIdx.x;
  int b = rowptr[i], e = rowptr[i+1];
  if (b < o) b = o;
  int hi = o + Cc; if (e > hi) e = hi;
  if (b >= e) return;
  const float is128 = 0.08838834764831845f;
  float am = 0.f, v0 = 0.f, v1 = 0.f, v2 = 0.f;
  int m = b;
  for (; m + 1 < e; m += 2){
    int ml = m - o, ml2 = ml + 1;
    float m1a = b2f(mb[(size_t)ml*384 + h]);
    float m1b = b2f(mb[(size_t)ml2*384 + h]);
    float mma = b2f(mb[(size_t)ml*384 + 256 + h]) * is128;
    float mmb = b2f(mb[(size_t)ml2*384 + 256 + h]) * is128;
    am += m1a + m1b;
    v0 += mma*edb[3*ml]   + mmb*edb[3*ml2];
    v1 += mma*edb[3*ml+1] + mmb*edb[3*ml2+1];
    v2 += mma*edb[3*ml+2] + mmb*edb[3*ml2+2];
  }
  if (m < e){
    int ml = m - o;
    float m1 = b2f(mb[(size_t)ml*384 + h]);
    float mm = b2f(mb[(size_t)ml*384 + 256 + h]) * is128;
    am += m1;
    v0 += mm*edb[3*ml]; v1 += mm*edb[3*ml+1]; v2 += mm*edb[3*ml+2];
  }
  s[(size_t)i*HIDDIM + h] += am;
  float* base = &vecacc[(size_t)i*384 + h];
  base[0]   += v0;
  base[128] += v1;
  base[256] += v2;
}

// ---------------- fused geometry + scalarize + ew assembly ----------------
// block = 1 edge, 256 threads: which = t>>7, h = t&127
// Geometry computed once (thread 0) -> LDS; l3 weights pre-scaled in LDS.
__global__ __launch_bounds__(256) void k_scal2(
  const int* __restrict__ jp, const int* __restrict__ ip, int off,
  const float* __restrict__ pos, const float* __restrict__ S,
  const ushortT* __restrict__ rhid,
  const float* __restrict__ w1, const float* __restrict__ b1,
  const float* __restrict__ w2, const float* __restrict__ b2,
  ushortT* __restrict__ ew,
  ushortT* __restrict__ remb_out, const ushortT* __restrict__ remb_src)
{
  __shared__ float geo[11];
  __shared__ float w1s[96], b1s[32], w2s[32];
  __shared__ float sb2;
  int el = blockIdx.x;
  int g = off + el;
  int t = threadIdx.x;
  if (t < 96) w1s[t] = w1[t] * (-LOG2E);
  else if (t < 128) b1s[t-96] = b1[t-96] * (-LOG2E);
  else if (t < 160) w2s[t-128] = w2[t-128] * (-LN2);
  else if (t == 160) sb2 = b2[0];
  if (t == 0){
    int j = jp[g], i = ip[g];
    float pjx = pos[3*j], pjy = pos[3*j+1], pjz = pos[3*j+2];
    float pix = pos[3*i], piy = pos[3*i+1], piz = pos[3*i+2];
    float vx = pjx-pix, vy = pjy-piy, vz = pjz-piz;
    float d = sqrtf(vx*vx + vy*vy + vz*vz);
    float inv = RCPF(d + 1e-10f);
    float f00 = vx*inv, f01 = vy*inv, f02 = vz*inv;
    float cx = piy*pjz - piz*pjy;
    float cy = piz*pjx - pix*pjz;
    float cz = pix*pjy - piy*pjx;
    float cn = sqrtf(cx*cx + cy*cy + cz*cz);
    float inv2 = RCPF(cn + 1e-10f);
    float f10 = cx*inv2, f11 = cy*inv2, f12 = cz*inv2;
    geo[0]=f00; geo[1]=f01; geo[2]=f02;
    geo[3]=f10; geo[4]=f11; geo[5]=f12;
    geo[6]=f01*f12 - f02*f11;
    geo[7]=f02*f10 - f00*f12;
    geo[8]=f00*f11 - f01*f10;
    geo[9]=0.5f*(COSR(d*0.08333333333f) + 1.f);
    geo[10]=d;
  }
  __syncthreads();
  int which = t >> 7;
  int h = t & 127;
  int n = which ? jp[g] : ip[g];
  const float* Sn = &S[(size_t)n*384];
  float S0 = Sn[h], S1 = Sn[128+h], S2 = Sn[256+h];
  float v0 = S0*geo[0] + S1*geo[1] + S2*geo[2];
  float v1 = fabsf(S0*geo[3] + S1*geo[4] + S2*geo[5]);
  float v2 = S0*geo[6] + S1*geo[7] + S2*geo[8];
  float out = 0.f;
  #pragma unroll
  for (int u = 0; u < 32; ++u){
    float tt = fmaf(v0, w1s[u], fmaf(v1, w1s[32+u], fmaf(v2, w1s[64+u], b1s[u])));
    float r = RCPF(1.f + EXP2F(tt));
    out = fmaf(tt*r, w2s[u], out);
  }
  float scal = out + sb2 + v0;
  ushortT* ewr = &ew[(size_t)el*480];
  ewr[which*128 + h] = f2b(scal * geo[9]);
  if (which == 0){
    ewr[256 + h] = rhid[(size_t)el*HIDDIM + h];
    if (h < NRAD){
      ushortT rv;
      if (remb_src){
        rv = remb_src[(size_t)el*NRAD + h];
      } else {
        float d = geo[10];
        float rbv = geo[9];
        float env = (d < 6.f) ? rbv : 0.f;
        const float stf = 0.0024787522f;
        const float prf = (2.0f/96.0f)*(1.0f - stf);
        const float betaL = LOG2E/(prf*prf);
        float mu = stf + (1.0f - stf)*((float)h*(1.0f/95.0f));
        float tr = EXP2F(-LOG2E*d) - mu;
        rv = f2b(env * EXP2F(-betaL*tr*tr));
        remb_out[(size_t)el*NRAD + h] = rv;
      }
      ewr[384 + h] = rv;
    }
  }
}

// ---------------- bf16 MFMA GEMM ----------------
// A: MxK bf16 row-major; BT: NxK bf16 row-major. N%128==0, K%32==0.
// epi: 0 none, 1 silu, 2 *rowscale[row], 3 *mul1b[row,col]*xhpb[jidx[row],col]
// skipTile >= 0: that 128-col tile is not computed (grid.x is one smaller).
__global__ __launch_bounds__(256) void mgemm(
  const ushortT* __restrict__ A, const ushortT* __restrict__ BT,
  const float* __restrict__ bias,
  float* __restrict__ Cf, ushortT* __restrict__ Cb,
  int M, int N, int K, int epi,
  const float* __restrict__ rowscale,
  const ushortT* __restrict__ mul1b,
  const ushortT* __restrict__ xhpb,
  const int* __restrict__ jidx,
  int skipTile)
{
  const int tid = threadIdx.x;
  const int w = tid >> 6;
  const int lane = tid & 63;
  const int l15 = lane & 15;
  const int q = lane >> 4;
  const int wm = w & 1, wn = w >> 1;
  const int rowBase = blockIdx.y * 128;
  int bx = blockIdx.x;
  if (skipTile >= 0 && bx >= skipTile) bx++;
  const int colBase = bx * 128;
  f4_t acc[4][4] = {};

#ifdef HAVE_GLDS
  __shared__ ushortT As[128*32];
  __shared__ ushortT Bs[128*32];
  const int rS = 32*w + (lane >> 2);
  const int kS = (lane & 3) << 3;
  ushortT* lA0 = &As[(32*w)*32];
  ushortT* lA1 = &As[(32*w+16)*32];
  ushortT* lB0 = &Bs[(32*w)*32];
  ushortT* lB1 = &Bs[(32*w+16)*32];
  int ra0 = rowBase + rS;      if (ra0 >= M) ra0 = M-1;
  int ra1 = rowBase + rS + 16; if (ra1 >= M) ra1 = M-1;
  const ushortT* gA0 = A  + (size_t)ra0*K + kS;
  const ushortT* gA1 = A  + (size_t)ra1*K + kS;
  const ushortT* gB0 = BT + (size_t)(colBase + rS)*K + kS;
  const ushortT* gB1 = BT + (size_t)(colBase + rS + 16)*K + kS;
  for (int k0 = 0; k0 < K; k0 += 32){
    glds16(gA0 + k0, lA0);
    glds16(gA1 + k0, lA1);
    glds16(gB0 + k0, lB0);
    glds16(gB1 + k0, lB1);
    __syncthreads();
    bf8_t a[4], b[4];
    #pragma unroll
    for (int mt = 0; mt < 4; ++mt)
      a[mt] = *(const bf8_t*)&As[(wm*64 + mt*16 + l15)*32 + q*8];
    #pragma unroll
    for (int nt = 0; nt < 4; ++nt)
      b[nt] = *(const bf8_t*)&Bs[(wn*64 + nt*16 + l15)*32 + q*8];
    #pragma unroll
    for (int mt = 0; mt < 4; ++mt){
      #pragma unroll
      for (int nt = 0; nt < 4; ++nt)
        acc[mt][nt] = __builtin_amdgcn_mfma_f32_16x16x32_bf16(a[mt], b[nt], acc[mt][nt], 0, 0, 0);
    }
    __syncthreads();
  }
#else
  __shared__ ushortT As[128*48];
  __shared__ ushortT Bs[128*48];
  const int r0 = tid >> 2,         s0 = (tid & 3) << 3;
  const int r1 = (tid + 256) >> 2, s1 = ((tid + 256) & 3) << 3;
  for (int k0 = 0; k0 < K; k0 += 32){
    int4 a0v = make_int4(0,0,0,0), a1v = make_int4(0,0,0,0);
    if (rowBase + r0 < M) a0v = *(const int4*)&A[(size_t)(rowBase + r0)*K + k0 + s0];
    if (rowBase + r1 < M) a1v = *(const int4*)&A[(size_t)(rowBase + r1)*K + k0 + s1];
    int4 b0v = *(const int4*)&BT[(size_t)(colBase + r0)*K + k0 + s0];
    int4 b1v = *(const int4*)&BT[(size_t)(colBase + r1)*K + k0 + s1];
    __syncthreads();
    *(int4*)&As[r0*48 + s0] = a0v;
    *(int4*)&As[r1*48 + s1] = a1v;
    *(int4*)&Bs[r0*48 + s0] = b0v;
    *(int4*)&Bs[r1*48 + s1] = b1v;
    __syncthreads();
    bf8_t a[4], b[4];
    #pragma unroll
    for (int mt = 0; mt < 4; ++mt)
      a[mt] = *(const bf8_t*)&As[(wm*64 + mt*16 + l15)*48 + q*8];
    #pragma unroll
    for (int nt = 0; nt < 4; ++nt)
      b[nt] = *(const bf8_t*)&Bs[(wn*64 + nt*16 + l15)*48 + q*8];
    #pragma unroll
    for (int mt = 0; mt < 4; ++mt){
      #pragma unroll
      for (int nt = 0; nt < 4; ++nt)
        acc[mt][nt] = __builtin_amdgcn_mfma_f32_16x16x32_bf16(a[mt], b[nt], acc[mt][nt], 0, 0, 0);
    }
  }
#endif

  #pragma unroll
  for (int mt = 0; mt < 4; ++mt){
    int row = rowBase + wm*64 + mt*16 + q*4;
    #pragma unroll
    for (int nt = 0; nt < 4; ++nt){
      int col = colBase + wn*64 + nt*16 + l15;
      float bv = bias ? bias[col] : 0.f;
      #pragma unroll
      for (int r = 0; r < 4; ++r){
        int rr = row + r;
        if (rr >= M) continue;
        float x = acc[mt][nt][r] + bv;
        if (epi == 1) x = silu_f(x);
        else if (epi == 2) x *= rowscale[rr];
        else if (epi == 3) x = x * b2f(mul1b[(size_t)rr*N + col]) * b2f(xhpb[(size_t)jidx[rr]*N + col]);
        if (Cb) Cb[(size_t)rr*N + col] = f2b(x);
        else    Cf[(size_t)rr*N + col] = x;
      }
    }
  }
}

// ---------------- fte prep ----------------
__global__ __launch_bounds__(128) void k_fte_pre(const float* __restrict__ vpc,
    const float* __restrict__ s, ushortT* __restrict__ catb, float* __restrict__ vdot,
    int no)
{
  int nl = blockIdx.x, h = threadIdx.x;
  int n = no + nl;
  const float* base = &vpc[(size_t)nl*768];
  float a0 = base[h],       a1 = base[256+h],     a2 = base[512+h];
  float c0 = base[128+h],   c1 = base[384+h],     c2 = base[640+h];
  float scal = sqrtf(a0*a0 + a1*a1 + a2*a2 + 1e-10f);
  float vd = (a0*c0 + a1*c1 + a2*c2) * 0.08838834764831845f;
  catb[(size_t)n*256 + h] = f2b(s[(size_t)n*HIDDIM + h]);
  catb[(size_t)n*256 + 128 + h] = f2b(scal);
  vdot[(size_t)n*HIDDIM + h] = vd;
}

// ---------------- final ----------------
__global__ __launch_bounds__(128) void k_out(const float* __restrict__ xh2,
    const float* __restrict__ vdot, const float* __restrict__ s,
    const float* __restrict__ ow, const float* __restrict__ ob,
    float* __restrict__ nodeout)
{
  int n = blockIdx.x, h = threadIdx.x;
  float a1 = xh2[(size_t)n*384 + h];
  float a2 = xh2[(size_t)n*384 + 128 + h];
  float sv = s[(size_t)n*HIDDIM + h] + (a1 + a2*vdot[(size_t)n*HIDDIM + h]) * 0.7071067811865476f;
  __shared__ float red[128];
  red[h] = sv * ow[h];
  __syncthreads();
  for (int o = 64; o > 0; o >>= 1){ if (h < o) red[h] += red[h+o]; __syncthreads(); }
  if (h == 0) nodeout[n] = red[0] + ob[0];
}

__global__ __launch_bounds__(256) void k_final(const float* __restrict__ nodeout,
    const int* __restrict__ batch, void* __restrict__ out, int Nn, const int* flags)
{
  int g = blockIdx.x;
  __shared__ float rs[256], rc[256];
  float sm = 0.f, c = 0.f;
  for (int n = threadIdx.x; n < Nn; n += 256){
    if (batch[n] == g){ sm += nodeout[n]; c += 1.f; }
  }
  rs[threadIdx.x] = sm; rc[threadIdx.x] = c;
  __syncthreads();
  for (int o = 128; o > 0; o >>= 1){
    if (threadIdx.x < o){ rs[threadIdx.x] += rs[threadIdx.x+o]; rc[threadIdx.x] += rc[threadIdx.x+o]; }
    __syncthreads();
  }
  if (threadIdx.x == 0){
    float v = (rc[0] > 0.f) ? rs[0]/rc[0] : 0.f;
    if (flags[2] == 0) ((__hip_bfloat16*)out)[g] = __float2bfloat16(v);
    else ((float*)out)[g] = v;
  }
}

// =====================================================================
extern "C" void kernel_launch(void* const* d_in, const int* in_sizes, int n_in,
                              void* d_out, int out_size, void* d_ws, size_t ws_size,
                              hipStream_t stream)
{
  const int N = in_sizes[0] / 3;
  const int E = in_sizes[3] / 2;

  size_t off = 0;
  auto alloc = [&](size_t n)->float*{
    float* p = (float*)d_ws + off;
    off += (n + 3) & ~(size_t)3;
    return p;
  };
  auto allocU = [&](size_t n)->ushortT*{ return (ushortT*)alloc((n + 1) / 2); };

  int* flags  = (int*)alloc(4);
  int* deg    = (int*)alloc((size_t)N);
  int* cursor = (int*)alloc((size_t)N);
  size_t zeroHdr = off;
  int* zi     = (int*)alloc((size_t)N);
  int* bi     = (int*)alloc((size_t)N);
  int* eii    = (int*)alloc((size_t)2*E);
  int* rowptr = (int*)alloc((size_t)N + 4);
  int* jp     = (int*)alloc((size_t)E);
  int* ipp    = (int*)alloc((size_t)E);

  float* pos = alloc((size_t)N*3);
  float* w[31];
  for (int t = 0; t < 31; ++t) w[t] = alloc((size_t)in_sizes[4+t]);
  float* rl_b1=w[1];  float* rl_b2=w[3];
  float* ne_w =w[4];  float* ne_b =w[5];  float* sv_b =w[7];
  float* l3_w1=w[8];  float* l3_b1=w[9];  float* l3_w2=w[10]; float* l3_b2=w[11];
  float* mp_w =w[12]; float* mp_b =w[13]; float* xp_b1=w[15];
  float* xp_b2=w[17]; float* rp_b =w[19];
  float* ip_b1=w[21]; float* ip_b2=w[23];
  float* fte_b1=w[26];float* fte_b2=w[28];float* out_w=w[29]; float* out_b=w[30];

  ushortT* wt_rl1 = allocU(96*128);
  ushortT* wt_rl2 = allocU(128*128);
  ushortT* wt_sv  = allocU(128*128);
  ushortT* wt_xp1 = allocU(128*128);
  ushortT* wt_xp2 = allocU((size_t)128*384);
  ushortT* wt_rp  = allocU((size_t)96*384);
  ushortT* wt_ip1 = allocU((size_t)480*384);
  ushortT* wt_ip2 = allocU((size_t)384*384);
  ushortT* wt_feq = allocU((size_t)128*256);
  ushortT* wt_ft1 = allocU((size_t)256*128);
  ushortT* wt_ft2 = allocU((size_t)128*384);

  float* s    = alloc((size_t)N*HIDDIM);
  float* h0   = alloc((size_t)N*HIDDIM);      // -> vdot overlay after seg1
  ushortT* sb     = allocU((size_t)N*HIDDIM); // sb+slin_b contiguous -> catb overlay
  ushortT* slin_b = allocU((size_t)N*HIDDIM);
  ushortT* xln_b  = allocU((size_t)N*HIDDIM);
  ushortT* hb     = allocU((size_t)N*HIDDIM);
  float* S    = alloc((size_t)N*384);         // -> vab overlay in phase F
  float* vecacc = alloc((size_t)N*384);       // -> xh2 overlay after f2b
  ushortT* xh_b = allocU((size_t)N*384);
  float* nodeout = alloc((size_t)N);
  float* vdot = h0;
  ushortT* catb = sb;
  ushortT* vab = (ushortT*)S;
  float* xh2 = vecacc;

  size_t wsF = ws_size / sizeof(float);

  // tier selection:
  //  tier2: persist edb(3f) + rhid(64f) + remb(48f) + rb(1f) per edge; chunk 624 f/edge
  //  tier1: persist edb + rhid (67f);                               chunk 672 f/edge
  //  tier0: nothing persists;                                       chunk 739 f/edge
  int tier = 0; size_t p = 739;
  if (off + 116ULL*(size_t)E + 16 + 256ULL*624 <= wsF){ tier = 2; p = 624; }
  else if (off + 67ULL*(size_t)E + 16 + 256ULL*672 <= wsF){ tier = 1; p = 672; }

  ushortT *rhid_a = nullptr, *remb_a = nullptr;
  float *edb_a = nullptr, *rb_a = nullptr;
  if (tier >= 1){
    rhid_a = allocU((size_t)E*128);
    edb_a  = alloc((size_t)3*E);
  }
  if (tier == 2){
    remb_a = allocU((size_t)E*96);
    rb_a   = alloc((size_t)E);
  }
  size_t availF = (wsF > off) ? (wsF - off) : 0;
  if (availF < 256*p){
    k_sentinel<<<1, 64, 0, stream>>>((__hip_bfloat16*)d_out, out_size,
                                     (float)(double)(ws_size >> 20));
    return;
  }
  size_t Cs = availF / p; if (Cs > (size_t)E) Cs = E;
  int C = (int)(Cs & ~(size_t)15);
  if (C < 256) C = 256;

  float* scratch0 = (float*)d_ws + off;
  ushortT* remb_l = nullptr;
  if (tier <= 1) remb_l = allocU((size_t)C*96);     // 48C
  float* edb_l = nullptr; ushortT* rhid_l = nullptr;
  if (tier == 0){
    edb_l  = alloc((size_t)3*C);
    rhid_l = allocU((size_t)C*128);
  }
  ushortT* ew_b = allocU((size_t)C*480);      // 240C ; Rmb overlays; geom dumps overlay
  ushortT* R2b  = allocU((size_t)C*384);      // 192C ; R2rl overlays
  ushortT* R1b  = allocU((size_t)C*384);      // 192C
  ushortT* Rmb  = ew_b;
  float* ecv_d  = (float*)ew_b;               // chunked geom dump (6C)
  float* rb_d   = (float*)ew_b + (size_t)6*C; // chunked geom rowscale (C)
  ushortT* R2rl = R2b;
  float* vpc = scratch0;
  size_t scratchF = (size_t)C*p;

  auto mg = [&](const ushortT* A, const ushortT* BT, const float* bias,
                float* Cf, ushortT* Cb, int M, int Nc, int K, int epi,
                const float* rowscale = nullptr, const ushortT* mul1b = nullptr,
                const ushortT* xhpb = nullptr, const int* jidx = nullptr,
                int skipTile = -1){
    dim3 grid(Nc/128 - (skipTile >= 0 ? 1 : 0), (M + 127)/128);
    mgemm<<<grid, 256, 0, stream>>>(A, BT, bias, Cf, Cb, M, Nc, K, epi,
                                    rowscale, mul1b, xhpb, jidx, skipTile);
  };

  // 0) zero header, detect dtypes, int-normalize (+deg histogram)
  k_zero<<<64, 256, 0, stream>>>((float*)flags, (int)zeroHdr);
  k_detect<<<64, 256, 0, stream>>>((const ushortT*)d_in[0], in_sizes[0],
                                   (const int*)d_in[2], in_sizes[2], flags);
  k_iconv<<<1024, 256, 0, stream>>>((const int*)d_in[1], (const int*)d_in[2],
                                    (const int*)d_in[3], zi, bi, eii, N, E, flags, deg);

  // 1) float conversions + transposed bf16 weights
  ConvArgs ca;
  ca.d[0] = { (const ushortT*)d_in[0], pos, in_sizes[0] };
  for (int t = 0; t < 31; ++t)
    ca.d[1+t] = { (const ushortT*)d_in[4+t], w[t], in_sizes[4+t] };
  k_conv<<<dim3(32, 32), 256, 0, stream>>>(ca, 32, flags);

  TArgs ta;
  ta.d[0]  = { (const ushortT*)d_in[4],  wt_rl1, 96, 128 };
  ta.d[1]  = { (const ushortT*)d_in[6],  wt_rl2, 128, 128 };
  ta.d[2]  = { (const ushortT*)d_in[10], wt_sv,  128, 128 };
  ta.d[3]  = { (const ushortT*)d_in[18], wt_xp1, 128, 128 };
  ta.d[4]  = { (const ushortT*)d_in[20], wt_xp2, 128, 384 };
  ta.d[5]  = { (const ushortT*)d_in[22], wt_rp,  96, 384 };
  ta.d[6]  = { (const ushortT*)d_in[24], wt_ip1, 480, 384 };
  ta.d[7]  = { (const ushortT*)d_in[26], wt_ip2, 384, 384 };
  ta.d[8]  = { (const ushortT*)d_in[28], wt_feq, 128, 256 };
  ta.d[9]  = { (const ushortT*)d_in[29], wt_ft1, 256, 128 };
  ta.d[10] = { (const ushortT*)d_in[31], wt_ft2, 128, 384 };
  k_wt<<<dim3(48, 11), 256, 0, stream>>>(ta, 11, flags);

  // 2) CSR scan + scatter
  k_csr_scan<<<1, 256, 0, stream>>>(deg, rowptr, N);
  k_csr_scatter<<<(E + 255)/256, 256, 0, stream>>>(eii, E, rowptr, cursor, jp, ipp);

  // 3) node embedding (+ S/vecacc zero fused)
  k_embed<<<N, 128, 0, stream>>>(zi, ne_w, ne_b, s, h0, S, vecacc);

  // pre-pass + Phase B
  if (tier == 2){
    k_geom<<<(E + 255)/256, 256, 0, stream>>>(pos, jp, ipp, 0, E,
                                              edb_a, nullptr, rb_a, remb_a);
    for (int o = 0; o < E; o += C){
      int Cc = (E - o < C) ? (E - o) : C;
      mg(remb_a + (size_t)o*96, wt_rl1, rl_b1, nullptr, R2rl, Cc, 128, 96, 1);
      mg(R2rl, wt_rl2, rl_b2, nullptr, rhid_a + (size_t)o*128, Cc, 128, 128, 2, rb_a + o);
    }
    k_seg1n<<<N, 128, 0, stream>>>(rowptr, jp, 0, E, h0, rhid_a, s);
  } else if (tier == 1){
    for (int o = 0; o < E; o += C){
      int Cc = (E - o < C) ? (E - o) : C;
      k_geom<<<(Cc + 255)/256, 256, 0, stream>>>(pos, jp, ipp, o, Cc,
                                                 edb_a + (size_t)3*o, ecv_d, rb_d, remb_l);
      mg(remb_l, wt_rl1, rl_b1, nullptr, R2rl, Cc, 128, 96, 1);
      mg(R2rl, wt_rl2, rl_b2, nullptr, rhid_a + (size_t)o*128, Cc, 128, 128, 2, rb_d);
    }
    k_seg1n<<<N, 128, 0, stream>>>(rowptr, jp, 0, E, h0, rhid_a, s);
  } else {
    for (int o = 0; o < E; o += C){
      int Cc = (E - o < C) ? (E - o) : C;
      k_geom<<<(Cc + 255)/256, 256, 0, stream>>>(pos, jp, ipp, o, Cc,
                                                 edb_l, ecv_d, rb_d, remb_l);
      mg(remb_l, wt_rl1, rl_b1, nullptr, R2rl, Cc, 128, 96, 1);
      mg(R2rl, wt_rl2, rl_b2, nullptr, rhid_l, Cc, 128, 128, 2, rb_d);
      k_seg1n<<<N, 128, 0, stream>>>(rowptr, jp, o, Cc, h0, rhid_l, s);
    }
  }

  // Phase C: slin, xln(+sb), xh (xh cols 128-255 dead -> skip tile 1)
  k_ln<<<N, 128, 0, stream>>>(s, xln_b, mp_w, mp_b, sb);
  mg(sb, wt_sv, sv_b, nullptr, slin_b, N, 128, 128, 1);
  mg(xln_b, wt_xp1, xp_b1, nullptr, hb, N, 128, 128, 1);
  mg(hb, wt_xp2, xp_b2, nullptr, xh_b, N, 384, 128, 0, nullptr, nullptr, nullptr, nullptr, 1);

  // Phase D: seg2
  if (tier >= 1){
    k_seg2n<<<N, 128, 0, stream>>>(rowptr, jp, 0, E, slin_b, rhid_a, edb_a, S);
  } else {
    for (int o = 0; o < E; o += C){
      int Cc = (E - o < C) ? (E - o) : C;
      k_geom<<<(Cc + 255)/256, 256, 0, stream>>>(pos, jp, ipp, o, Cc,
                                                 edb_l, ecv_d, rb_d, remb_l);
      mg(remb_l, wt_rl1, rl_b1, nullptr, R2rl, Cc, 128, 96, 1);
      mg(R2rl, wt_rl2, rl_b2, nullptr, rhid_l, Cc, 128, 128, 2, rb_d);
      k_seg2n<<<N, 128, 0, stream>>>(rowptr, jp, o, Cc, slin_b, rhid_l, edb_l, S);
    }
  }

  // Phase E: per-edge big MLPs + seg3 (rp/ip2 skip dead middle tile)
  for (int o = 0; o < E; o += C){
    int Cc = (E - o < C) ? (E - o) : C;
    const ushortT* rhid_p; const float* edb_p;
    const ushortT* remb_p; const ushortT* remb_srcp;
    if (tier == 2){
      rhid_p = rhid_a + (size_t)o*128;
      edb_p  = edb_a + (size_t)3*o;
      remb_p = remb_a + (size_t)o*96;
      remb_srcp = remb_p;
    } else if (tier == 1){
      rhid_p = rhid_a + (size_t)o*128;
      edb_p  = edb_a + (size_t)3*o;
      remb_p = remb_l;
      remb_srcp = nullptr;
    } else {
      k_geom<<<(Cc + 255)/256, 256, 0, stream>>>(pos, jp, ipp, o, Cc,
                                                 edb_l, ecv_d, rb_d, remb_l);
      mg(remb_l, wt_rl1, rl_b1, nullptr, R2rl, Cc, 128, 96, 1);
      mg(R2rl, wt_rl2, rl_b2, nullptr, rhid_l, Cc, 128, 128, 2, rb_d);
      rhid_p = rhid_l; edb_p = edb_l; remb_p = remb_l; remb_srcp = nullptr;
    }
    k_scal2<<<Cc, 256, 0, stream>>>(jp, ipp, o, pos, S, rhid_p,
                                    l3_w1, l3_b1, l3_w2, l3_b2, ew_b,
                                    remb_l, remb_srcp);
    mg(remb_p, wt_rp, rp_b, nullptr, R1b, Cc, 384, 96, 0,
       nullptr, nullptr, nullptr, nullptr, 1);
    mg(ew_b, wt_ip1, ip_b1, nullptr, R2b, Cc, 384, 480, 1);
    mg(R2b, wt_ip2, ip_b2, nullptr, Rmb, Cc, 384, 384, 3,
       nullptr, R1b, xh_b, jp + o, 1);
    k_seg3n<<<N, 128, 0, stream>>>(rowptr, o, Cc, Rmb, edb_p, s, vecacc);
  }

  // Phase F: fte
  k_f2b<<<1024, 256, 0, stream>>>(vecacc, vab, N*384);
  int Cn = (int)(scratchF / 768);
  if (Cn > N) Cn = N;
  for (int no = 0; no < N; no += Cn){
    int Cc = (N - no < Cn) ? (N - no) : Cn;
    mg(vab + (size_t)no*384, wt_feq, nullptr, vpc, nullptr, 3*Cc, 256, 128, 0);
    k_fte_pre<<<Cc, 128, 0, stream>>>(vpc, s, catb, vdot, no);
  }
  mg(catb, wt_ft1, fte_b1, nullptr, hb, N, 128, 256, 1);
  mg(hb, wt_ft2, fte_b2, xh2, nullptr, N, 384, 128, 0);

  // Phase G
  k_out<<<N, 128, 0, stream>>>(xh2, vdot, s, out_w, out_b, nodeout);
  k_final<<<out_size, 256, 0, stream>>>(nodeout, bi, d_out, N, flags);
}

// Round 10
// 1926.182 us; speedup vs baseline: 4.0799x; 1.0509x over previous
//
#include <hip/hip_runtime.h>
#include <hip/hip_bf16.h>
#include <math.h>

#define NRAD 96
#define HIDDIM 128
typedef unsigned short ushortT;

typedef __attribute__((ext_vector_type(8))) short bf8_t;   // 8 bf16 (4 VGPRs)
typedef __attribute__((ext_vector_type(4))) float f4_t;    // 4 fp32 acc
typedef __attribute__((ext_vector_type(2))) float f2_t;    // packed fp32 pair

#if defined(__has_builtin)
#  if __has_builtin(__builtin_amdgcn_global_load_lds)
#    define HAVE_GLDS 1
#  endif
#  if __has_builtin(__builtin_amdgcn_rcpf)
#    define RCPF(x) __builtin_amdgcn_rcpf(x)
#  endif
#  if __has_builtin(__builtin_amdgcn_exp2f)
#    define EXP2F(x) __builtin_amdgcn_exp2f(x)
#  endif
#  if __has_builtin(__builtin_amdgcn_cosf)
#    define COSR(x) __builtin_amdgcn_cosf(x)   /* cos(2*pi*x) */
#  endif
#endif
#ifndef RCPF
#  define RCPF(x) (1.f/(x))
#endif
#ifndef EXP2F
#  define EXP2F(x) exp2f(x)
#endif
#ifndef COSR
#  define COSR(x) cosf(6.2831853071795864f*(x))
#endif
#define LOG2E 1.44269504088896f
#define LN2   0.69314718055995f

__device__ __forceinline__ float silu_f(float x){
  return x * RCPF(1.f + EXP2F(-LOG2E*x));
}
__device__ __forceinline__ float b2f(ushortT u){ return __uint_as_float(((unsigned int)u) << 16); }
__device__ __forceinline__ ushortT f2b(float x){
  unsigned int u = __float_as_uint(x);
  unsigned int r = (u + 0x7fffu + ((u >> 16) & 1u)) >> 16;
  return (ushortT)r;
}

#ifdef HAVE_GLDS
__device__ __forceinline__ void glds16(const ushortT* g, ushortT* l){
  __builtin_amdgcn_global_load_lds(
      (const __attribute__((address_space(1))) ushortT*)g,
      (__attribute__((address_space(3))) ushortT*)l, 16, 0, 0);
}
#endif

// ---------------- dtype detection (parallel) ----------------
__global__ void k_detect(const ushortT* posw, int npos,
                         const int* batchw, int nb, int* flags){
  int tot = (npos < 4096 ? npos : 4096);
  int big = tot > nb ? tot : nb;
  int bad = 0, orv = 0;
  for (int t = blockIdx.x*blockDim.x + threadIdx.x; t < big; t += gridDim.x*blockDim.x){
    if (t < tot){
      float x = b2f(posw[t]);
      if (!(fabsf(x) <= 1000.f)) bad = 1;
    }
    if (t < nb && (t & 1)) orv |= batchw[t];
  }
  if (bad) atomicOr(&flags[2], 1);
  if (orv) atomicOr(&flags[3], 1);
}

__global__ void k_iconv(const int* zsrc, const int* bsrc, const int* esrc,
                        int* zi, int* bi, int* eii, int Nn, int E, const int* flags,
                        int* deg){
  int f = (flags[3] == 0) ? 1 : 0;   // 1 => int64
  int total = 2*Nn + 2*E;
  for (int t = blockIdx.x*blockDim.x + threadIdx.x; t < total; t += gridDim.x*blockDim.x){
    if (t < Nn) zi[t] = zsrc[(size_t)t << f];
    else if (t < 2*Nn) bi[t-Nn] = bsrc[(size_t)(t-Nn) << f];
    else {
      int e = t - 2*Nn;
      int v = esrc[(size_t)e << f];
      eii[e] = v;
      if (e >= E) atomicAdd(&deg[v], 1);
    }
  }
}

// ---------------- conversion: (bf16|f32) -> f32 ----------------
struct ConvDesc { const ushortT* src; float* dst; int n; };
struct ConvArgs { ConvDesc d[32]; };

__global__ void k_conv(ConvArgs a, int cnt, const int* flags){
  int y = blockIdx.y;
  if (y >= cnt) return;
  int f = (flags[2] == 0) ? 1 : 0;    // 1 => bf16
  const ushortT* s = a.d[y].src;
  float* dst = a.d[y].dst;
  int n = a.d[y].n;
  if (f){
    for (int t = blockIdx.x*blockDim.x + threadIdx.x; t < n; t += gridDim.x*blockDim.x)
      dst[t] = b2f(s[t]);
  } else {
    const float* sf = (const float*)s;
    for (int t = blockIdx.x*blockDim.x + threadIdx.x; t < n; t += gridDim.x*blockDim.x)
      dst[t] = sf[t];
  }
}

// ---------------- weight transpose -> bf16 [N][K] ----------------
struct TDesc { const ushortT* src; ushortT* dst; int K, N; };
struct TArgs { TDesc d[12]; };

__global__ void k_wt(TArgs a, int cnt, const int* flags){
  int y = blockIdx.y;
  if (y >= cnt) return;
  int f = (flags[2] == 0) ? 1 : 0;
  const ushortT* s = a.d[y].src;
  ushortT* dst = a.d[y].dst;
  int K = a.d[y].K, N = a.d[y].N, tot = K*N;
  for (int t = blockIdx.x*blockDim.x + threadIdx.x; t < tot; t += gridDim.x*blockDim.x){
    int k = t / N, n = t - k*N;
    ushortT v = f ? s[t] : f2b(((const float*)s)[t]);
    dst[(size_t)n*K + k] = v;
  }
}

__global__ void k_f2b(const float* __restrict__ src, ushortT* __restrict__ dst, int n){
  for (int t = blockIdx.x*blockDim.x + threadIdx.x; t < n; t += gridDim.x*blockDim.x)
    dst[t] = f2b(src[t]);
}

__global__ void k_zero(float* __restrict__ p, int n){
  int t = blockIdx.x*blockDim.x + threadIdx.x;
  int stride = gridDim.x*blockDim.x;
  for (; t < n; t += stride) p[t] = 0.f;
}

__global__ void k_sentinel(__hip_bfloat16* out, int n, float val){
  int t = threadIdx.x;
  if (t < n) out[t] = __float2bfloat16(val);
}

// ---------------- CSR scan + scatter ----------------
__global__ void k_csr_scan(const int* __restrict__ deg, int* __restrict__ rowptr, int Nn){
  __shared__ int sh[256];
  __shared__ int carry;
  if (threadIdx.x == 0){ carry = 0; rowptr[0] = 0; }
  __syncthreads();
  for (int t0 = 0; t0 < Nn; t0 += 256){
    int idx = t0 + threadIdx.x;
    int v = (idx < Nn) ? deg[idx] : 0;
    sh[threadIdx.x] = v; __syncthreads();
    for (int o = 1; o < 256; o <<= 1){
      int u = (threadIdx.x >= o) ? sh[threadIdx.x - o] : 0;
      __syncthreads();
      sh[threadIdx.x] += u; __syncthreads();
    }
    if (idx < Nn) rowptr[idx + 1] = carry + sh[threadIdx.x];
    __syncthreads();
    if (threadIdx.x == 0) carry += sh[255];
    __syncthreads();
  }
}

__global__ void k_csr_scatter(const int* __restrict__ eii, int E,
                              const int* __restrict__ rowptr, int* __restrict__ cursor,
                              int* __restrict__ jp, int* __restrict__ ip){
  int e = blockIdx.x*blockDim.x + threadIdx.x;
  if (e >= E) return;
  int i = eii[E+e];
  int p = atomicAdd(&cursor[i], 1);
  int k = rowptr[i] + p;
  jp[k] = eii[e];
  ip[k] = i;
}

// ---------------- geometry + RBF ----------------
__global__ void k_geom(const float* __restrict__ pos,
                       const int* __restrict__ jp, const int* __restrict__ ip,
                       int off, int Cc,
                       float* __restrict__ edb, float* __restrict__ ecv,
                       float* __restrict__ rb, ushortT* __restrict__ remb)
{
  int el = blockIdx.x*blockDim.x + threadIdx.x;
  if (el >= Cc) return;
  int g = off + el;
  int j = jp[g], i = ip[g];
  float pjx = pos[3*j], pjy = pos[3*j+1], pjz = pos[3*j+2];
  float pix = pos[3*i], piy = pos[3*i+1], piz = pos[3*i+2];
  float vx = pjx-pix, vy = pjy-piy, vz = pjz-piz;
  float d = sqrtf(vx*vx + vy*vy + vz*vz);
  float inv = RCPF(d + 1e-10f);
  float edx = vx*inv, edy = vy*inv, edz = vz*inv;
  edb[3*el]=edx; edb[3*el+1]=edy; edb[3*el+2]=edz;
  if (ecv){
    float cx = piy*pjz - piz*pjy;
    float cy = piz*pjx - pix*pjz;
    float cz = pix*pjy - piy*pjx;
    float cn = sqrtf(cx*cx + cy*cy + cz*cz);
    float inv2 = RCPF(cn + 1e-10f);
    cx *= inv2; cy *= inv2; cz *= inv2;
    ecv[6*el]=cx; ecv[6*el+1]=cy; ecv[6*el+2]=cz;
    ecv[6*el+3]=edy*cz - edz*cy;
    ecv[6*el+4]=edz*cx - edx*cz;
    ecv[6*el+5]=edx*cy - edy*cx;
  }
  float rbv = 0.5f*(COSR(d*0.08333333333f) + 1.f);   // cos(d*pi/6)
  rb[el] = rbv;
  float env = (d < 6.f) ? rbv : 0.f;
  const float stf = 0.0024787522f;
  const float prf = (2.0f/96.0f)*(1.0f - stf);
  const float betaL = LOG2E/(prf*prf);
  float emd = EXP2F(-LOG2E*d);
  for (int k = 0; k < NRAD; ++k){
    float mu = stf + (1.0f - stf)*((float)k*(1.0f/95.0f));
    float t = emd - mu;
    remb[(size_t)el*NRAD + k] = f2b(env * EXP2F(-betaL*t*t));
  }
}

// ---------------- node embedding + layernorm (+ fused accumulator zeroing) ----------------
__global__ __launch_bounds__(128) void k_embed(const int* __restrict__ z,
    const float* __restrict__ ne_w, const float* __restrict__ ne_b,
    float* __restrict__ s, float* __restrict__ h0,
    float* __restrict__ S, float* __restrict__ vecacc)
{
  int n = blockIdx.x; int h = threadIdx.x;
  float x = ne_w[(size_t)z[n]*HIDDIM + h] + ne_b[h];
  __shared__ float red[128];
  red[h] = x; __syncthreads();
  for (int o = 64; o > 0; o >>= 1){ if (h < o) red[h] += red[h+o]; __syncthreads(); }
  float mean = red[0] * (1.f/128.f);
  __syncthreads();
  float dx = x - mean;
  red[h] = dx*dx; __syncthreads();
  for (int o = 64; o > 0; o >>= 1){ if (h < o) red[h] += red[h+o]; __syncthreads(); }
  float var = red[0] * (1.f/128.f);
  float y = dx * rsqrtf(var + 1e-5f);
  s[(size_t)n*HIDDIM + h] = y;
  h0[(size_t)n*HIDDIM + h] = y;
  float* Sr = &S[(size_t)n*384 + h];
  float* Vr = &vecacc[(size_t)n*384 + h];
  Sr[0]=0.f; Sr[128]=0.f; Sr[256]=0.f;
  Vr[0]=0.f; Vr[128]=0.f; Vr[256]=0.f;
}

// LN -> xln_b, plus fused s -> sb conversion
__global__ __launch_bounds__(128) void k_ln(const float* __restrict__ src, ushortT* __restrict__ dst,
    const float* __restrict__ g, const float* __restrict__ b, ushortT* __restrict__ sb)
{
  int n = blockIdx.x; int h = threadIdx.x;
  float x = src[(size_t)n*HIDDIM + h];
  sb[(size_t)n*HIDDIM + h] = f2b(x);
  __shared__ float red[128];
  red[h] = x; __syncthreads();
  for (int o = 64; o > 0; o >>= 1){ if (h < o) red[h] += red[h+o]; __syncthreads(); }
  float mean = red[0] * (1.f/128.f);
  __syncthreads();
  float dx = x - mean;
  red[h] = dx*dx; __syncthreads();
  for (int o = 64; o > 0; o >>= 1){ if (h < o) red[h] += red[h+o]; __syncthreads(); }
  float var = red[0] * (1.f/128.f);
  float y = dx * rsqrtf(var + 1e-5f);
  dst[(size_t)n*HIDDIM + h] = f2b(y * g[h] + b[h]);
}

// ---------------- rowptr-based segment sums (one block per node) ----------------
__global__ __launch_bounds__(128) void k_seg1n(const int* __restrict__ rowptr,
    const int* __restrict__ jp, int o, int Cc,
    const float* __restrict__ h0, const ushortT* __restrict__ rhid,
    float* __restrict__ s)
{
  int i = blockIdx.x, h = threadIdx.x;
  int b = rowptr[i], e = rowptr[i+1];
  if (b < o) b = o;
  int hi = o + Cc; if (e > hi) e = hi;
  if (b >= e) return;
  float acc = 0.f;
  int m = b;
  for (; m + 1 < e; m += 2){
    int j0 = jp[m], j1 = jp[m+1];
    float r0 = b2f(rhid[(size_t)(m-o)*HIDDIM + h]);
    float r1 = b2f(rhid[(size_t)(m+1-o)*HIDDIM + h]);
    acc += h0[(size_t)j0*HIDDIM + h]*r0 + h0[(size_t)j1*HIDDIM + h]*r1;
  }
  if (m < e) acc += h0[(size_t)jp[m]*HIDDIM + h] * b2f(rhid[(size_t)(m-o)*HIDDIM + h]);
  s[(size_t)i*HIDDIM + h] += acc;
}

__global__ __launch_bounds__(128) void k_seg2n(const int* __restrict__ rowptr,
    const int* __restrict__ jp, int o, int Cc,
    const ushortT* __restrict__ slin, const ushortT* __restrict__ rhid,
    const float* __restrict__ edb, float* __restrict__ S)
{
  int i = blockIdx.x, h = threadIdx.x;
  int b = rowptr[i], e = rowptr[i+1];
  if (b < o) b = o;
  int hi = o + Cc; if (e > hi) e = hi;
  if (b >= e) return;
  float a0 = 0.f, a1 = 0.f, a2 = 0.f;
  int m = b;
  for (; m + 1 < e; m += 2){
    int ml = m - o, ml2 = ml + 1;
    float u0 = b2f(slin[(size_t)jp[m]*HIDDIM + h])   * b2f(rhid[(size_t)ml*HIDDIM + h]);
    float u1 = b2f(slin[(size_t)jp[m+1]*HIDDIM + h]) * b2f(rhid[(size_t)ml2*HIDDIM + h]);
    a0 += u0*edb[3*ml]   + u1*edb[3*ml2];
    a1 += u0*edb[3*ml+1] + u1*edb[3*ml2+1];
    a2 += u0*edb[3*ml+2] + u1*edb[3*ml2+2];
  }
  if (m < e){
    int ml = m - o;
    float u0 = b2f(slin[(size_t)jp[m]*HIDDIM + h]) * b2f(rhid[(size_t)ml*HIDDIM + h]);
    a0 += u0*edb[3*ml]; a1 += u0*edb[3*ml+1]; a2 += u0*edb[3*ml+2];
  }
  float* base = &S[(size_t)i*384 + h];
  base[0]   += a0;
  base[128] += a1;
  base[256] += a2;
}

__global__ __launch_bounds__(128) void k_seg3n(const int* __restrict__ rowptr,
    int o, int Cc,
    const ushortT* __restrict__ mb, const float* __restrict__ edb,
    float* __restrict__ s, float* __restrict__ vecacc)
{
  int i = blockIdx.x, h = threadIdx.x;
  int b = rowptr[i], e = rowptr[i+1];
  if (b < o) b = o;
  int hi = o + Cc; if (e > hi) e = hi;
  if (b >= e) return;
  const float is128 = 0.08838834764831845f;
  float am = 0.f, v0 = 0.f, v1 = 0.f, v2 = 0.f;
  int m = b;
  for (; m + 1 < e; m += 2){
    int ml = m - o, ml2 = ml + 1;
    float m1a = b2f(mb[(size_t)ml*384 + h]);
    float m1b = b2f(mb[(size_t)ml2*384 + h]);
    float mma = b2f(mb[(size_t)ml*384 + 256 + h]) * is128;
    float mmb = b2f(mb[(size_t)ml2*384 + 256 + h]) * is128;
    am += m1a + m1b;
    v0 += mma*edb[3*ml]   + mmb*edb[3*ml2];
    v1 += mma*edb[3*ml+1] + mmb*edb[3*ml2+1];
    v2 += mma*edb[3*ml+2] + mmb*edb[3*ml2+2];
  }
  if (m < e){
    int ml = m - o;
    float m1 = b2f(mb[(size_t)ml*384 + h]);
    float mm = b2f(mb[(size_t)ml*384 + 256 + h]) * is128;
    am += m1;
    v0 += mm*edb[3*ml]; v1 += mm*edb[3*ml+1]; v2 += mm*edb[3*ml+2];
  }
  s[(size_t)i*HIDDIM + h] += am;
  float* base = &vecacc[(size_t)i*384 + h];
  base[0]   += v0;
  base[128] += v1;
  base[256] += v2;
}

// ---------------- scalarize v3: 2 edges/block, packed f32 pairs ----------------
// 256 threads: which = t>>7, h = t&127; lanes process edges (ea, eb) as .x/.y
// Frames are precomputed (edb/ecv/rb) -> block-uniform scalar loads.
__global__ __launch_bounds__(256) void k_scal3(
  const int* __restrict__ jp, const int* __restrict__ ip, int off, int Cc,
  const float* __restrict__ S,
  const ushortT* __restrict__ rhid, const float* __restrict__ edb,
  const float* __restrict__ ecv, const float* __restrict__ rb,
  const ushortT* __restrict__ remb,
  const float* __restrict__ w1, const float* __restrict__ b1,
  const float* __restrict__ w2, const float* __restrict__ b2,
  ushortT* __restrict__ ew)
{
  __shared__ float w1s[96], b1s[32], w2s[32];
  __shared__ float sb2;
  int t = threadIdx.x;
  if (t < 96) w1s[t] = w1[t] * (-LOG2E);
  else if (t < 128) b1s[t-96] = b1[t-96] * (-LOG2E);
  else if (t < 160) w2s[t-128] = w2[t-128] * (-LN2);
  else if (t == 160) sb2 = b2[0];
  int ea = blockIdx.x*2;
  int eb = (ea + 1 < Cc) ? ea + 1 : ea;
  int which = t >> 7, h = t & 127;
  int ga = off + ea, gb = off + eb;
  int na = which ? jp[ga] : ip[ga];
  int nb = which ? jp[gb] : ip[gb];
  f2_t f00 = {edb[3*ea],   edb[3*eb]};
  f2_t f01 = {edb[3*ea+1], edb[3*eb+1]};
  f2_t f02 = {edb[3*ea+2], edb[3*eb+2]};
  f2_t f10 = {ecv[6*ea],   ecv[6*eb]};
  f2_t f11 = {ecv[6*ea+1], ecv[6*eb+1]};
  f2_t f12 = {ecv[6*ea+2], ecv[6*eb+2]};
  f2_t f20 = {ecv[6*ea+3], ecv[6*eb+3]};
  f2_t f21 = {ecv[6*ea+4], ecv[6*eb+4]};
  f2_t f22 = {ecv[6*ea+5], ecv[6*eb+5]};
  f2_t rbv = {rb[ea], rb[eb]};
  __syncthreads();
  const float* Sa = &S[(size_t)na*384];
  const float* Sb = &S[(size_t)nb*384];
  f2_t S0 = {Sa[h],     Sb[h]};
  f2_t S1 = {Sa[128+h], Sb[128+h]};
  f2_t S2 = {Sa[256+h], Sb[256+h]};
  f2_t v0 = S0*f00 + S1*f01 + S2*f02;
  f2_t v1t = S0*f10 + S1*f11 + S2*f12;
  f2_t v1 = {fabsf(v1t.x), fabsf(v1t.y)};
  f2_t v2 = S0*f20 + S1*f21 + S2*f22;
  f2_t out = {0.f, 0.f};
  #pragma unroll
  for (int u = 0; u < 32; ++u){
    f2_t tt = v0*w1s[u] + v1*w1s[32+u] + v2*w1s[64+u] + b1s[u];
    f2_t r;
    r.x = RCPF(1.f + EXP2F(tt.x));
    r.y = RCPF(1.f + EXP2F(tt.y));
    out += (tt*r)*w2s[u];
  }
  f2_t res = (out + sb2 + v0) * rbv;
  ushortT* ewa = &ew[(size_t)ea*480];
  ewa[which*128 + h] = f2b(res.x);
  if (eb != ea) ew[(size_t)eb*480 + which*128 + h] = f2b(res.y);
  if (which == 0){
    ewa[256 + h] = rhid[(size_t)ea*HIDDIM + h];
    if (h < NRAD) ewa[384 + h] = remb[(size_t)ea*NRAD + h];
    if (eb != ea){
      ew[(size_t)eb*480 + 256 + h] = rhid[(size_t)eb*HIDDIM + h];
      if (h < NRAD) ew[(size_t)eb*480 + 384 + h] = remb[(size_t)eb*NRAD + h];
    }
  }
}

// ---------------- bf16 MFMA GEMM ----------------
// A: MxK bf16 row-major; BT: NxK bf16 row-major. N%128==0, K%32==0.
// epi: 0 none, 1 silu, 2 *rowscale[row], 3 *mul1b[row,col]*xhpb[jidx[row],col]
// skipTile >= 0: that 128-col tile is not computed (grid.x is one smaller).
__global__ __launch_bounds__(256) void mgemm(
  const ushortT* __restrict__ A, const ushortT* __restrict__ BT,
  const float* __restrict__ bias,
  float* __restrict__ Cf, ushortT* __restrict__ Cb,
  int M, int N, int K, int epi,
  const float* __restrict__ rowscale,
  const ushortT* __restrict__ mul1b,
  const ushortT* __restrict__ xhpb,
  const int* __restrict__ jidx,
  int skipTile)
{
  const int tid = threadIdx.x;
  const int w = tid >> 6;
  const int lane = tid & 63;
  const int l15 = lane & 15;
  const int q = lane >> 4;
  const int wm = w & 1, wn = w >> 1;
  const int rowBase = blockIdx.y * 128;
  int bx = blockIdx.x;
  if (skipTile >= 0 && bx >= skipTile) bx++;
  const int colBase = bx * 128;
  f4_t acc[4][4] = {};

#ifdef HAVE_GLDS
  __shared__ ushortT As[128*32];
  __shared__ ushortT Bs[128*32];
  const int rS = 32*w + (lane >> 2);
  const int kS = (lane & 3) << 3;
  ushortT* lA0 = &As[(32*w)*32];
  ushortT* lA1 = &As[(32*w+16)*32];
  ushortT* lB0 = &Bs[(32*w)*32];
  ushortT* lB1 = &Bs[(32*w+16)*32];
  int ra0 = rowBase + rS;      if (ra0 >= M) ra0 = M-1;
  int ra1 = rowBase + rS + 16; if (ra1 >= M) ra1 = M-1;
  const ushortT* gA0 = A  + (size_t)ra0*K + kS;
  const ushortT* gA1 = A  + (size_t)ra1*K + kS;
  const ushortT* gB0 = BT + (size_t)(colBase + rS)*K + kS;
  const ushortT* gB1 = BT + (size_t)(colBase + rS + 16)*K + kS;
  for (int k0 = 0; k0 < K; k0 += 32){
    glds16(gA0 + k0, lA0);
    glds16(gA1 + k0, lA1);
    glds16(gB0 + k0, lB0);
    glds16(gB1 + k0, lB1);
    __syncthreads();
    bf8_t a[4], b[4];
    #pragma unroll
    for (int mt = 0; mt < 4; ++mt)
      a[mt] = *(const bf8_t*)&As[(wm*64 + mt*16 + l15)*32 + q*8];
    #pragma unroll
    for (int nt = 0; nt < 4; ++nt)
      b[nt] = *(const bf8_t*)&Bs[(wn*64 + nt*16 + l15)*32 + q*8];
    #pragma unroll
    for (int mt = 0; mt < 4; ++mt){
      #pragma unroll
      for (int nt = 0; nt < 4; ++nt)
        acc[mt][nt] = __builtin_amdgcn_mfma_f32_16x16x32_bf16(a[mt], b[nt], acc[mt][nt], 0, 0, 0);
    }
    __syncthreads();
  }
#else
  __shared__ ushortT As[128*48];
  __shared__ ushortT Bs[128*48];
  const int r0 = tid >> 2,         s0 = (tid & 3) << 3;
  const int r1 = (tid + 256) >> 2, s1 = ((tid + 256) & 3) << 3;
  for (int k0 = 0; k0 < K; k0 += 32){
    int4 a0v = make_int4(0,0,0,0), a1v = make_int4(0,0,0,0);
    if (rowBase + r0 < M) a0v = *(const int4*)&A[(size_t)(rowBase + r0)*K + k0 + s0];
    if (rowBase + r1 < M) a1v = *(const int4*)&A[(size_t)(rowBase + r1)*K + k0 + s1];
    int4 b0v = *(const int4*)&BT[(size_t)(colBase + r0)*K + k0 + s0];
    int4 b1v = *(const int4*)&BT[(size_t)(colBase + r1)*K + k0 + s1];
    __syncthreads();
    *(int4*)&As[r0*48 + s0] = a0v;
    *(int4*)&As[r1*48 + s1] = a1v;
    *(int4*)&Bs[r0*48 + s0] = b0v;
    *(int4*)&Bs[r1*48 + s1] = b1v;
    __syncthreads();
    bf8_t a[4], b[4];
    #pragma unroll
    for (int mt = 0; mt < 4; ++mt)
      a[mt] = *(const bf8_t*)&As[(wm*64 + mt*16 + l15)*48 + q*8];
    #pragma unroll
    for (int nt = 0; nt < 4; ++nt)
      b[nt] = *(const bf8_t*)&Bs[(wn*64 + nt*16 + l15)*48 + q*8];
    #pragma unroll
    for (int mt = 0; mt < 4; ++mt){
      #pragma unroll
      for (int nt = 0; nt < 4; ++nt)
        acc[mt][nt] = __builtin_amdgcn_mfma_f32_16x16x32_bf16(a[mt], b[nt], acc[mt][nt], 0, 0, 0);
    }
  }
#endif

  #pragma unroll
  for (int mt = 0; mt < 4; ++mt){
    int row = rowBase + wm*64 + mt*16 + q*4;
    #pragma unroll
    for (int nt = 0; nt < 4; ++nt){
      int col = colBase + wn*64 + nt*16 + l15;
      float bv = bias ? bias[col] : 0.f;
      #pragma unroll
      for (int r = 0; r < 4; ++r){
        int rr = row + r;
        if (rr >= M) continue;
        float x = acc[mt][nt][r] + bv;
        if (epi == 1) x = silu_f(x);
        else if (epi == 2) x *= rowscale[rr];
        else if (epi == 3) x = x * b2f(mul1b[(size_t)rr*N + col]) * b2f(xhpb[(size_t)jidx[rr]*N + col]);
        if (Cb) Cb[(size_t)rr*N + col] = f2b(x);
        else    Cf[(size_t)rr*N + col] = x;
      }
    }
  }
}

// ---------------- fte prep ----------------
__global__ __launch_bounds__(128) void k_fte_pre(const float* __restrict__ vpc,
    const float* __restrict__ s, ushortT* __restrict__ catb, float* __restrict__ vdot,
    int no)
{
  int nl = blockIdx.x, h = threadIdx.x;
  int n = no + nl;
  const float* base = &vpc[(size_t)nl*768];
  float a0 = base[h],       a1 = base[256+h],     a2 = base[512+h];
  float c0 = base[128+h],   c1 = base[384+h],     c2 = base[640+h];
  float scal = sqrtf(a0*a0 + a1*a1 + a2*a2 + 1e-10f);
  float vd = (a0*c0 + a1*c1 + a2*c2) * 0.08838834764831845f;
  catb[(size_t)n*256 + h] = f2b(s[(size_t)n*HIDDIM + h]);
  catb[(size_t)n*256 + 128 + h] = f2b(scal);
  vdot[(size_t)n*HIDDIM + h] = vd;
}

// ---------------- final ----------------
__global__ __launch_bounds__(128) void k_out(const float* __restrict__ xh2,
    const float* __restrict__ vdot, const float* __restrict__ s,
    const float* __restrict__ ow, const float* __restrict__ ob,
    float* __restrict__ nodeout)
{
  int n = blockIdx.x, h = threadIdx.x;
  float a1 = xh2[(size_t)n*384 + h];
  float a2 = xh2[(size_t)n*384 + 128 + h];
  float sv = s[(size_t)n*HIDDIM + h] + (a1 + a2*vdot[(size_t)n*HIDDIM + h]) * 0.7071067811865476f;
  __shared__ float red[128];
  red[h] = sv * ow[h];
  __syncthreads();
  for (int o = 64; o > 0; o >>= 1){ if (h < o) red[h] += red[h+o]; __syncthreads(); }
  if (h == 0) nodeout[n] = red[0] + ob[0];
}

__global__ __launch_bounds__(256) void k_final(const float* __restrict__ nodeout,
    const int* __restrict__ batch, void* __restrict__ out, int Nn, const int* flags)
{
  int g = blockIdx.x;
  __shared__ float rs[256], rc[256];
  float sm = 0.f, c = 0.f;
  for (int n = threadIdx.x; n < Nn; n += 256){
    if (batch[n] == g){ sm += nodeout[n]; c += 1.f; }
  }
  rs[threadIdx.x] = sm; rc[threadIdx.x] = c;
  __syncthreads();
  for (int o = 128; o > 0; o >>= 1){
    if (threadIdx.x < o){ rs[threadIdx.x] += rs[threadIdx.x+o]; rc[threadIdx.x] += rc[threadIdx.x+o]; }
    __syncthreads();
  }
  if (threadIdx.x == 0){
    float v = (rc[0] > 0.f) ? rs[0]/rc[0] : 0.f;
    if (flags[2] == 0) ((__hip_bfloat16*)out)[g] = __float2bfloat16(v);
    else ((float*)out)[g] = v;
  }
}

// =====================================================================
extern "C" void kernel_launch(void* const* d_in, const int* in_sizes, int n_in,
                              void* d_out, int out_size, void* d_ws, size_t ws_size,
                              hipStream_t stream)
{
  const int N = in_sizes[0] / 3;
  const int E = in_sizes[3] / 2;

  size_t off = 0;
  auto alloc = [&](size_t n)->float*{
    float* p = (float*)d_ws + off;
    off += (n + 3) & ~(size_t)3;
    return p;
  };
  auto allocU = [&](size_t n)->ushortT*{ return (ushortT*)alloc((n + 1) / 2); };

  int* flags  = (int*)alloc(4);
  int* deg    = (int*)alloc((size_t)N);
  int* cursor = (int*)alloc((size_t)N);
  size_t zeroHdr = off;
  int* zi     = (int*)alloc((size_t)N);
  int* bi     = (int*)alloc((size_t)N);
  int* eii    = (int*)alloc((size_t)2*E);
  int* rowptr = (int*)alloc((size_t)N + 4);
  int* jp     = (int*)alloc((size_t)E);
  int* ipp    = (int*)alloc((size_t)E);

  float* pos = alloc((size_t)N*3);
  float* w[31];
  for (int t = 0; t < 31; ++t) w[t] = alloc((size_t)in_sizes[4+t]);
  float* rl_b1=w[1];  float* rl_b2=w[3];
  float* ne_w =w[4];  float* ne_b =w[5];  float* sv_b =w[7];
  float* l3_w1=w[8];  float* l3_b1=w[9];  float* l3_w2=w[10]; float* l3_b2=w[11];
  float* mp_w =w[12]; float* mp_b =w[13]; float* xp_b1=w[15];
  float* xp_b2=w[17]; float* rp_b =w[19];
  float* ip_b1=w[21]; float* ip_b2=w[23];
  float* fte_b1=w[26];float* fte_b2=w[28];float* out_w=w[29]; float* out_b=w[30];

  ushortT* wt_rl1 = allocU(96*128);
  ushortT* wt_rl2 = allocU(128*128);
  ushortT* wt_sv  = allocU(128*128);
  ushortT* wt_xp1 = allocU(128*128);
  ushortT* wt_xp2 = allocU((size_t)128*384);
  ushortT* wt_rp  = allocU((size_t)96*384);
  ushortT* wt_ip1 = allocU((size_t)480*384);
  ushortT* wt_ip2 = allocU((size_t)384*384);
  ushortT* wt_feq = allocU((size_t)128*256);
  ushortT* wt_ft1 = allocU((size_t)256*128);
  ushortT* wt_ft2 = allocU((size_t)128*384);

  float* s    = alloc((size_t)N*HIDDIM);
  float* h0   = alloc((size_t)N*HIDDIM);      // -> vdot overlay after seg1
  ushortT* sb     = allocU((size_t)N*HIDDIM); // sb+slin_b contiguous -> catb overlay
  ushortT* slin_b = allocU((size_t)N*HIDDIM);
  ushortT* xln_b  = allocU((size_t)N*HIDDIM);
  ushortT* hb     = allocU((size_t)N*HIDDIM);
  float* S    = alloc((size_t)N*384);         // -> vab overlay in phase F
  float* vecacc = alloc((size_t)N*384);       // -> xh2 overlay after f2b
  ushortT* xh_b = allocU((size_t)N*384);
  float* nodeout = alloc((size_t)N);
  float* vdot = h0;
  ushortT* catb = sb;
  ushortT* vab = (ushortT*)S;
  float* xh2 = vecacc;

  size_t wsF = ws_size / sizeof(float);

  // tier selection:
  //  tier2: persist edb(3)+ecv(6)+rb(1)+remb(48)+rhid(64) = 122 f/edge; chunk 624 f/edge
  //  tier1: persist edb+rhid (67 f/edge);                  chunk 679 f/edge
  //  tier0: nothing persists;                              chunk 746 f/edge
  int tier = 0; size_t p = 746;
  if (off + 122ULL*(size_t)E + 16 + 256ULL*624 <= wsF){ tier = 2; p = 624; }
  else if (off + 67ULL*(size_t)E + 16 + 256ULL*679 <= wsF){ tier = 1; p = 679; }

  ushortT *rhid_a = nullptr, *remb_a = nullptr;
  float *edb_a = nullptr, *ecv_a = nullptr, *rb_a = nullptr;
  if (tier >= 1){
    rhid_a = allocU((size_t)E*128);
    edb_a  = alloc((size_t)3*E);
  }
  if (tier == 2){
    ecv_a  = alloc((size_t)6*E);
    rb_a   = alloc((size_t)E);
    remb_a = allocU((size_t)E*96);
  }
  size_t availF = (wsF > off) ? (wsF - off) : 0;
  if (availF < 256*p){
    k_sentinel<<<1, 64, 0, stream>>>((__hip_bfloat16*)d_out, out_size,
                                     (float)(double)(ws_size >> 20));
    return;
  }
  size_t Cs = availF / p; if (Cs > (size_t)E) Cs = E;
  int C = (int)(Cs & ~(size_t)15);
  if (C < 256) C = 256;

  float* scratch0 = (float*)d_ws + off;
  ushortT* remb_l = nullptr; float *ecv_l = nullptr, *rb_l = nullptr;
  if (tier <= 1){
    remb_l = allocU((size_t)C*96);   // 48C
    ecv_l  = alloc((size_t)6*C);
    rb_l   = alloc((size_t)C);
  }
  float* edb_l = nullptr; ushortT* rhid_l = nullptr;
  if (tier == 0){
    edb_l  = alloc((size_t)3*C);
    rhid_l = allocU((size_t)C*128);
  }
  ushortT* ew_b = allocU((size_t)C*480);      // 240C ; Rmb overlays
  ushortT* R2b  = allocU((size_t)C*384);      // 192C ; R2rl overlays
  ushortT* R1b  = allocU((size_t)C*384);      // 192C
  ushortT* Rmb  = ew_b;
  ushortT* R2rl = R2b;
  float* vpc = scratch0;
  size_t scratchF = (size_t)C*p;

  auto mg = [&](const ushortT* A, const ushortT* BT, const float* bias,
                float* Cf, ushortT* Cb, int M, int Nc, int K, int epi,
                const float* rowscale = nullptr, const ushortT* mul1b = nullptr,
                const ushortT* xhpb = nullptr, const int* jidx = nullptr,
                int skipTile = -1){
    dim3 grid(Nc/128 - (skipTile >= 0 ? 1 : 0), (M + 127)/128);
    mgemm<<<grid, 256, 0, stream>>>(A, BT, bias, Cf, Cb, M, Nc, K, epi,
                                    rowscale, mul1b, xhpb, jidx, skipTile);
  };

  // 0) zero header, detect dtypes, int-normalize (+deg histogram)
  k_zero<<<64, 256, 0, stream>>>((float*)flags, (int)zeroHdr);
  k_detect<<<64, 256, 0, stream>>>((const ushortT*)d_in[0], in_sizes[0],
                                   (const int*)d_in[2], in_sizes[2], flags);
  k_iconv<<<1024, 256, 0, stream>>>((const int*)d_in[1], (const int*)d_in[2],
                                    (const int*)d_in[3], zi, bi, eii, N, E, flags, deg);

  // 1) float conversions + transposed bf16 weights
  ConvArgs ca;
  ca.d[0] = { (const ushortT*)d_in[0], pos, in_sizes[0] };
  for (int t = 0; t < 31; ++t)
    ca.d[1+t] = { (const ushortT*)d_in[4+t], w[t], in_sizes[4+t] };
  k_conv<<<dim3(32, 32), 256, 0, stream>>>(ca, 32, flags);

  TArgs ta;
  ta.d[0]  = { (const ushortT*)d_in[4],  wt_rl1, 96, 128 };
  ta.d[1]  = { (const ushortT*)d_in[6],  wt_rl2, 128, 128 };
  ta.d[2]  = { (const ushortT*)d_in[10], wt_sv,  128, 128 };
  ta.d[3]  = { (const ushortT*)d_in[18], wt_xp1, 128, 128 };
  ta.d[4]  = { (const ushortT*)d_in[20], wt_xp2, 128, 384 };
  ta.d[5]  = { (const ushortT*)d_in[22], wt_rp,  96, 384 };
  ta.d[6]  = { (const ushortT*)d_in[24], wt_ip1, 480, 384 };
  ta.d[7]  = { (const ushortT*)d_in[26], wt_ip2, 384, 384 };
  ta.d[8]  = { (const ushortT*)d_in[28], wt_feq, 128, 256 };
  ta.d[9]  = { (const ushortT*)d_in[29], wt_ft1, 256, 128 };
  ta.d[10] = { (const ushortT*)d_in[31], wt_ft2, 128, 384 };
  k_wt<<<dim3(48, 11), 256, 0, stream>>>(ta, 11, flags);

  // 2) CSR scan + scatter
  k_csr_scan<<<1, 256, 0, stream>>>(deg, rowptr, N);
  k_csr_scatter<<<(E + 255)/256, 256, 0, stream>>>(eii, E, rowptr, cursor, jp, ipp);

  // 3) node embedding (+ S/vecacc zero fused)
  k_embed<<<N, 128, 0, stream>>>(zi, ne_w, ne_b, s, h0, S, vecacc);

  // pre-pass + Phase B
  if (tier == 2){
    k_geom<<<(E + 255)/256, 256, 0, stream>>>(pos, jp, ipp, 0, E,
                                              edb_a, ecv_a, rb_a, remb_a);
    for (int o = 0; o < E; o += C){
      int Cc = (E - o < C) ? (E - o) : C;
      mg(remb_a + (size_t)o*96, wt_rl1, rl_b1, nullptr, R2rl, Cc, 128, 96, 1);
      mg(R2rl, wt_rl2, rl_b2, nullptr, rhid_a + (size_t)o*128, Cc, 128, 128, 2, rb_a + o);
    }
    k_seg1n<<<N, 128, 0, stream>>>(rowptr, jp, 0, E, h0, rhid_a, s);
  } else if (tier == 1){
    for (int o = 0; o < E; o += C){
      int Cc = (E - o < C) ? (E - o) : C;
      k_geom<<<(Cc + 255)/256, 256, 0, stream>>>(pos, jp, ipp, o, Cc,
                                                 edb_a + (size_t)3*o, nullptr, rb_l, remb_l);
      mg(remb_l, wt_rl1, rl_b1, nullptr, R2rl, Cc, 128, 96, 1);
      mg(R2rl, wt_rl2, rl_b2, nullptr, rhid_a + (size_t)o*128, Cc, 128, 128, 2, rb_l);
    }
    k_seg1n<<<N, 128, 0, stream>>>(rowptr, jp, 0, E, h0, rhid_a, s);
  } else {
    for (int o = 0; o < E; o += C){
      int Cc = (E - o < C) ? (E - o) : C;
      k_geom<<<(Cc + 255)/256, 256, 0, stream>>>(pos, jp, ipp, o, Cc,
                                                 edb_l, nullptr, rb_l, remb_l);
      mg(remb_l, wt_rl1, rl_b1, nullptr, R2rl, Cc, 128, 96, 1);
      mg(R2rl, wt_rl2, rl_b2, nullptr, rhid_l, Cc, 128, 128, 2, rb_l);
      k_seg1n<<<N, 128, 0, stream>>>(rowptr, jp, o, Cc, h0, rhid_l, s);
    }
  }

  // Phase C: slin, xln(+sb), xh (xh cols 128-255 dead -> skip tile 1)
  k_ln<<<N, 128, 0, stream>>>(s, xln_b, mp_w, mp_b, sb);
  mg(sb, wt_sv, sv_b, nullptr, slin_b, N, 128, 128, 1);
  mg(xln_b, wt_xp1, xp_b1, nullptr, hb, N, 128, 128, 1);
  mg(hb, wt_xp2, xp_b2, nullptr, xh_b, N, 384, 128, 0, nullptr, nullptr, nullptr, nullptr, 1);

  // Phase D: seg2
  if (tier >= 1){
    k_seg2n<<<N, 128, 0, stream>>>(rowptr, jp, 0, E, slin_b, rhid_a, edb_a, S);
  } else {
    for (int o = 0; o < E; o += C){
      int Cc = (E - o < C) ? (E - o) : C;
      k_geom<<<(Cc + 255)/256, 256, 0, stream>>>(pos, jp, ipp, o, Cc,
                                                 edb_l, nullptr, rb_l, remb_l);
      mg(remb_l, wt_rl1, rl_b1, nullptr, R2rl, Cc, 128, 96, 1);
      mg(R2rl, wt_rl2, rl_b2, nullptr, rhid_l, Cc, 128, 128, 2, rb_l);
      k_seg2n<<<N, 128, 0, stream>>>(rowptr, jp, o, Cc, slin_b, rhid_l, edb_l, S);
    }
  }

  // Phase E: per-edge big MLPs + seg3 (rp/ip2 skip dead middle tile)
  for (int o = 0; o < E; o += C){
    int Cc = (E - o < C) ? (E - o) : C;
    const ushortT *rhid_p, *remb_p;
    const float *edb_p, *ecv_p, *rb_p;
    if (tier == 2){
      rhid_p = rhid_a + (size_t)o*128;
      edb_p  = edb_a + (size_t)3*o;
      ecv_p  = ecv_a + (size_t)6*o;
      rb_p   = rb_a + o;
      remb_p = remb_a + (size_t)o*96;
    } else if (tier == 1){
      k_geom<<<(Cc + 255)/256, 256, 0, stream>>>(pos, jp, ipp, o, Cc,
                                                 edb_a + (size_t)3*o, ecv_l, rb_l, remb_l);
      rhid_p = rhid_a + (size_t)o*128;
      edb_p  = edb_a + (size_t)3*o;
      ecv_p  = ecv_l; rb_p = rb_l; remb_p = remb_l;
    } else {
      k_geom<<<(Cc + 255)/256, 256, 0, stream>>>(pos, jp, ipp, o, Cc,
                                                 edb_l, ecv_l, rb_l, remb_l);
      mg(remb_l, wt_rl1, rl_b1, nullptr, R2rl, Cc, 128, 96, 1);
      mg(R2rl, wt_rl2, rl_b2, nullptr, rhid_l, Cc, 128, 128, 2, rb_l);
      rhid_p = rhid_l; edb_p = edb_l; ecv_p = ecv_l; rb_p = rb_l; remb_p = remb_l;
    }
    k_scal3<<<(Cc + 1)/2, 256, 0, stream>>>(jp, ipp, o, Cc, S, rhid_p,
                                            edb_p, ecv_p, rb_p, remb_p,
                                            l3_w1, l3_b1, l3_w2, l3_b2, ew_b);
    mg(remb_p, wt_rp, rp_b, nullptr, R1b, Cc, 384, 96, 0,
       nullptr, nullptr, nullptr, nullptr, 1);
    mg(ew_b, wt_ip1, ip_b1, nullptr, R2b, Cc, 384, 480, 1);
    mg(R2b, wt_ip2, ip_b2, nullptr, Rmb, Cc, 384, 384, 3,
       nullptr, R1b, xh_b, jp + o, 1);
    k_seg3n<<<N, 128, 0, stream>>>(rowptr, o, Cc, Rmb, edb_p, s, vecacc);
  }

  // Phase F: fte
  k_f2b<<<1024, 256, 0, stream>>>(vecacc, vab, N*384);
  int Cn = (int)(scratchF / 768);
  if (Cn > N) Cn = N;
  for (int no = 0; no < N; no += Cn){
    int Cc = (N - no < Cn) ? (N - no) : Cn;
    mg(vab + (size_t)no*384, wt_feq, nullptr, vpc, nullptr, 3*Cc, 256, 128, 0);
    k_fte_pre<<<Cc, 128, 0, stream>>>(vpc, s, catb, vdot, no);
  }
  mg(catb, wt_ft1, fte_b1, nullptr, hb, N, 128, 256, 1);
  mg(hb, wt_ft2, fte_b2, xh2, nullptr, N, 384, 128, 0);

  // Phase G
  k_out<<<N, 128, 0, stream>>>(xh2, vdot, s, out_w, out_b, nodeout);
  k_final<<<out_size, 256, 0, stream>>>(nodeout, bi, d_out, N, flags);
}

// Round 11
// 1824.894 us; speedup vs baseline: 4.3063x; 1.0555x over previous
//
#include <hip/hip_runtime.h>
#include <hip/hip_bf16.h>
#include <math.h>

#define NRAD 96
#define HIDDIM 128
typedef unsigned short ushortT;

typedef __attribute__((ext_vector_type(8))) short bf8_t;   // 8 bf16 (4 VGPRs)
typedef __attribute__((ext_vector_type(4))) float f4_t;    // 4 fp32 acc
typedef __attribute__((ext_vector_type(2))) float f2_t;    // packed fp32 pair

#if defined(__has_builtin)
#  if __has_builtin(__builtin_amdgcn_global_load_lds)
#    define HAVE_GLDS 1
#  endif
#  if __has_builtin(__builtin_amdgcn_rcpf)
#    define RCPF(x) __builtin_amdgcn_rcpf(x)
#  endif
#  if __has_builtin(__builtin_amdgcn_exp2f)
#    define EXP2F(x) __builtin_amdgcn_exp2f(x)
#  endif
#  if __has_builtin(__builtin_amdgcn_cosf)
#    define COSR(x) __builtin_amdgcn_cosf(x)   /* cos(2*pi*x) */
#  endif
#endif
#ifndef RCPF
#  define RCPF(x) (1.f/(x))
#endif
#ifndef EXP2F
#  define EXP2F(x) exp2f(x)
#endif
#ifndef COSR
#  define COSR(x) cosf(6.2831853071795864f*(x))
#endif
#define LOG2E 1.44269504088896f
#define LN2   0.69314718055995f

__device__ __forceinline__ float silu_f(float x){
  return x * RCPF(1.f + EXP2F(-LOG2E*x));
}
__device__ __forceinline__ float b2f(ushortT u){ return __uint_as_float(((unsigned int)u) << 16); }
__device__ __forceinline__ ushortT f2b(float x){
  unsigned int u = __float_as_uint(x);
  unsigned int r = (u + 0x7fffu + ((u >> 16) & 1u)) >> 16;
  return (ushortT)r;
}

#ifdef HAVE_GLDS
__device__ __forceinline__ void glds16(const ushortT* g, ushortT* l){
  __builtin_amdgcn_global_load_lds(
      (const __attribute__((address_space(1))) ushortT*)g,
      (__attribute__((address_space(3))) ushortT*)l, 16, 0, 0);
}
#endif

// ---------------- dtype detection (parallel) ----------------
__global__ void k_detect(const ushortT* posw, int npos,
                         const int* batchw, int nb, int* flags){
  int tot = (npos < 4096 ? npos : 4096);
  int big = tot > nb ? tot : nb;
  int bad = 0, orv = 0;
  for (int t = blockIdx.x*blockDim.x + threadIdx.x; t < big; t += gridDim.x*blockDim.x){
    if (t < tot){
      float x = b2f(posw[t]);
      if (!(fabsf(x) <= 1000.f)) bad = 1;
    }
    if (t < nb && (t & 1)) orv |= batchw[t];
  }
  if (bad) atomicOr(&flags[2], 1);
  if (orv) atomicOr(&flags[3], 1);
}

__global__ void k_iconv(const int* zsrc, const int* bsrc, const int* esrc,
                        int* zi, int* bi, int* eii, int Nn, int E, const int* flags,
                        int* deg){
  int f = (flags[3] == 0) ? 1 : 0;   // 1 => int64
  int total = 2*Nn + 2*E;
  for (int t = blockIdx.x*blockDim.x + threadIdx.x; t < total; t += gridDim.x*blockDim.x){
    if (t < Nn) zi[t] = zsrc[(size_t)t << f];
    else if (t < 2*Nn) bi[t-Nn] = bsrc[(size_t)(t-Nn) << f];
    else {
      int e = t - 2*Nn;
      int v = esrc[(size_t)e << f];
      eii[e] = v;
      if (e >= E) atomicAdd(&deg[v], 1);
    }
  }
}

// ---------------- conversion: (bf16|f32) -> f32 ----------------
struct ConvDesc { const ushortT* src; float* dst; int n; };
struct ConvArgs { ConvDesc d[32]; };

__global__ void k_conv(ConvArgs a, int cnt, const int* flags){
  int y = blockIdx.y;
  if (y >= cnt) return;
  int f = (flags[2] == 0) ? 1 : 0;    // 1 => bf16
  const ushortT* s = a.d[y].src;
  float* dst = a.d[y].dst;
  int n = a.d[y].n;
  if (f){
    for (int t = blockIdx.x*blockDim.x + threadIdx.x; t < n; t += gridDim.x*blockDim.x)
      dst[t] = b2f(s[t]);
  } else {
    const float* sf = (const float*)s;
    for (int t = blockIdx.x*blockDim.x + threadIdx.x; t < n; t += gridDim.x*blockDim.x)
      dst[t] = sf[t];
  }
}

// prescale l3 weights for scal4: [0,96) w1*-log2e, [96,128) b1*-log2e,
// [128,160) w2*-ln2, [160] b2
__global__ void k_l3pre(const float* __restrict__ w1, const float* __restrict__ b1,
                        const float* __restrict__ w2, const float* __restrict__ b2,
                        float* __restrict__ l3s){
  int t = threadIdx.x;
  if (t < 96) l3s[t] = w1[t] * (-LOG2E);
  else if (t < 128) l3s[t] = b1[t-96] * (-LOG2E);
  else if (t < 160) l3s[t] = w2[t-128] * (-LN2);
  else if (t == 160) l3s[160] = b2[0];
}

// ---------------- weight transpose -> bf16 [N][K] ----------------
struct TDesc { const ushortT* src; ushortT* dst; int K, N; };
struct TArgs { TDesc d[12]; };

__global__ void k_wt(TArgs a, int cnt, const int* flags){
  int y = blockIdx.y;
  if (y >= cnt) return;
  int f = (flags[2] == 0) ? 1 : 0;
  const ushortT* s = a.d[y].src;
  ushortT* dst = a.d[y].dst;
  int K = a.d[y].K, N = a.d[y].N, tot = K*N;
  for (int t = blockIdx.x*blockDim.x + threadIdx.x; t < tot; t += gridDim.x*blockDim.x){
    int k = t / N, n = t - k*N;
    ushortT v = f ? s[t] : f2b(((const float*)s)[t]);
    dst[(size_t)n*K + k] = v;
  }
}

__global__ void k_f2b(const float* __restrict__ src, ushortT* __restrict__ dst, int n){
  for (int t = blockIdx.x*blockDim.x + threadIdx.x; t < n; t += gridDim.x*blockDim.x)
    dst[t] = f2b(src[t]);
}

__global__ void k_zero(float* __restrict__ p, int n){
  int t = blockIdx.x*blockDim.x + threadIdx.x;
  int stride = gridDim.x*blockDim.x;
  for (; t < n; t += stride) p[t] = 0.f;
}

__global__ void k_sentinel(__hip_bfloat16* out, int n, float val){
  int t = threadIdx.x;
  if (t < n) out[t] = __float2bfloat16(val);
}

// ---------------- CSR scan + scatter ----------------
__global__ void k_csr_scan(const int* __restrict__ deg, int* __restrict__ rowptr, int Nn){
  __shared__ int sh[256];
  __shared__ int carry;
  if (threadIdx.x == 0){ carry = 0; rowptr[0] = 0; }
  __syncthreads();
  for (int t0 = 0; t0 < Nn; t0 += 256){
    int idx = t0 + threadIdx.x;
    int v = (idx < Nn) ? deg[idx] : 0;
    sh[threadIdx.x] = v; __syncthreads();
    for (int o = 1; o < 256; o <<= 1){
      int u = (threadIdx.x >= o) ? sh[threadIdx.x - o] : 0;
      __syncthreads();
      sh[threadIdx.x] += u; __syncthreads();
    }
    if (idx < Nn) rowptr[idx + 1] = carry + sh[threadIdx.x];
    __syncthreads();
    if (threadIdx.x == 0) carry += sh[255];
    __syncthreads();
  }
}

__global__ void k_csr_scatter(const int* __restrict__ eii, int E,
                              const int* __restrict__ rowptr, int* __restrict__ cursor,
                              int* __restrict__ jp, int* __restrict__ ip){
  int e = blockIdx.x*blockDim.x + threadIdx.x;
  if (e >= E) return;
  int i = eii[E+e];
  int p = atomicAdd(&cursor[i], 1);
  int k = rowptr[i] + p;
  jp[k] = eii[e];
  ip[k] = i;
}

// ---------------- geometry + RBF ----------------
__global__ void k_geom(const float* __restrict__ pos,
                       const int* __restrict__ jp, const int* __restrict__ ip,
                       int off, int Cc,
                       float* __restrict__ edb, float* __restrict__ ecv,
                       float* __restrict__ rb, ushortT* __restrict__ remb)
{
  int el = blockIdx.x*blockDim.x + threadIdx.x;
  if (el >= Cc) return;
  int g = off + el;
  int j = jp[g], i = ip[g];
  float pjx = pos[3*j], pjy = pos[3*j+1], pjz = pos[3*j+2];
  float pix = pos[3*i], piy = pos[3*i+1], piz = pos[3*i+2];
  float vx = pjx-pix, vy = pjy-piy, vz = pjz-piz;
  float d = sqrtf(vx*vx + vy*vy + vz*vz);
  float inv = RCPF(d + 1e-10f);
  float edx = vx*inv, edy = vy*inv, edz = vz*inv;
  edb[3*el]=edx; edb[3*el+1]=edy; edb[3*el+2]=edz;
  if (ecv){
    float cx = piy*pjz - piz*pjy;
    float cy = piz*pjx - pix*pjz;
    float cz = pix*pjy - piy*pjx;
    float cn = sqrtf(cx*cx + cy*cy + cz*cz);
    float inv2 = RCPF(cn + 1e-10f);
    cx *= inv2; cy *= inv2; cz *= inv2;
    ecv[6*el]=cx; ecv[6*el+1]=cy; ecv[6*el+2]=cz;
    ecv[6*el+3]=edy*cz - edz*cy;
    ecv[6*el+4]=edz*cx - edx*cz;
    ecv[6*el+5]=edx*cy - edy*cx;
  }
  float rbv = 0.5f*(COSR(d*0.08333333333f) + 1.f);   // cos(d*pi/6)
  rb[el] = rbv;
  float env = (d < 6.f) ? rbv : 0.f;
  const float stf = 0.0024787522f;
  const float prf = (2.0f/96.0f)*(1.0f - stf);
  const float betaL = LOG2E/(prf*prf);
  float emd = EXP2F(-LOG2E*d);
  for (int k = 0; k < NRAD; ++k){
    float mu = stf + (1.0f - stf)*((float)k*(1.0f/95.0f));
    float t = emd - mu;
    remb[(size_t)el*NRAD + k] = f2b(env * EXP2F(-betaL*t*t));
  }
}

// ---------------- node embedding + layernorm (+ fused accumulator zeroing) ----------------
__global__ __launch_bounds__(128) void k_embed(const int* __restrict__ z,
    const float* __restrict__ ne_w, const float* __restrict__ ne_b,
    float* __restrict__ s, float* __restrict__ h0,
    float* __restrict__ S, float* __restrict__ vecacc)
{
  int n = blockIdx.x; int h = threadIdx.x;
  float x = ne_w[(size_t)z[n]*HIDDIM + h] + ne_b[h];
  __shared__ float red[128];
  red[h] = x; __syncthreads();
  for (int o = 64; o > 0; o >>= 1){ if (h < o) red[h] += red[h+o]; __syncthreads(); }
  float mean = red[0] * (1.f/128.f);
  __syncthreads();
  float dx = x - mean;
  red[h] = dx*dx; __syncthreads();
  for (int o = 64; o > 0; o >>= 1){ if (h < o) red[h] += red[h+o]; __syncthreads(); }
  float var = red[0] * (1.f/128.f);
  float y = dx * rsqrtf(var + 1e-5f);
  s[(size_t)n*HIDDIM + h] = y;
  h0[(size_t)n*HIDDIM + h] = y;
  float* Sr = &S[(size_t)n*384 + h];
  float* Vr = &vecacc[(size_t)n*384 + h];
  Sr[0]=0.f; Sr[128]=0.f; Sr[256]=0.f;
  Vr[0]=0.f; Vr[128]=0.f; Vr[256]=0.f;
}

// LN -> xln_b, plus fused s -> sb conversion
__global__ __launch_bounds__(128) void k_ln(const float* __restrict__ src, ushortT* __restrict__ dst,
    const float* __restrict__ g, const float* __restrict__ b, ushortT* __restrict__ sb)
{
  int n = blockIdx.x; int h = threadIdx.x;
  float x = src[(size_t)n*HIDDIM + h];
  sb[(size_t)n*HIDDIM + h] = f2b(x);
  __shared__ float red[128];
  red[h] = x; __syncthreads();
  for (int o = 64; o > 0; o >>= 1){ if (h < o) red[h] += red[h+o]; __syncthreads(); }
  float mean = red[0] * (1.f/128.f);
  __syncthreads();
  float dx = x - mean;
  red[h] = dx*dx; __syncthreads();
  for (int o = 64; o > 0; o >>= 1){ if (h < o) red[h] += red[h+o]; __syncthreads(); }
  float var = red[0] * (1.f/128.f);
  float y = dx * rsqrtf(var + 1e-5f);
  dst[(size_t)n*HIDDIM + h] = f2b(y * g[h] + b[h]);
}

// ---------------- rowptr-based segment sums (one block per node) ----------------
__global__ __launch_bounds__(128) void k_seg1n(const int* __restrict__ rowptr,
    const int* __restrict__ jp, int o, int Cc,
    const float* __restrict__ h0, const ushortT* __restrict__ rhid,
    float* __restrict__ s)
{
  int i = blockIdx.x, h = threadIdx.x;
  int b = rowptr[i], e = rowptr[i+1];
  if (b < o) b = o;
  int hi = o + Cc; if (e > hi) e = hi;
  if (b >= e) return;
  float acc = 0.f;
  int m = b;
  for (; m + 1 < e; m += 2){
    int j0 = jp[m], j1 = jp[m+1];
    float r0 = b2f(rhid[(size_t)(m-o)*HIDDIM + h]);
    float r1 = b2f(rhid[(size_t)(m+1-o)*HIDDIM + h]);
    acc += h0[(size_t)j0*HIDDIM + h]*r0 + h0[(size_t)j1*HIDDIM + h]*r1;
  }
  if (m < e) acc += h0[(size_t)jp[m]*HIDDIM + h] * b2f(rhid[(size_t)(m-o)*HIDDIM + h]);
  s[(size_t)i*HIDDIM + h] += acc;
}

__global__ __launch_bounds__(128) void k_seg2n(const int* __restrict__ rowptr,
    const int* __restrict__ jp, int o, int Cc,
    const ushortT* __restrict__ slin, const ushortT* __restrict__ rhid,
    const float* __restrict__ edb, float* __restrict__ S)
{
  int i = blockIdx.x, h = threadIdx.x;
  int b = rowptr[i], e = rowptr[i+1];
  if (b < o) b = o;
  int hi = o + Cc; if (e > hi) e = hi;
  if (b >= e) return;
  float a0 = 0.f, a1 = 0.f, a2 = 0.f;
  int m = b;
  for (; m + 1 < e; m += 2){
    int ml = m - o, ml2 = ml + 1;
    float u0 = b2f(slin[(size_t)jp[m]*HIDDIM + h])   * b2f(rhid[(size_t)ml*HIDDIM + h]);
    float u1 = b2f(slin[(size_t)jp[m+1]*HIDDIM + h]) * b2f(rhid[(size_t)ml2*HIDDIM + h]);
    a0 += u0*edb[3*ml]   + u1*edb[3*ml2];
    a1 += u0*edb[3*ml+1] + u1*edb[3*ml2+1];
    a2 += u0*edb[3*ml+2] + u1*edb[3*ml2+2];
  }
  if (m < e){
    int ml = m - o;
    float u0 = b2f(slin[(size_t)jp[m]*HIDDIM + h]) * b2f(rhid[(size_t)ml*HIDDIM + h]);
    a0 += u0*edb[3*ml]; a1 += u0*edb[3*ml+1]; a2 += u0*edb[3*ml+2];
  }
  float* base = &S[(size_t)i*384 + h];
  base[0]   += a0;
  base[128] += a1;
  base[256] += a2;
}

__global__ __launch_bounds__(128) void k_seg3n(const int* __restrict__ rowptr,
    int o, int Cc,
    const ushortT* __restrict__ mb, const float* __restrict__ edb,
    float* __restrict__ s, float* __restrict__ vecacc)
{
  int i = blockIdx.x, h = threadIdx.x;
  int b = rowptr[i], e = rowptr[i+1];
  if (b < o) b = o;
  int hi = o + Cc; if (e > hi) e = hi;
  if (b >= e) return;
  const float is128 = 0.08838834764831845f;
  float am = 0.f, v0 = 0.f, v1 = 0.f, v2 = 0.f;
  int m = b;
  for (; m + 1 < e; m += 2){
    int ml = m - o, ml2 = ml + 1;
    float m1a = b2f(mb[(size_t)ml*384 + h]);
    float m1b = b2f(mb[(size_t)ml2*384 + h]);
    float mma = b2f(mb[(size_t)ml*384 + 256 + h]) * is128;
    float mmb = b2f(mb[(size_t)ml2*384 + 256 + h]) * is128;
    am += m1a + m1b;
    v0 += mma*edb[3*ml]   + mmb*edb[3*ml2];
    v1 += mma*edb[3*ml+1] + mmb*edb[3*ml2+1];
    v2 += mma*edb[3*ml+2] + mmb*edb[3*ml2+2];
  }
  if (m < e){
    int ml = m - o;
    float m1 = b2f(mb[(size_t)ml*384 + h]);
    float mm = b2f(mb[(size_t)ml*384 + 256 + h]) * is128;
    am += m1;
    v0 += mm*edb[3*ml]; v1 += mm*edb[3*ml+1]; v2 += mm*edb[3*ml+2];
  }
  s[(size_t)i*HIDDIM + h] += am;
  float* base = &vecacc[(size_t)i*384 + h];
  base[0]   += v0;
  base[128] += v1;
  base[256] += v2;
}

// ---------------- scalarize v4: 2 edges/block, no LDS, scalar weights ----------------
// writes only scal values (256/edge) to ews (stride 256)
__global__ __launch_bounds__(256) void k_scal4(
  const int* __restrict__ jp, const int* __restrict__ ip, int off, int Cc,
  const float* __restrict__ S,
  const float* __restrict__ edb, const float* __restrict__ ecv,
  const float* __restrict__ rb,
  const float* __restrict__ l3s,
  ushortT* __restrict__ ews)
{
  int ea = blockIdx.x*2;
  int eb = (ea + 1 < Cc) ? ea + 1 : ea;
  int t = threadIdx.x;
  int which = t >> 7, h = t & 127;
  int ga = off + ea, gb = off + eb;
  int na = which ? jp[ga] : ip[ga];
  int nb = which ? jp[gb] : ip[gb];
  f2_t f00 = {edb[3*ea],   edb[3*eb]};
  f2_t f01 = {edb[3*ea+1], edb[3*eb+1]};
  f2_t f02 = {edb[3*ea+2], edb[3*eb+2]};
  f2_t f10 = {ecv[6*ea],   ecv[6*eb]};
  f2_t f11 = {ecv[6*ea+1], ecv[6*eb+1]};
  f2_t f12 = {ecv[6*ea+2], ecv[6*eb+2]};
  f2_t f20 = {ecv[6*ea+3], ecv[6*eb+3]};
  f2_t f21 = {ecv[6*ea+4], ecv[6*eb+4]};
  f2_t f22 = {ecv[6*ea+5], ecv[6*eb+5]};
  f2_t rbv = {rb[ea], rb[eb]};
  const float* Sa = &S[(size_t)na*384];
  const float* Sb = &S[(size_t)nb*384];
  f2_t S0 = {Sa[h],     Sb[h]};
  f2_t S1 = {Sa[128+h], Sb[128+h]};
  f2_t S2 = {Sa[256+h], Sb[256+h]};
  f2_t v0 = S0*f00 + S1*f01 + S2*f02;
  f2_t v1t = S0*f10 + S1*f11 + S2*f12;
  f2_t v1 = {fabsf(v1t.x), fabsf(v1t.y)};
  f2_t v2 = S0*f20 + S1*f21 + S2*f22;
  f2_t out = {0.f, 0.f};
  #pragma unroll
  for (int u = 0; u < 32; ++u){
    f2_t tt = v0*l3s[u] + v1*l3s[32+u] + v2*l3s[64+u] + l3s[96+u];
    f2_t r;
    r.x = RCPF(1.f + EXP2F(tt.x));
    r.y = RCPF(1.f + EXP2F(tt.y));
    out += (tt*r)*l3s[128+u];
  }
  f2_t res = (out + l3s[160] + v0) * rbv;
  ews[(size_t)ea*256 + which*128 + h] = f2b(res.x);
  if (eb != ea) ews[(size_t)eb*256 + which*128 + h] = f2b(res.y);
}

// ---------------- bf16 MFMA GEMM ----------------
// A: MxK bf16 row-major; BT: NxK bf16 row-major. N%128==0, K%32==0.
// epi: 0 none, 1 silu, 2 *rowscale[row], 3 *mul1b[row,col]*xhpb[jidx[row],col]
// skipTile >= 0: that 128-col tile is not computed (grid.x one smaller).
// A1 != nullptr: split-A — K [0,256) from A (stride 256), [256,384) from A1
// (stride 128), [384,480) from A2 (stride 96).
__global__ __launch_bounds__(256) void mgemm(
  const ushortT* __restrict__ A, const ushortT* __restrict__ BT,
  const float* __restrict__ bias,
  float* __restrict__ Cf, ushortT* __restrict__ Cb,
  int M, int N, int K, int epi,
  const float* __restrict__ rowscale,
  const ushortT* __restrict__ mul1b,
  const ushortT* __restrict__ xhpb,
  const int* __restrict__ jidx,
  int skipTile,
  const ushortT* __restrict__ A1, const ushortT* __restrict__ A2)
{
  const int tid = threadIdx.x;
  const int w = tid >> 6;
  const int lane = tid & 63;
  const int l15 = lane & 15;
  const int q = lane >> 4;
  const int wm = w & 1, wn = w >> 1;
  const int rowBase = blockIdx.y * 128;
  int bx = blockIdx.x;
  if (skipTile >= 0 && bx >= skipTile) bx++;
  const int colBase = bx * 128;
  f4_t acc[4][4] = {};

#ifdef HAVE_GLDS
  __shared__ ushortT As[128*32];
  __shared__ ushortT Bs[128*32];
  const int rS = 32*w + (lane >> 2);
  const int kS = (lane & 3) << 3;
  ushortT* lA0 = &As[(32*w)*32];
  ushortT* lA1 = &As[(32*w+16)*32];
  ushortT* lB0 = &Bs[(32*w)*32];
  ushortT* lB1 = &Bs[(32*w+16)*32];
  int ra0 = rowBase + rS;      if (ra0 >= M) ra0 = M-1;
  int ra1 = rowBase + rS + 16; if (ra1 >= M) ra1 = M-1;
  const ushortT* gB0 = BT + (size_t)(colBase + rS)*K + kS;
  const ushortT* gB1 = BT + (size_t)(colBase + rS + 16)*K + kS;
  for (int k0 = 0; k0 < K; k0 += 32){
    const ushortT* srcA; size_t strA; int kc;
    if (!A1){ srcA = A; strA = (size_t)K; kc = k0; }
    else if (k0 < 256){ srcA = A; strA = 256; kc = k0; }
    else if (k0 < 384){ srcA = A1; strA = 128; kc = k0 - 256; }
    else { srcA = A2; strA = 96; kc = k0 - 384; }
    glds16(srcA + (size_t)ra0*strA + kc + kS, lA0);
    glds16(srcA + (size_t)ra1*strA + kc + kS, lA1);
    glds16(gB0 + k0, lB0);
    glds16(gB1 + k0, lB1);
    __syncthreads();
    bf8_t a[4], b[4];
    #pragma unroll
    for (int mt = 0; mt < 4; ++mt)
      a[mt] = *(const bf8_t*)&As[(wm*64 + mt*16 + l15)*32 + q*8];
    #pragma unroll
    for (int nt = 0; nt < 4; ++nt)
      b[nt] = *(const bf8_t*)&Bs[(wn*64 + nt*16 + l15)*32 + q*8];
    #pragma unroll
    for (int mt = 0; mt < 4; ++mt){
      #pragma unroll
      for (int nt = 0; nt < 4; ++nt)
        acc[mt][nt] = __builtin_amdgcn_mfma_f32_16x16x32_bf16(a[mt], b[nt], acc[mt][nt], 0, 0, 0);
    }
    __syncthreads();
  }
#else
  __shared__ ushortT As[128*48];
  __shared__ ushortT Bs[128*48];
  const int r0 = tid >> 2,         s0 = (tid & 3) << 3;
  const int r1 = (tid + 256) >> 2, s1 = ((tid + 256) & 3) << 3;
  for (int k0 = 0; k0 < K; k0 += 32){
    const ushortT* srcA; size_t strA; int kc;
    if (!A1){ srcA = A; strA = (size_t)K; kc = k0; }
    else if (k0 < 256){ srcA = A; strA = 256; kc = k0; }
    else if (k0 < 384){ srcA = A1; strA = 128; kc = k0 - 256; }
    else { srcA = A2; strA = 96; kc = k0 - 384; }
    int4 a0v = make_int4(0,0,0,0), a1v = make_int4(0,0,0,0);
    if (rowBase + r0 < M) a0v = *(const int4*)&srcA[(size_t)(rowBase + r0)*strA + kc + s0];
    if (rowBase + r1 < M) a1v = *(const int4*)&srcA[(size_t)(rowBase + r1)*strA + kc + s1];
    int4 b0v = *(const int4*)&BT[(size_t)(colBase + r0)*K + k0 + s0];
    int4 b1v = *(const int4*)&BT[(size_t)(colBase + r1)*K + k0 + s1];
    __syncthreads();
    *(int4*)&As[r0*48 + s0] = a0v;
    *(int4*)&As[r1*48 + s1] = a1v;
    *(int4*)&Bs[r0*48 + s0] = b0v;
    *(int4*)&Bs[r1*48 + s1] = b1v;
    __syncthreads();
    bf8_t a[4], b[4];
    #pragma unroll
    for (int mt = 0; mt < 4; ++mt)
      a[mt] = *(const bf8_t*)&As[(wm*64 + mt*16 + l15)*48 + q*8];
    #pragma unroll
    for (int nt = 0; nt < 4; ++nt)
      b[nt] = *(const bf8_t*)&Bs[(wn*64 + nt*16 + l15)*48 + q*8];
    #pragma unroll
    for (int mt = 0; mt < 4; ++mt){
      #pragma unroll
      for (int nt = 0; nt < 4; ++nt)
        acc[mt][nt] = __builtin_amdgcn_mfma_f32_16x16x32_bf16(a[mt], b[nt], acc[mt][nt], 0, 0, 0);
    }
  }
#endif

  #pragma unroll
  for (int mt = 0; mt < 4; ++mt){
    int row = rowBase + wm*64 + mt*16 + q*4;
    #pragma unroll
    for (int nt = 0; nt < 4; ++nt){
      int col = colBase + wn*64 + nt*16 + l15;
      float bv = bias ? bias[col] : 0.f;
      #pragma unroll
      for (int r = 0; r < 4; ++r){
        int rr = row + r;
        if (rr >= M) continue;
        float x = acc[mt][nt][r] + bv;
        if (epi == 1) x = silu_f(x);
        else if (epi == 2) x *= rowscale[rr];
        else if (epi == 3) x = x * b2f(mul1b[(size_t)rr*N + col]) * b2f(xhpb[(size_t)jidx[rr]*N + col]);
        if (Cb) Cb[(size_t)rr*N + col] = f2b(x);
        else    Cf[(size_t)rr*N + col] = x;
      }
    }
  }
}

// ---------------- fte prep ----------------
__global__ __launch_bounds__(128) void k_fte_pre(const float* __restrict__ vpc,
    const float* __restrict__ s, ushortT* __restrict__ catb, float* __restrict__ vdot,
    int no)
{
  int nl = blockIdx.x, h = threadIdx.x;
  int n = no + nl;
  const float* base = &vpc[(size_t)nl*768];
  float a0 = base[h],       a1 = base[256+h],     a2 = base[512+h];
  float c0 = base[128+h],   c1 = base[384+h],     c2 = base[640+h];
  float scal = sqrtf(a0*a0 + a1*a1 + a2*a2 + 1e-10f);
  float vd = (a0*c0 + a1*c1 + a2*c2) * 0.08838834764831845f;
  catb[(size_t)n*256 + h] = f2b(s[(size_t)n*HIDDIM + h]);
  catb[(size_t)n*256 + 128 + h] = f2b(scal);
  vdot[(size_t)n*HIDDIM + h] = vd;
}

// ---------------- final ----------------
__global__ __launch_bounds__(128) void k_out(const float* __restrict__ xh2,
    const float* __restrict__ vdot, const float* __restrict__ s,
    const float* __restrict__ ow, const float* __restrict__ ob,
    float* __restrict__ nodeout)
{
  int n = blockIdx.x, h = threadIdx.x;
  float a1 = xh2[(size_t)n*384 + h];
  float a2 = xh2[(size_t)n*384 + 128 + h];
  float sv = s[(size_t)n*HIDDIM + h] + (a1 + a2*vdot[(size_t)n*HIDDIM + h]) * 0.7071067811865476f;
  __shared__ float red[128];
  red[h] = sv * ow[h];
  __syncthreads();
  for (int o = 64; o > 0; o >>= 1){ if (h < o) red[h] += red[h+o]; __syncthreads(); }
  if (h == 0) nodeout[n] = red[0] + ob[0];
}

__global__ __launch_bounds__(256) void k_final(const float* __restrict__ nodeout,
    const int* __restrict__ batch, void* __restrict__ out, int Nn, const int* flags)
{
  int g = blockIdx.x;
  __shared__ float rs[256], rc[256];
  float sm = 0.f, c = 0.f;
  for (int n = threadIdx.x; n < Nn; n += 256){
    if (batch[n] == g){ sm += nodeout[n]; c += 1.f; }
  }
  rs[threadIdx.x] = sm; rc[threadIdx.x] = c;
  __syncthreads();
  for (int o = 128; o > 0; o >>= 1){
    if (threadIdx.x < o){ rs[threadIdx.x] += rs[threadIdx.x+o]; rc[threadIdx.x] += rc[threadIdx.x+o]; }
    __syncthreads();
  }
  if (threadIdx.x == 0){
    float v = (rc[0] > 0.f) ? rs[0]/rc[0] : 0.f;
    if (flags[2] == 0) ((__hip_bfloat16*)out)[g] = __float2bfloat16(v);
    else ((float*)out)[g] = v;
  }
}

// =====================================================================
extern "C" void kernel_launch(void* const* d_in, const int* in_sizes, int n_in,
                              void* d_out, int out_size, void* d_ws, size_t ws_size,
                              hipStream_t stream)
{
  const int N = in_sizes[0] / 3;
  const int E = in_sizes[3] / 2;

  size_t off = 0;
  auto alloc = [&](size_t n)->float*{
    float* p = (float*)d_ws + off;
    off += (n + 3) & ~(size_t)3;
    return p;
  };
  auto allocU = [&](size_t n)->ushortT*{ return (ushortT*)alloc((n + 1) / 2); };

  int* flags  = (int*)alloc(4);
  int* deg    = (int*)alloc((size_t)N);
  int* cursor = (int*)alloc((size_t)N);
  size_t zeroHdr = off;
  int* zi     = (int*)alloc((size_t)N);
  int* bi     = (int*)alloc((size_t)N);
  int* eii    = (int*)alloc((size_t)2*E);
  int* rowptr = (int*)alloc((size_t)N + 4);
  int* jp     = (int*)alloc((size_t)E);
  int* ipp    = (int*)alloc((size_t)E);
  float* l3s  = alloc(164);

  float* pos = alloc((size_t)N*3);
  float* w[31];
  for (int t = 0; t < 31; ++t) w[t] = alloc((size_t)in_sizes[4+t]);
  float* rl_b1=w[1];  float* rl_b2=w[3];
  float* ne_w =w[4];  float* ne_b =w[5];  float* sv_b =w[7];
  float* l3_w1=w[8];  float* l3_b1=w[9];  float* l3_w2=w[10]; float* l3_b2=w[11];
  float* mp_w =w[12]; float* mp_b =w[13]; float* xp_b1=w[15];
  float* xp_b2=w[17]; float* rp_b =w[19];
  float* ip_b1=w[21]; float* ip_b2=w[23];
  float* fte_b1=w[26];float* fte_b2=w[28];float* out_w=w[29]; float* out_b=w[30];

  ushortT* wt_rl1 = allocU(96*128);
  ushortT* wt_rl2 = allocU(128*128);
  ushortT* wt_sv  = allocU(128*128);
  ushortT* wt_xp1 = allocU(128*128);
  ushortT* wt_xp2 = allocU((size_t)128*384);
  ushortT* wt_rp  = allocU((size_t)96*384);
  ushortT* wt_ip1 = allocU((size_t)480*384);
  ushortT* wt_ip2 = allocU((size_t)384*384);
  ushortT* wt_feq = allocU((size_t)128*256);
  ushortT* wt_ft1 = allocU((size_t)256*128);
  ushortT* wt_ft2 = allocU((size_t)128*384);

  float* s    = alloc((size_t)N*HIDDIM);
  float* h0   = alloc((size_t)N*HIDDIM);      // -> vdot overlay after seg1
  ushortT* sb     = allocU((size_t)N*HIDDIM); // sb+slin_b contiguous -> catb overlay
  ushortT* slin_b = allocU((size_t)N*HIDDIM);
  ushortT* xln_b  = allocU((size_t)N*HIDDIM);
  ushortT* hb     = allocU((size_t)N*HIDDIM);
  float* S    = alloc((size_t)N*384);         // -> vab overlay in phase F
  float* vecacc = alloc((size_t)N*384);       // -> xh2 overlay after f2b
  ushortT* xh_b = allocU((size_t)N*384);
  float* nodeout = alloc((size_t)N);
  float* vdot = h0;
  ushortT* catb = sb;
  ushortT* vab = (ushortT*)S;
  float* xh2 = vecacc;

  size_t wsF = ws_size / sizeof(float);

  // tier selection:
  //  tier2: persist edb(3)+ecv(6)+rb(1)+remb(48)+rhid(64) = 122 f/edge; chunk 576 f/edge
  //  tier1: persist edb+rhid (67 f/edge);                  chunk 631 f/edge
  //  tier0: nothing persists;                              chunk 698 f/edge
  int tier = 0; size_t p = 698;
  if (off + 122ULL*(size_t)E + 16 + 256ULL*576 <= wsF){ tier = 2; p = 576; }
  else if (off + 67ULL*(size_t)E + 16 + 256ULL*631 <= wsF){ tier = 1; p = 631; }

  ushortT *rhid_a = nullptr, *remb_a = nullptr;
  float *edb_a = nullptr, *ecv_a = nullptr, *rb_a = nullptr;
  if (tier >= 1){
    rhid_a = allocU((size_t)E*128);
    edb_a  = alloc((size_t)3*E);
  }
  if (tier == 2){
    ecv_a  = alloc((size_t)6*E);
    rb_a   = alloc((size_t)E);
    remb_a = allocU((size_t)E*96);
  }
  size_t availF = (wsF > off) ? (wsF - off) : 0;
  if (availF < 256*p){
    k_sentinel<<<1, 64, 0, stream>>>((__hip_bfloat16*)d_out, out_size,
                                     (float)(double)(ws_size >> 20));
    return;
  }
  size_t Cs = availF / p; if (Cs > (size_t)E) Cs = E;
  int C = (int)(Cs & ~(size_t)15);
  if (C < 256) C = 256;

  float* scratch0 = (float*)d_ws + off;
  ushortT* remb_l = nullptr; float *ecv_l = nullptr, *rb_l = nullptr;
  if (tier <= 1){
    remb_l = allocU((size_t)C*96);   // 48C
    ecv_l  = alloc((size_t)6*C);
    rb_l   = alloc((size_t)C);
  }
  float* edb_l = nullptr; ushortT* rhid_l = nullptr;
  if (tier == 0){
    edb_l  = alloc((size_t)3*C);
    rhid_l = allocU((size_t)C*128);
  }
  ushortT* ewReg = allocU((size_t)C*384);     // 192C: ews (256/edge) then Rmb (384/edge)
  ushortT* R2b  = allocU((size_t)C*384);      // 192C ; R2rl overlays
  ushortT* R1b  = allocU((size_t)C*384);      // 192C
  ushortT* ews  = ewReg;
  ushortT* Rmb  = ewReg;
  ushortT* R2rl = R2b;
  float* vpc = scratch0;
  size_t scratchF = (size_t)C*p;

  auto mg = [&](const ushortT* A, const ushortT* BT, const float* bias,
                float* Cf, ushortT* Cb, int M, int Nc, int K, int epi,
                const float* rowscale = nullptr, const ushortT* mul1b = nullptr,
                const ushortT* xhpb = nullptr, const int* jidx = nullptr,
                int skipTile = -1,
                const ushortT* A1 = nullptr, const ushortT* A2 = nullptr){
    dim3 grid(Nc/128 - (skipTile >= 0 ? 1 : 0), (M + 127)/128);
    mgemm<<<grid, 256, 0, stream>>>(A, BT, bias, Cf, Cb, M, Nc, K, epi,
                                    rowscale, mul1b, xhpb, jidx, skipTile, A1, A2);
  };

  // 0) zero header, detect dtypes, int-normalize (+deg histogram)
  k_zero<<<64, 256, 0, stream>>>((float*)flags, (int)zeroHdr);
  k_detect<<<64, 256, 0, stream>>>((const ushortT*)d_in[0], in_sizes[0],
                                   (const int*)d_in[2], in_sizes[2], flags);
  k_iconv<<<1024, 256, 0, stream>>>((const int*)d_in[1], (const int*)d_in[2],
                                    (const int*)d_in[3], zi, bi, eii, N, E, flags, deg);

  // 1) float conversions + transposed bf16 weights + l3 prescale
  ConvArgs ca;
  ca.d[0] = { (const ushortT*)d_in[0], pos, in_sizes[0] };
  for (int t = 0; t < 31; ++t)
    ca.d[1+t] = { (const ushortT*)d_in[4+t], w[t], in_sizes[4+t] };
  k_conv<<<dim3(32, 32), 256, 0, stream>>>(ca, 32, flags);
  k_l3pre<<<1, 192, 0, stream>>>(l3_w1, l3_b1, l3_w2, l3_b2, l3s);

  TArgs ta;
  ta.d[0]  = { (const ushortT*)d_in[4],  wt_rl1, 96, 128 };
  ta.d[1]  = { (const ushortT*)d_in[6],  wt_rl2, 128, 128 };
  ta.d[2]  = { (const ushortT*)d_in[10], wt_sv,  128, 128 };
  ta.d[3]  = { (const ushortT*)d_in[18], wt_xp1, 128, 128 };
  ta.d[4]  = { (const ushortT*)d_in[20], wt_xp2, 128, 384 };
  ta.d[5]  = { (const ushortT*)d_in[22], wt_rp,  96, 384 };
  ta.d[6]  = { (const ushortT*)d_in[24], wt_ip1, 480, 384 };
  ta.d[7]  = { (const ushortT*)d_in[26], wt_ip2, 384, 384 };
  ta.d[8]  = { (const ushortT*)d_in[28], wt_feq, 128, 256 };
  ta.d[9]  = { (const ushortT*)d_in[29], wt_ft1, 256, 128 };
  ta.d[10] = { (const ushortT*)d_in[31], wt_ft2, 128, 384 };
  k_wt<<<dim3(48, 11), 256, 0, stream>>>(ta, 11, flags);

  // 2) CSR scan + scatter
  k_csr_scan<<<1, 256, 0, stream>>>(deg, rowptr, N);
  k_csr_scatter<<<(E + 255)/256, 256, 0, stream>>>(eii, E, rowptr, cursor, jp, ipp);

  // 3) node embedding (+ S/vecacc zero fused)
  k_embed<<<N, 128, 0, stream>>>(zi, ne_w, ne_b, s, h0, S, vecacc);

  // pre-pass + Phase B
  if (tier == 2){
    k_geom<<<(E + 255)/256, 256, 0, stream>>>(pos, jp, ipp, 0, E,
                                              edb_a, ecv_a, rb_a, remb_a);
    for (int o = 0; o < E; o += C){
      int Cc = (E - o < C) ? (E - o) : C;
      mg(remb_a + (size_t)o*96, wt_rl1, rl_b1, nullptr, R2rl, Cc, 128, 96, 1);
      mg(R2rl, wt_rl2, rl_b2, nullptr, rhid_a + (size_t)o*128, Cc, 128, 128, 2, rb_a + o);
    }
    k_seg1n<<<N, 128, 0, stream>>>(rowptr, jp, 0, E, h0, rhid_a, s);
  } else if (tier == 1){
    for (int o = 0; o < E; o += C){
      int Cc = (E - o < C) ? (E - o) : C;
      k_geom<<<(Cc + 255)/256, 256, 0, stream>>>(pos, jp, ipp, o, Cc,
                                                 edb_a + (size_t)3*o, nullptr, rb_l, remb_l);
      mg(remb_l, wt_rl1, rl_b1, nullptr, R2rl, Cc, 128, 96, 1);
      mg(R2rl, wt_rl2, rl_b2, nullptr, rhid_a + (size_t)o*128, Cc, 128, 128, 2, rb_l);
    }
    k_seg1n<<<N, 128, 0, stream>>>(rowptr, jp, 0, E, h0, rhid_a, s);
  } else {
    for (int o = 0; o < E; o += C){
      int Cc = (E - o < C) ? (E - o) : C;
      k_geom<<<(Cc + 255)/256, 256, 0, stream>>>(pos, jp, ipp, o, Cc,
                                                 edb_l, nullptr, rb_l, remb_l);
      mg(remb_l, wt_rl1, rl_b1, nullptr, R2rl, Cc, 128, 96, 1);
      mg(R2rl, wt_rl2, rl_b2, nullptr, rhid_l, Cc, 128, 128, 2, rb_l);
      k_seg1n<<<N, 128, 0, stream>>>(rowptr, jp, o, Cc, h0, rhid_l, s);
    }
  }

  // Phase C: slin, xln(+sb), xh (xh cols 128-255 dead -> skip tile 1)
  k_ln<<<N, 128, 0, stream>>>(s, xln_b, mp_w, mp_b, sb);
  mg(sb, wt_sv, sv_b, nullptr, slin_b, N, 128, 128, 1);
  mg(xln_b, wt_xp1, xp_b1, nullptr, hb, N, 128, 128, 1);
  mg(hb, wt_xp2, xp_b2, nullptr, xh_b, N, 384, 128, 0, nullptr, nullptr, nullptr, nullptr, 1);

  // Phase D: seg2
  if (tier >= 1){
    k_seg2n<<<N, 128, 0, stream>>>(rowptr, jp, 0, E, slin_b, rhid_a, edb_a, S);
  } else {
    for (int o = 0; o < E; o += C){
      int Cc = (E - o < C) ? (E - o) : C;
      k_geom<<<(Cc + 255)/256, 256, 0, stream>>>(pos, jp, ipp, o, Cc,
                                                 edb_l, nullptr, rb_l, remb_l);
      mg(remb_l, wt_rl1, rl_b1, nullptr, R2rl, Cc, 128, 96, 1);
      mg(R2rl, wt_rl2, rl_b2, nullptr, rhid_l, Cc, 128, 128, 2, rb_l);
      k_seg2n<<<N, 128, 0, stream>>>(rowptr, jp, o, Cc, slin_b, rhid_l, edb_l, S);
    }
  }

  // Phase E: per-edge big MLPs + seg3 (rp/ip2 skip dead middle tile; ip1 split-A)
  for (int o = 0; o < E; o += C){
    int Cc = (E - o < C) ? (E - o) : C;
    const ushortT *rhid_p, *remb_p;
    const float *edb_p, *ecv_p, *rb_p;
    if (tier == 2){
      rhid_p = rhid_a + (size_t)o*128;
      edb_p  = edb_a + (size_t)3*o;
      ecv_p  = ecv_a + (size_t)6*o;
      rb_p   = rb_a + o;
      remb_p = remb_a + (size_t)o*96;
    } else if (tier == 1){
      k_geom<<<(Cc + 255)/256, 256, 0, stream>>>(pos, jp, ipp, o, Cc,
                                                 edb_a + (size_t)3*o, ecv_l, rb_l, remb_l);
      rhid_p = rhid_a + (size_t)o*128;
      edb_p  = edb_a + (size_t)3*o;
      ecv_p  = ecv_l; rb_p = rb_l; remb_p = remb_l;
    } else {
      k_geom<<<(Cc + 255)/256, 256, 0, stream>>>(pos, jp, ipp, o, Cc,
                                                 edb_l, ecv_l, rb_l, remb_l);
      mg(remb_l, wt_rl1, rl_b1, nullptr, R2rl, Cc, 128, 96, 1);
      mg(R2rl, wt_rl2, rl_b2, nullptr, rhid_l, Cc, 128, 128, 2, rb_l);
      rhid_p = rhid_l; edb_p = edb_l; ecv_p = ecv_l; rb_p = rb_l; remb_p = remb_l;
    }
    k_scal4<<<(Cc + 1)/2, 256, 0, stream>>>(jp, ipp, o, Cc, S,
                                            edb_p, ecv_p, rb_p, l3s, ews);
    mg(remb_p, wt_rp, rp_b, nullptr, R1b, Cc, 384, 96, 0,
       nullptr, nullptr, nullptr, nullptr, 1);
    mg(ews, wt_ip1, ip_b1, nullptr, R2b, Cc, 384, 480, 1,
       nullptr, nullptr, nullptr, nullptr, -1, rhid_p, remb_p);
    mg(R2b, wt_ip2, ip_b2, nullptr, Rmb, Cc, 384, 384, 3,
       nullptr, R1b, xh_b, jp + o, 1);
    k_seg3n<<<N, 128, 0, stream>>>(rowptr, o, Cc, Rmb, edb_p, s, vecacc);
  }

  // Phase F: fte
  k_f2b<<<1024, 256, 0, stream>>>(vecacc, vab, N*384);
  int Cn = (int)(scratchF / 768);
  if (Cn > N) Cn = N;
  for (int no = 0; no < N; no += Cn){
    int Cc = (N - no < Cn) ? (N - no) : Cn;
    mg(vab + (size_t)no*384, wt_feq, nullptr, vpc, nullptr, 3*Cc, 256, 128, 0);
    k_fte_pre<<<Cc, 128, 0, stream>>>(vpc, s, catb, vdot, no);
  }
  mg(catb, wt_ft1, fte_b1, nullptr, hb, N, 128, 256, 1);
  mg(hb, wt_ft2, fte_b2, xh2, nullptr, N, 384, 128, 0);

  // Phase G
  k_out<<<N, 128, 0, stream>>>(xh2, vdot, s, out_w, out_b, nodeout);
  k_final<<<out_size, 256, 0, stream>>>(nodeout, bi, d_out, N, flags);
}